// Round 1
// baseline (1013.634 us; speedup 1.0000x reference)
//
#include <hip/hip_runtime.h>
#include <hip/hip_bf16.h>

#define DIM 2048
#define HEAD_DIM 128
#define N_HEADS 16
#define SEQ 2048
#define HID 8192

typedef short bf16x8 __attribute__((ext_vector_type(8)));
typedef float f32x4 __attribute__((ext_vector_type(4)));
using bf16 = __hip_bfloat16;

#define MFMA16(a, b, c) __builtin_amdgcn_mfma_f32_16x16x32_bf16(a, b, c, 0, 0, 0)

__device__ __forceinline__ unsigned short f2bu(float f) {
    union { bf16 b; unsigned short u; } cv;
    cv.b = __float2bfloat16(f);
    return cv.u;
}

// ---------------- rmsnorm (fp32 in -> bf16 out) ----------------
__global__ __launch_bounds__(256) void rmsnorm_bf16_k(
    const float* __restrict__ x, const float* __restrict__ w, bf16* __restrict__ y)
{
    const int row = blockIdx.x;
    const int tid = threadIdx.x;
    const float* xr = x + (size_t)row * DIM;
    float4 v0 = ((const float4*)xr)[tid];
    float4 v1 = ((const float4*)xr)[tid + 256];
    float ss = v0.x*v0.x + v0.y*v0.y + v0.z*v0.z + v0.w*v0.w
             + v1.x*v1.x + v1.y*v1.y + v1.z*v1.z + v1.w*v1.w;
    for (int o = 32; o > 0; o >>= 1) ss += __shfl_down(ss, o);
    __shared__ float red[4];
    if ((tid & 63) == 0) red[tid >> 6] = ss;
    __syncthreads();
    float tot = red[0] + red[1] + red[2] + red[3];
    float r = rsqrtf(tot * (1.0f / DIM) + 1e-6f);
    float4 w0 = ((const float4*)w)[tid];
    float4 w1 = ((const float4*)w)[tid + 256];
    ushort4 o0, o1;
    o0.x = f2bu(v0.x * r * w0.x); o0.y = f2bu(v0.y * r * w0.y);
    o0.z = f2bu(v0.z * r * w0.z); o0.w = f2bu(v0.w * r * w0.w);
    o1.x = f2bu(v1.x * r * w1.x); o1.y = f2bu(v1.y * r * w1.y);
    o1.z = f2bu(v1.z * r * w1.z); o1.w = f2bu(v1.w * r * w1.w);
    ushort4* yr = (ushort4*)(y + (size_t)row * DIM);
    yr[tid] = o0;
    yr[tid + 256] = o1;
}

// ---------------- fp32 [R][C] -> bf16 [C][R] transpose-convert ----------------
__global__ __launch_bounds__(256) void convT_f32_bf16_k(
    const float* __restrict__ in, bf16* __restrict__ out, int R, int C)
{
    __shared__ float t[32][33];
    const int tx = threadIdx.x, ty = threadIdx.y;
    const int x0 = blockIdx.x * 32, y0 = blockIdx.y * 32;
#pragma unroll
    for (int i = 0; i < 4; ++i)
        t[ty + i * 8][tx] = in[(size_t)(y0 + ty + i * 8) * C + x0 + tx];
    __syncthreads();
#pragma unroll
    for (int i = 0; i < 4; ++i)
        out[(size_t)(x0 + ty + i * 8) * R + y0 + tx] = __float2bfloat16(t[tx][ty + i * 8]);
}

// ---------------- bf16 [2048][2048] transpose ----------------
__global__ __launch_bounds__(256) void transpose_bf16_k(
    const bf16* __restrict__ in, bf16* __restrict__ out)
{
    __shared__ unsigned short t[32][33];
    const int tx = threadIdx.x, ty = threadIdx.y;
    const int x = blockIdx.x * 32 + tx;
    const int y0 = blockIdx.y * 32;
    const unsigned short* inu = (const unsigned short*)in;
    unsigned short* outu = (unsigned short*)out;
#pragma unroll
    for (int i = 0; i < 4; ++i)
        t[ty + i * 8][tx] = inu[(size_t)(y0 + ty + i * 8) * DIM + x];
    __syncthreads();
    const int x2 = blockIdx.y * 32 + tx;
    const int y2 = blockIdx.x * 32;
#pragma unroll
    for (int i = 0; i < 4; ++i)
        outu[(size_t)(y2 + ty + i * 8) * DIM + x2] = t[tx][ty + i * 8];
}

// ---------------- RoPE in-place on bf16 q,k ----------------
__global__ __launch_bounds__(256) void rope_qk_k(
    bf16* __restrict__ q, bf16* __restrict__ k,
    const float* __restrict__ cosb, const float* __restrict__ sinb)
{
    const int gid = blockIdx.x * 256 + threadIdx.x;   // < SEQ * 1024
    const int s = gid >> 10;
    const int p = gid & 1023;
    const int h = p >> 6, j = p & 63;
    const size_t off = (size_t)s * DIM + h * HEAD_DIM + 2 * j;
    const float c = cosb[s * 64 + j], sn = sinb[s * 64 + j];
    float xr = __bfloat162float(q[off]), xi = __bfloat162float(q[off + 1]);
    q[off]     = __float2bfloat16(xr * c - xi * sn);
    q[off + 1] = __float2bfloat16(xr * sn + xi * c);
    xr = __bfloat162float(k[off]); xi = __bfloat162float(k[off + 1]);
    k[off]     = __float2bfloat16(xr * c - xi * sn);
    k[off + 1] = __float2bfloat16(xr * sn + xi * c);
}

// ---------------- GEMM: C[M][N] = A[M][K](bf16) x Bt[N][K](bf16)^T ----------------
// EP 0: store bf16   EP 1: Cf = resid + acc (fp32)   EP 2: Cb = silu(other)*acc (in-place ok)
template <int EP>
__global__ __launch_bounds__(256) void gemm_bt_k(
    const bf16* __restrict__ A, const bf16* __restrict__ Bt,
    bf16* Cb, float* Cf, const float* __restrict__ resid, const bf16* other,
    int M, int N, int K)
{
    __shared__ __align__(16) unsigned short As[128][40];
    __shared__ __align__(16) unsigned short Bs[128][40];
    const int tid = threadIdx.x;
    const int wid = tid >> 6, lane = tid & 63;
    const int lr = lane & 15, lg = lane >> 4;
    const int wm = wid >> 1, wn = wid & 1;
    const int m0 = blockIdx.y * 128, n0 = blockIdx.x * 128;
    const int arow = tid >> 2;            // 0..63
    const int acol = (tid & 3) * 8;       // 0,8,16,24
    f32x4 acc[4][4] = {};

    for (int k0 = 0; k0 < K; k0 += 32) {
        __syncthreads();
        int4 va0 = *(const int4*)(A  + (size_t)(m0 + arow)      * K + k0 + acol);
        int4 va1 = *(const int4*)(A  + (size_t)(m0 + arow + 64) * K + k0 + acol);
        int4 vb0 = *(const int4*)(Bt + (size_t)(n0 + arow)      * K + k0 + acol);
        int4 vb1 = *(const int4*)(Bt + (size_t)(n0 + arow + 64) * K + k0 + acol);
        *(int4*)&As[arow][acol]      = va0;
        *(int4*)&As[arow + 64][acol] = va1;
        *(int4*)&Bs[arow][acol]      = vb0;
        *(int4*)&Bs[arow + 64][acol] = vb1;
        __syncthreads();
        bf16x8 af[4], bfr[4];
#pragma unroll
        for (int i = 0; i < 4; ++i)
            af[i] = *(const bf16x8*)&As[wm * 64 + i * 16 + lr][lg * 8];
#pragma unroll
        for (int j = 0; j < 4; ++j)
            bfr[j] = *(const bf16x8*)&Bs[wn * 64 + j * 16 + lr][lg * 8];
#pragma unroll
        for (int i = 0; i < 4; ++i)
#pragma unroll
            for (int j = 0; j < 4; ++j)
                acc[i][j] = MFMA16(af[i], bfr[j], acc[i][j]);
    }

#pragma unroll
    for (int i = 0; i < 4; ++i)
#pragma unroll
        for (int j = 0; j < 4; ++j) {
            const int row = m0 + wm * 64 + i * 16 + lg * 4;
            const int col = n0 + wn * 64 + j * 16 + lr;
#pragma unroll
            for (int r = 0; r < 4; ++r) {
                const size_t idx = (size_t)(row + r) * N + col;
                const float v = acc[i][j][r];
                if (EP == 0) {
                    Cb[idx] = __float2bfloat16(v);
                } else if (EP == 1) {
                    Cf[idx] = resid[idx] + v;
                } else {
                    const float g = __bfloat162float(other[idx]);
                    const float s = g / (1.0f + __expf(-g));
                    Cb[idx] = __float2bfloat16(s * v);
                }
            }
        }
}

// ---------------- causal flash attention: 1 wave per (head, 16 q-rows) ----------------
__global__ __launch_bounds__(64) void attn_fwd_k(
    const bf16* __restrict__ q, const bf16* __restrict__ k,
    const bf16* __restrict__ vT, bf16* __restrict__ ctx)
{
    const int lane = threadIdx.x;
    const int lr = lane & 15, lg = lane >> 4;
    const int h = blockIdx.y;
    const int q0 = blockIdx.x * 16;
    __shared__ __align__(16) unsigned short P[16][32];

    bf16x8 qf[4];
    const bf16* qrow = q + (size_t)(q0 + lr) * DIM + h * HEAD_DIM;
#pragma unroll
    for (int dt = 0; dt < 4; ++dt)
        qf[dt] = *(const bf16x8*)(qrow + dt * 32 + lg * 8);

    f32x4 o[8] = {};
    float m[4], l[4];
#pragma unroll
    for (int j = 0; j < 4; ++j) { m[j] = -3e38f; l[j] = 0.0f; }
    const float scale = 0.08838834764831845f;   // 1/sqrt(128)
    const int ktiles = (q0 + 16 + 31) >> 5;

    for (int kt = 0; kt < ktiles; ++kt) {
        const int kb = kt * 32;
        f32x4 s0 = {}, s1 = {};
        const bf16* krow0 = k + (size_t)(kb + lr) * DIM + h * HEAD_DIM;
        const bf16* krow1 = krow0 + (size_t)16 * DIM;
#pragma unroll
        for (int dt = 0; dt < 4; ++dt) {
            bf16x8 k0f = *(const bf16x8*)(krow0 + dt * 32 + lg * 8);
            bf16x8 k1f = *(const bf16x8*)(krow1 + dt * 32 + lg * 8);
            s0 = MFMA16(qf[dt], k0f, s0);
            s1 = MFMA16(qf[dt], k1f, s1);
        }
        float p0[4], p1[4], al[4];
#pragma unroll
        for (int j = 0; j < 4; ++j) {
            const int qi = q0 + lg * 4 + j;
            float a0 = s0[j] * scale + ((kb + lr)      > qi ? -1e9f : 0.0f);
            float a1 = s1[j] * scale + ((kb + 16 + lr) > qi ? -1e9f : 0.0f);
            float mx = fmaxf(a0, a1);
            mx = fmaxf(mx, __shfl_xor(mx, 1));
            mx = fmaxf(mx, __shfl_xor(mx, 2));
            mx = fmaxf(mx, __shfl_xor(mx, 4));
            mx = fmaxf(mx, __shfl_xor(mx, 8));
            const float mn = fmaxf(m[j], mx);
            const float a = __expf(m[j] - mn);
            const float e0 = __expf(a0 - mn), e1 = __expf(a1 - mn);
            float rs = e0 + e1;
            rs += __shfl_xor(rs, 1); rs += __shfl_xor(rs, 2);
            rs += __shfl_xor(rs, 4); rs += __shfl_xor(rs, 8);
            l[j] = l[j] * a + rs;
            m[j] = mn;
            al[j] = a;
            p0[j] = e0; p1[j] = e1;
        }
#pragma unroll
        for (int d2 = 0; d2 < 8; ++d2)
#pragma unroll
            for (int j = 0; j < 4; ++j) o[d2][j] *= al[j];
        __syncthreads();
#pragma unroll
        for (int j = 0; j < 4; ++j) {
            P[lg * 4 + j][lr]      = f2bu(p0[j]);
            P[lg * 4 + j][16 + lr] = f2bu(p1[j]);
        }
        __syncthreads();
        const bf16x8 pa = *(const bf16x8*)&P[lr][lg * 8];
#pragma unroll
        for (int d2 = 0; d2 < 8; ++d2) {
            const bf16x8 vf = *(const bf16x8*)(vT + (size_t)(h * HEAD_DIM + d2 * 16 + lr) * SEQ + kb + lg * 8);
            o[d2] = MFMA16(pa, vf, o[d2]);
        }
    }

#pragma unroll
    for (int d2 = 0; d2 < 8; ++d2)
#pragma unroll
        for (int j = 0; j < 4; ++j) {
            const float v = o[d2][j] / l[j];
            const size_t idx = (size_t)(q0 + lg * 4 + j) * DIM + h * HEAD_DIM + d2 * 16 + lr;
            ctx[idx] = __float2bfloat16(v);
        }
}

// ---------------- host ----------------
extern "C" void kernel_launch(void* const* d_in, const int* in_sizes, int n_in,
                              void* d_out, int out_size, void* d_ws, size_t ws_size,
                              hipStream_t stream)
{
    const float* x   = (const float*)d_in[0];
    const float* fc  = (const float*)d_in[1];
    const float* fs  = (const float*)d_in[2];
    // d_in[3] = mask (unused; causal computed analytically)
    const float* wq  = (const float*)d_in[4];
    const float* wk  = (const float*)d_in[5];
    const float* wv  = (const float*)d_in[6];
    const float* wo  = (const float*)d_in[7];
    const float* w1  = (const float*)d_in[8];
    const float* w2  = (const float*)d_in[9];
    const float* w3  = (const float*)d_in[10];
    const float* anw = (const float*)d_in[11];
    const float* fnw = (const float*)d_in[12];
    float* out = (float*)d_out;

    char* p = (char*)d_ws;
    auto alloc = [&](size_t n) { char* r = p; p += (n + 255) & ~(size_t)255; return r; };
    bf16* wT  = (bf16*)alloc((size_t)HID * DIM * 2);   // reused for every weight (max 8192x2048)
    bf16* hn  = (bf16*)alloc((size_t)SEQ * DIM * 2);
    bf16* qb  = (bf16*)alloc((size_t)SEQ * DIM * 2);
    bf16* kb  = (bf16*)alloc((size_t)SEQ * DIM * 2);
    bf16* vb  = (bf16*)alloc((size_t)SEQ * DIM * 2);
    bf16* vt  = (bf16*)alloc((size_t)SEQ * DIM * 2);
    bf16* ctx = (bf16*)alloc((size_t)SEQ * DIM * 2);
    bf16* fn  = (bf16*)alloc((size_t)SEQ * DIM * 2);
    float* h  = (float*)alloc((size_t)SEQ * DIM * 4);
    bf16* g   = (bf16*)alloc((size_t)SEQ * HID * 2);

    const dim3 tb32(32, 8);
    const dim3 g2k(DIM / 32, DIM / 32);          // 2048x2048 transpose grids

    // hn = rmsnorm(x, attn_norm_w)
    rmsnorm_bf16_k<<<SEQ, 256, 0, stream>>>(x, anw, hn);

    // q = hn @ wq ; k = hn @ wk ; v = hn @ wv
    convT_f32_bf16_k<<<g2k, tb32, 0, stream>>>(wq, wT, DIM, DIM);
    gemm_bt_k<0><<<dim3(DIM / 128, SEQ / 128), 256, 0, stream>>>(hn, wT, qb, nullptr, nullptr, nullptr, SEQ, DIM, DIM);
    convT_f32_bf16_k<<<g2k, tb32, 0, stream>>>(wk, wT, DIM, DIM);
    gemm_bt_k<0><<<dim3(DIM / 128, SEQ / 128), 256, 0, stream>>>(hn, wT, kb, nullptr, nullptr, nullptr, SEQ, DIM, DIM);
    convT_f32_bf16_k<<<g2k, tb32, 0, stream>>>(wv, wT, DIM, DIM);
    gemm_bt_k<0><<<dim3(DIM / 128, SEQ / 128), 256, 0, stream>>>(hn, wT, vb, nullptr, nullptr, nullptr, SEQ, DIM, DIM);

    // RoPE(q,k) in-place ; vT for attention
    rope_qk_k<<<(SEQ * 1024) / 256, 256, 0, stream>>>(qb, kb, fc, fs);
    transpose_bf16_k<<<dim3(DIM / 32, SEQ / 32), tb32, 0, stream>>>(vb, vt);

    // attention
    attn_fwd_k<<<dim3(SEQ / 16, N_HEADS), 64, 0, stream>>>(qb, kb, vt, ctx);

    // h = x + ctx @ wo   (fp32)
    convT_f32_bf16_k<<<g2k, tb32, 0, stream>>>(wo, wT, DIM, DIM);
    gemm_bt_k<1><<<dim3(DIM / 128, SEQ / 128), 256, 0, stream>>>(ctx, wT, nullptr, h, x, nullptr, SEQ, DIM, DIM);

    // fn = rmsnorm(h, ffn_norm_w)
    rmsnorm_bf16_k<<<SEQ, 256, 0, stream>>>(h, fnw, fn);

    // g = fn @ w1 ; g = silu(g) * (fn @ w3)
    convT_f32_bf16_k<<<dim3(HID / 32, DIM / 32), tb32, 0, stream>>>(w1, wT, DIM, HID);
    gemm_bt_k<0><<<dim3(HID / 128, SEQ / 128), 256, 0, stream>>>(fn, wT, g, nullptr, nullptr, nullptr, SEQ, HID, DIM);
    convT_f32_bf16_k<<<dim3(HID / 32, DIM / 32), tb32, 0, stream>>>(w3, wT, DIM, HID);
    gemm_bt_k<2><<<dim3(HID / 128, SEQ / 128), 256, 0, stream>>>(fn, wT, g, nullptr, nullptr, g, SEQ, HID, DIM);

    // out = h + g @ w2   (fp32)
    convT_f32_bf16_k<<<dim3(DIM / 32, HID / 32), tb32, 0, stream>>>(w2, wT, HID, DIM);
    gemm_bt_k<1><<<dim3(DIM / 128, SEQ / 128), 256, 0, stream>>>(g, wT, nullptr, out, h, nullptr, SEQ, DIM, HID);
}

// Round 2
// 802.547 us; speedup vs baseline: 1.2630x; 1.2630x over previous
//
#include <hip/hip_runtime.h>
#include <hip/hip_bf16.h>

#define DIM 2048
#define HEAD_DIM 128
#define N_HEADS 16
#define SEQ 2048
#define HID 8192

typedef short bf16x8 __attribute__((ext_vector_type(8)));
typedef float f32x4 __attribute__((ext_vector_type(4)));
using bf16 = __hip_bfloat16;

#define MFMA16(a, b, c) __builtin_amdgcn_mfma_f32_16x16x32_bf16(a, b, c, 0, 0, 0)

__device__ __forceinline__ unsigned short f2bu(float f) {
    union { bf16 b; unsigned short u; } cv;
    cv.b = __float2bfloat16(f);
    return cv.u;
}

// async global -> LDS, 16B per lane (dest must be lane-linear per wave)
__device__ __forceinline__ void gl16(const void* g, void* l) {
    __builtin_amdgcn_global_load_lds(
        (const __attribute__((address_space(1))) unsigned int*)g,
        (__attribute__((address_space(3))) unsigned int*)l, 16, 0, 0);
}

// ---------------- rmsnorm (fp32 in -> bf16 out) ----------------
__global__ __launch_bounds__(256) void rmsnorm_bf16_k(
    const float* __restrict__ x, const float* __restrict__ w, bf16* __restrict__ y)
{
    const int row = blockIdx.x;
    const int tid = threadIdx.x;
    const float* xr = x + (size_t)row * DIM;
    float4 v0 = ((const float4*)xr)[tid];
    float4 v1 = ((const float4*)xr)[tid + 256];
    float ss = v0.x*v0.x + v0.y*v0.y + v0.z*v0.z + v0.w*v0.w
             + v1.x*v1.x + v1.y*v1.y + v1.z*v1.z + v1.w*v1.w;
    for (int o = 32; o > 0; o >>= 1) ss += __shfl_down(ss, o);
    __shared__ float red[4];
    if ((tid & 63) == 0) red[tid >> 6] = ss;
    __syncthreads();
    float tot = red[0] + red[1] + red[2] + red[3];
    float r = rsqrtf(tot * (1.0f / DIM) + 1e-6f);
    float4 w0 = ((const float4*)w)[tid];
    float4 w1 = ((const float4*)w)[tid + 256];
    ushort4 o0, o1;
    o0.x = f2bu(v0.x * r * w0.x); o0.y = f2bu(v0.y * r * w0.y);
    o0.z = f2bu(v0.z * r * w0.z); o0.w = f2bu(v0.w * r * w0.w);
    o1.x = f2bu(v1.x * r * w1.x); o1.y = f2bu(v1.y * r * w1.y);
    o1.z = f2bu(v1.z * r * w1.z); o1.w = f2bu(v1.w * r * w1.w);
    ushort4* yr = (ushort4*)(y + (size_t)row * DIM);
    yr[tid] = o0;
    yr[tid + 256] = o1;
}

// ---------------- fp32 [R][C] -> bf16 [C][R] transpose-convert ----------------
__global__ __launch_bounds__(256) void convT_f32_bf16_k(
    const float* __restrict__ in, bf16* __restrict__ out, int R, int C)
{
    __shared__ float t[32][33];
    const int tx = threadIdx.x, ty = threadIdx.y;
    const int x0 = blockIdx.x * 32, y0 = blockIdx.y * 32;
#pragma unroll
    for (int i = 0; i < 4; ++i)
        t[ty + i * 8][tx] = in[(size_t)(y0 + ty + i * 8) * C + x0 + tx];
    __syncthreads();
#pragma unroll
    for (int i = 0; i < 4; ++i)
        out[(size_t)(x0 + ty + i * 8) * R + y0 + tx] = __float2bfloat16(t[tx][ty + i * 8]);
}

// ---------------- bf16 [2048][2048] transpose ----------------
__global__ __launch_bounds__(256) void transpose_bf16_k(
    const bf16* __restrict__ in, bf16* __restrict__ out)
{
    __shared__ unsigned short t[32][33];
    const int tx = threadIdx.x, ty = threadIdx.y;
    const int x = blockIdx.x * 32 + tx;
    const int y0 = blockIdx.y * 32;
    const unsigned short* inu = (const unsigned short*)in;
    unsigned short* outu = (unsigned short*)out;
#pragma unroll
    for (int i = 0; i < 4; ++i)
        t[ty + i * 8][tx] = inu[(size_t)(y0 + ty + i * 8) * DIM + x];
    __syncthreads();
    const int x2 = blockIdx.y * 32 + tx;
    const int y2 = blockIdx.x * 32;
#pragma unroll
    for (int i = 0; i < 4; ++i)
        outu[(size_t)(y2 + ty + i * 8) * DIM + x2] = t[tx][ty + i * 8];
}

// ---------------- RoPE in-place on bf16 q,k ----------------
__global__ __launch_bounds__(256) void rope_qk_k(
    bf16* __restrict__ q, bf16* __restrict__ k,
    const float* __restrict__ cosb, const float* __restrict__ sinb)
{
    const int gid = blockIdx.x * 256 + threadIdx.x;   // < SEQ * 1024
    const int s = gid >> 10;
    const int p = gid & 1023;
    const int h = p >> 6, j = p & 63;
    const size_t off = (size_t)s * DIM + h * HEAD_DIM + 2 * j;
    const float c = cosb[s * 64 + j], sn = sinb[s * 64 + j];
    float xr = __bfloat162float(q[off]), xi = __bfloat162float(q[off + 1]);
    q[off]     = __float2bfloat16(xr * c - xi * sn);
    q[off + 1] = __float2bfloat16(xr * sn + xi * c);
    xr = __bfloat162float(k[off]); xi = __bfloat162float(k[off + 1]);
    k[off]     = __float2bfloat16(xr * c - xi * sn);
    k[off + 1] = __float2bfloat16(xr * sn + xi * c);
}

// ---------------- GEMM (m97 structure): C[M][N] = A[M][K] x Bt[N][K]^T ----------------
// linear LDS (required by global_load_lds), 2 barriers per K-step
// EP 0: store bf16   EP 1: Cf = resid + acc (fp32)   EP 2: Cb = silu(other)*acc
template <int EP>
__global__ __launch_bounds__(256) void gemm_bt_k(
    const bf16* __restrict__ A, const bf16* __restrict__ Bt,
    bf16* Cb, float* Cf, const float* __restrict__ resid, const bf16* other,
    int M, int N, int K)
{
    __shared__ __align__(16) unsigned short As[128 * 32];
    __shared__ __align__(16) unsigned short Bs[128 * 32];
    const int tid = threadIdx.x;
    const int wid = tid >> 6, lane = tid & 63;
    const int lr = lane & 15, lg = lane >> 4;
    const int wm = wid >> 1, wn = wid & 1;
    const int m0 = blockIdx.y * 128, n0 = blockIdx.x * 128;
    const int s0 = tid, s1 = tid + 256;        // 16B slots: row = s>>2, col8 = s&3
    const int r0 = s0 >> 2, c0 = (s0 & 3) * 8;
    const int r1 = s1 >> 2, c1 = (s1 & 3) * 8;
    f32x4 acc[4][4] = {};

    for (int k0 = 0; k0 < K; k0 += 32) {
        if (k0) __syncthreads();               // WAR: prev reads done
        gl16(A  + (size_t)(m0 + r0) * K + k0 + c0, &As[s0 * 8]);
        gl16(A  + (size_t)(m0 + r1) * K + k0 + c1, &As[s1 * 8]);
        gl16(Bt + (size_t)(n0 + r0) * K + k0 + c0, &Bs[s0 * 8]);
        gl16(Bt + (size_t)(n0 + r1) * K + k0 + c1, &Bs[s1 * 8]);
        __syncthreads();                       // drains vmcnt -> LDS filled
        bf16x8 af[4], bfr[4];
#pragma unroll
        for (int i = 0; i < 4; ++i)
            af[i] = *(const bf16x8*)&As[(wm * 64 + i * 16 + lr) * 32 + lg * 8];
#pragma unroll
        for (int j = 0; j < 4; ++j)
            bfr[j] = *(const bf16x8*)&Bs[(wn * 64 + j * 16 + lr) * 32 + lg * 8];
#pragma unroll
        for (int i = 0; i < 4; ++i)
#pragma unroll
            for (int j = 0; j < 4; ++j)
                acc[i][j] = MFMA16(af[i], bfr[j], acc[i][j]);
    }

#pragma unroll
    for (int i = 0; i < 4; ++i)
#pragma unroll
        for (int j = 0; j < 4; ++j) {
            const int row = m0 + wm * 64 + i * 16 + lg * 4;
            const int col = n0 + wn * 64 + j * 16 + lr;
#pragma unroll
            for (int r = 0; r < 4; ++r) {
                const size_t idx = (size_t)(row + r) * N + col;
                const float v = acc[i][j][r];
                if (EP == 0) {
                    Cb[idx] = __float2bfloat16(v);
                } else if (EP == 1) {
                    Cf[idx] = resid[idx] + v;
                } else {
                    const float g = __bfloat162float(other[idx]);
                    const float s = g / (1.0f + __expf(-g));
                    Cb[idx] = __float2bfloat16(s * v);
                }
            }
        }
}

// ---------------- causal flash attention: 4 waves split the KV range ----------------
// block = (q-tile of 16 rows, head); wave w handles k-tiles w, w+4, w+8, ...
__global__ __launch_bounds__(256) void attn_fwd_k(
    const bf16* __restrict__ q, const bf16* __restrict__ k,
    const bf16* __restrict__ vT, bf16* __restrict__ ctx)
{
    const int tid = threadIdx.x;
    const int w = tid >> 6, lane = tid & 63;
    const int lr = lane & 15, lg = lane >> 4;
    const int h = blockIdx.y;
    const int q0 = blockIdx.x * 16;
    __shared__ __align__(16) unsigned short P[4][16][32];
    __shared__ float Mw[4][16], Lw[4][16];
    __shared__ __align__(16) float Ow[4][16][128];

    bf16x8 qf[4];
    const bf16* qrow = q + (size_t)(q0 + lr) * DIM + h * HEAD_DIM;
#pragma unroll
    for (int dt = 0; dt < 4; ++dt)
        qf[dt] = *(const bf16x8*)(qrow + dt * 32 + lg * 8);

    f32x4 o[8] = {};
    float m[4], l[4];
#pragma unroll
    for (int j = 0; j < 4; ++j) { m[j] = -3e38f; l[j] = 0.0f; }
    const float scale = 0.08838834764831845f;   // 1/sqrt(128)
    const int ktiles = (q0 + 16 + 31) >> 5;     // causal bound

    for (int kt = w; kt < ktiles; kt += 4) {
        const int kb = kt * 32;
        f32x4 s0 = {}, s1 = {};
        const bf16* krow0 = k + (size_t)(kb + lr) * DIM + h * HEAD_DIM;
        const bf16* krow1 = krow0 + (size_t)16 * DIM;
#pragma unroll
        for (int dt = 0; dt < 4; ++dt) {
            bf16x8 k0f = *(const bf16x8*)(krow0 + dt * 32 + lg * 8);
            bf16x8 k1f = *(const bf16x8*)(krow1 + dt * 32 + lg * 8);
            s0 = MFMA16(qf[dt], k0f, s0);
            s1 = MFMA16(qf[dt], k1f, s1);
        }
        float p0[4], p1[4], al[4];
#pragma unroll
        for (int j = 0; j < 4; ++j) {
            const int qi = q0 + lg * 4 + j;
            float a0 = s0[j] * scale + ((kb + lr)      > qi ? -1e9f : 0.0f);
            float a1 = s1[j] * scale + ((kb + 16 + lr) > qi ? -1e9f : 0.0f);
            float mx = fmaxf(a0, a1);
            mx = fmaxf(mx, __shfl_xor(mx, 1));
            mx = fmaxf(mx, __shfl_xor(mx, 2));
            mx = fmaxf(mx, __shfl_xor(mx, 4));
            mx = fmaxf(mx, __shfl_xor(mx, 8));
            const float mn = fmaxf(m[j], mx);
            const float a = __expf(m[j] - mn);
            const float e0 = __expf(a0 - mn), e1 = __expf(a1 - mn);
            float rs = e0 + e1;
            rs += __shfl_xor(rs, 1); rs += __shfl_xor(rs, 2);
            rs += __shfl_xor(rs, 4); rs += __shfl_xor(rs, 8);
            l[j] = l[j] * a + rs;
            m[j] = mn;
            al[j] = a;
            p0[j] = e0; p1[j] = e1;
        }
#pragma unroll
        for (int d2 = 0; d2 < 8; ++d2)
#pragma unroll
            for (int j = 0; j < 4; ++j) o[d2][j] *= al[j];
        // in-wave P transpose through LDS (no barrier: DS ops are in-order per wave)
#pragma unroll
        for (int j = 0; j < 4; ++j) {
            P[w][lg * 4 + j][lr]      = f2bu(p0[j]);
            P[w][lg * 4 + j][16 + lr] = f2bu(p1[j]);
        }
        asm volatile("s_waitcnt lgkmcnt(0)" ::: "memory");
        __builtin_amdgcn_sched_barrier(0);
        const bf16x8 pa = *(const bf16x8*)&P[w][lr][lg * 8];
#pragma unroll
        for (int d2 = 0; d2 < 8; ++d2) {
            const bf16x8 vf = *(const bf16x8*)(vT + (size_t)(h * HEAD_DIM + d2 * 16 + lr) * SEQ + kb + lg * 8);
            o[d2] = MFMA16(pa, vf, o[d2]);
        }
    }

    // publish per-wave partials
#pragma unroll
    for (int j = 0; j < 4; ++j) {
        if (lr == 0) { Mw[w][lg * 4 + j] = m[j]; Lw[w][lg * 4 + j] = l[j]; }
#pragma unroll
        for (int d2 = 0; d2 < 8; ++d2)
            Ow[w][lg * 4 + j][d2 * 16 + lr] = o[d2][j];
    }
    __syncthreads();

    // combine 4 wave-partials: 16 threads per q-row, 8 d each
    {
        const int qq = tid >> 4;
        const int dbase = (tid & 15) * 8;
        float mw0 = Mw[0][qq], mw1 = Mw[1][qq], mw2 = Mw[2][qq], mw3 = Mw[3][qq];
        float mg = fmaxf(fmaxf(mw0, mw1), fmaxf(mw2, mw3));
        float sc[4];
        sc[0] = __expf(mw0 - mg); sc[1] = __expf(mw1 - mg);
        sc[2] = __expf(mw2 - mg); sc[3] = __expf(mw3 - mg);
        float ls = sc[0] * Lw[0][qq] + sc[1] * Lw[1][qq]
                 + sc[2] * Lw[2][qq] + sc[3] * Lw[3][qq];
        const float inv = 1.0f / ls;
        float acc[8] = {};
#pragma unroll
        for (int ww = 0; ww < 4; ++ww)
#pragma unroll
            for (int e = 0; e < 8; ++e)
                acc[e] += sc[ww] * Ow[ww][qq][dbase + e];
        bf16* dst = ctx + (size_t)(q0 + qq) * DIM + h * HEAD_DIM + dbase;
#pragma unroll
        for (int e = 0; e < 8; ++e)
            dst[e] = __float2bfloat16(acc[e] * inv);
    }
}

// ---------------- host ----------------
extern "C" void kernel_launch(void* const* d_in, const int* in_sizes, int n_in,
                              void* d_out, int out_size, void* d_ws, size_t ws_size,
                              hipStream_t stream)
{
    const float* x   = (const float*)d_in[0];
    const float* fc  = (const float*)d_in[1];
    const float* fs  = (const float*)d_in[2];
    // d_in[3] = mask (unused; causal computed analytically)
    const float* wq  = (const float*)d_in[4];
    const float* wk  = (const float*)d_in[5];
    const float* wv  = (const float*)d_in[6];
    const float* wo  = (const float*)d_in[7];
    const float* w1  = (const float*)d_in[8];
    const float* w2  = (const float*)d_in[9];
    const float* w3  = (const float*)d_in[10];
    const float* anw = (const float*)d_in[11];
    const float* fnw = (const float*)d_in[12];
    float* out = (float*)d_out;

    char* p = (char*)d_ws;
    auto alloc = [&](size_t n) { char* r = p; p += (n + 255) & ~(size_t)255; return r; };
    bf16* wT  = (bf16*)alloc((size_t)HID * DIM * 2);   // reused for every weight
    bf16* hn  = (bf16*)alloc((size_t)SEQ * DIM * 2);
    bf16* qb  = (bf16*)alloc((size_t)SEQ * DIM * 2);
    bf16* kb  = (bf16*)alloc((size_t)SEQ * DIM * 2);
    bf16* vb  = (bf16*)alloc((size_t)SEQ * DIM * 2);
    bf16* vt  = (bf16*)alloc((size_t)SEQ * DIM * 2);
    bf16* ctx = (bf16*)alloc((size_t)SEQ * DIM * 2);
    bf16* fn  = (bf16*)alloc((size_t)SEQ * DIM * 2);
    float* h  = (float*)alloc((size_t)SEQ * DIM * 4);
    bf16* g   = (bf16*)alloc((size_t)SEQ * HID * 2);

    const dim3 tb32(32, 8);
    const dim3 g2k(DIM / 32, DIM / 32);

    rmsnorm_bf16_k<<<SEQ, 256, 0, stream>>>(x, anw, hn);

    convT_f32_bf16_k<<<g2k, tb32, 0, stream>>>(wq, wT, DIM, DIM);
    gemm_bt_k<0><<<dim3(DIM / 128, SEQ / 128), 256, 0, stream>>>(hn, wT, qb, nullptr, nullptr, nullptr, SEQ, DIM, DIM);
    convT_f32_bf16_k<<<g2k, tb32, 0, stream>>>(wk, wT, DIM, DIM);
    gemm_bt_k<0><<<dim3(DIM / 128, SEQ / 128), 256, 0, stream>>>(hn, wT, kb, nullptr, nullptr, nullptr, SEQ, DIM, DIM);
    convT_f32_bf16_k<<<g2k, tb32, 0, stream>>>(wv, wT, DIM, DIM);
    gemm_bt_k<0><<<dim3(DIM / 128, SEQ / 128), 256, 0, stream>>>(hn, wT, vb, nullptr, nullptr, nullptr, SEQ, DIM, DIM);

    rope_qk_k<<<(SEQ * 1024) / 256, 256, 0, stream>>>(qb, kb, fc, fs);
    transpose_bf16_k<<<dim3(DIM / 32, SEQ / 32), tb32, 0, stream>>>(vb, vt);

    attn_fwd_k<<<dim3(SEQ / 16, N_HEADS), 256, 0, stream>>>(qb, kb, vt, ctx);

    convT_f32_bf16_k<<<g2k, tb32, 0, stream>>>(wo, wT, DIM, DIM);
    gemm_bt_k<1><<<dim3(DIM / 128, SEQ / 128), 256, 0, stream>>>(ctx, wT, nullptr, h, x, nullptr, SEQ, DIM, DIM);

    rmsnorm_bf16_k<<<SEQ, 256, 0, stream>>>(h, fnw, fn);

    convT_f32_bf16_k<<<dim3(HID / 32, DIM / 32), tb32, 0, stream>>>(w1, wT, DIM, HID);
    gemm_bt_k<0><<<dim3(HID / 128, SEQ / 128), 256, 0, stream>>>(fn, wT, g, nullptr, nullptr, nullptr, SEQ, HID, DIM);
    convT_f32_bf16_k<<<dim3(HID / 32, DIM / 32), tb32, 0, stream>>>(w3, wT, DIM, HID);
    gemm_bt_k<2><<<dim3(HID / 128, SEQ / 128), 256, 0, stream>>>(fn, wT, g, nullptr, nullptr, g, SEQ, HID, DIM);

    convT_f32_bf16_k<<<dim3(DIM / 32, HID / 32), tb32, 0, stream>>>(w2, wT, HID, DIM);
    gemm_bt_k<1><<<dim3(DIM / 128, SEQ / 128), 256, 0, stream>>>(g, wT, nullptr, out, h, nullptr, SEQ, DIM, HID);
}

// Round 3
// 742.960 us; speedup vs baseline: 1.3643x; 1.0802x over previous
//
#include <hip/hip_runtime.h>
#include <hip/hip_bf16.h>

#define DIM 2048
#define HEAD_DIM 128
#define N_HEADS 16
#define SEQ 2048
#define HID 8192
#define SQKV 6144   // row stride of fused qkv activation

typedef short bf16x8 __attribute__((ext_vector_type(8)));
typedef float f32x4 __attribute__((ext_vector_type(4)));
using bf16 = __hip_bfloat16;

#define MFMA16(a, b, c) __builtin_amdgcn_mfma_f32_16x16x32_bf16(a, b, c, 0, 0, 0)

__device__ __forceinline__ unsigned short f2bu(float f) {
    union { bf16 b; unsigned short u; } cv;
    cv.b = __float2bfloat16(f);
    return cv.u;
}

// async global -> LDS, 16B per lane (dest must be lane-linear per wave)
__device__ __forceinline__ void gl16(const void* g, void* l) {
    __builtin_amdgcn_global_load_lds(
        (const __attribute__((address_space(1))) unsigned int*)g,
        (__attribute__((address_space(3))) unsigned int*)l, 16, 0, 0);
}

// ---------------- rmsnorm (fp32 in -> bf16 out) ----------------
__global__ __launch_bounds__(256) void rmsnorm_bf16_k(
    const float* __restrict__ x, const float* __restrict__ w, bf16* __restrict__ y)
{
    const int row = blockIdx.x;
    const int tid = threadIdx.x;
    const float* xr = x + (size_t)row * DIM;
    float4 v0 = ((const float4*)xr)[tid];
    float4 v1 = ((const float4*)xr)[tid + 256];
    float ss = v0.x*v0.x + v0.y*v0.y + v0.z*v0.z + v0.w*v0.w
             + v1.x*v1.x + v1.y*v1.y + v1.z*v1.z + v1.w*v1.w;
    for (int o = 32; o > 0; o >>= 1) ss += __shfl_down(ss, o);
    __shared__ float red[4];
    if ((tid & 63) == 0) red[tid >> 6] = ss;
    __syncthreads();
    float tot = red[0] + red[1] + red[2] + red[3];
    float r = rsqrtf(tot * (1.0f / DIM) + 1e-6f);
    float4 w0 = ((const float4*)w)[tid];
    float4 w1 = ((const float4*)w)[tid + 256];
    ushort4 o0, o1;
    o0.x = f2bu(v0.x * r * w0.x); o0.y = f2bu(v0.y * r * w0.y);
    o0.z = f2bu(v0.z * r * w0.z); o0.w = f2bu(v0.w * r * w0.w);
    o1.x = f2bu(v1.x * r * w1.x); o1.y = f2bu(v1.y * r * w1.y);
    o1.z = f2bu(v1.z * r * w1.z); o1.w = f2bu(v1.w * r * w1.w);
    ushort4* yr = (ushort4*)(y + (size_t)row * DIM);
    yr[tid] = o0;
    yr[tid + 256] = o1;
}

// ---------------- fp32 [R][C] -> bf16 [C][R] transpose-convert ----------------
__global__ __launch_bounds__(256) void convT_f32_bf16_k(
    const float* __restrict__ in, bf16* __restrict__ out, int R, int C)
{
    __shared__ float t[32][33];
    const int tx = threadIdx.x, ty = threadIdx.y;
    const int x0 = blockIdx.x * 32, y0 = blockIdx.y * 32;
#pragma unroll
    for (int i = 0; i < 4; ++i)
        t[ty + i * 8][tx] = in[(size_t)(y0 + ty + i * 8) * C + x0 + tx];
    __syncthreads();
#pragma unroll
    for (int i = 0; i < 4; ++i)
        out[(size_t)(x0 + ty + i * 8) * R + y0 + tx] = __float2bfloat16(t[tx][ty + i * 8]);
}

// 3 square weights -> one [3*DIM][DIM] B^T buffer (z selects wq/wk/wv)
__global__ __launch_bounds__(256) void convT3_f32_bf16_k(
    const float* __restrict__ wq, const float* __restrict__ wk,
    const float* __restrict__ wv, bf16* __restrict__ out)
{
    const int z = blockIdx.z;
    const float* in = z == 0 ? wq : (z == 1 ? wk : wv);
    bf16* o = out + (size_t)z * DIM * DIM;
    __shared__ float t[32][33];
    const int tx = threadIdx.x, ty = threadIdx.y;
    const int x0 = blockIdx.x * 32, y0 = blockIdx.y * 32;
#pragma unroll
    for (int i = 0; i < 4; ++i)
        t[ty + i * 8][tx] = in[(size_t)(y0 + ty + i * 8) * DIM + x0 + tx];
    __syncthreads();
#pragma unroll
    for (int i = 0; i < 4; ++i)
        o[(size_t)(x0 + ty + i * 8) * DIM + y0 + tx] = __float2bfloat16(t[tx][ty + i * 8]);
}

// ---------------- bf16 transpose with src stride (vt[d][s] = in[s][d]) ----------------
__global__ __launch_bounds__(256) void transpose_bf16_k(
    const bf16* __restrict__ in, int istride, bf16* __restrict__ out)
{
    __shared__ unsigned short t[32][33];
    const int tx = threadIdx.x, ty = threadIdx.y;
    const int x = blockIdx.x * 32 + tx;       // d
    const int y0 = blockIdx.y * 32;           // s
    const unsigned short* inu = (const unsigned short*)in;
    unsigned short* outu = (unsigned short*)out;
#pragma unroll
    for (int i = 0; i < 4; ++i)
        t[ty + i * 8][tx] = inu[(size_t)(y0 + ty + i * 8) * istride + x];
    __syncthreads();
    const int x2 = blockIdx.y * 32 + tx;
    const int y2 = blockIdx.x * 32;
#pragma unroll
    for (int i = 0; i < 4; ++i)
        outu[(size_t)(y2 + ty + i * 8) * SEQ + x2] = t[tx][ty + i * 8];
}

// ---------------- RoPE in-place on strided bf16 q,k ----------------
__global__ __launch_bounds__(256) void rope_qk_k(
    bf16* __restrict__ q, bf16* __restrict__ k,
    const float* __restrict__ cosb, const float* __restrict__ sinb)
{
    const int gid = blockIdx.x * 256 + threadIdx.x;   // < SEQ * 1024
    const int s = gid >> 10;
    const int p = gid & 1023;
    const int h = p >> 6, j = p & 63;
    const size_t off = (size_t)s * SQKV + h * HEAD_DIM + 2 * j;
    const float c = cosb[s * 64 + j], sn = sinb[s * 64 + j];
    float xr = __bfloat162float(q[off]), xi = __bfloat162float(q[off + 1]);
    q[off]     = __float2bfloat16(xr * c - xi * sn);
    q[off + 1] = __float2bfloat16(xr * sn + xi * c);
    xr = __bfloat162float(k[off]); xi = __bfloat162float(k[off + 1]);
    k[off]     = __float2bfloat16(xr * c - xi * sn);
    k[off + 1] = __float2bfloat16(xr * sn + xi * c);
}

// ---------------- GEMM (m97 structure): C[M][N] = A[M][K] x Bt[N][K]^T ----------------
// EP 0: store bf16   EP 1: Cf = resid + acc (fp32)   EP 2: Cb = silu(other)*acc
template <int EP>
__global__ __launch_bounds__(256) void gemm_bt_k(
    const bf16* __restrict__ A, const bf16* __restrict__ Bt,
    bf16* Cb, float* Cf, const float* __restrict__ resid, const bf16* other,
    int M, int N, int K)
{
    __shared__ __align__(16) unsigned short As[128 * 32];
    __shared__ __align__(16) unsigned short Bs[128 * 32];
    const int tid = threadIdx.x;
    const int wid = tid >> 6, lane = tid & 63;
    const int lr = lane & 15, lg = lane >> 4;
    const int wm = wid >> 1, wn = wid & 1;
    const int m0 = blockIdx.y * 128, n0 = blockIdx.x * 128;
    const int s0 = tid, s1 = tid + 256;
    const int r0 = s0 >> 2, c0 = (s0 & 3) * 8;
    const int r1 = s1 >> 2, c1 = (s1 & 3) * 8;
    f32x4 acc[4][4] = {};

    for (int k0 = 0; k0 < K; k0 += 32) {
        if (k0) __syncthreads();
        gl16(A  + (size_t)(m0 + r0) * K + k0 + c0, &As[s0 * 8]);
        gl16(A  + (size_t)(m0 + r1) * K + k0 + c1, &As[s1 * 8]);
        gl16(Bt + (size_t)(n0 + r0) * K + k0 + c0, &Bs[s0 * 8]);
        gl16(Bt + (size_t)(n0 + r1) * K + k0 + c1, &Bs[s1 * 8]);
        __syncthreads();
        bf16x8 af[4], bfr[4];
#pragma unroll
        for (int i = 0; i < 4; ++i)
            af[i] = *(const bf16x8*)&As[(wm * 64 + i * 16 + lr) * 32 + lg * 8];
#pragma unroll
        for (int j = 0; j < 4; ++j)
            bfr[j] = *(const bf16x8*)&Bs[(wn * 64 + j * 16 + lr) * 32 + lg * 8];
#pragma unroll
        for (int i = 0; i < 4; ++i)
#pragma unroll
            for (int j = 0; j < 4; ++j)
                acc[i][j] = MFMA16(af[i], bfr[j], acc[i][j]);
    }

#pragma unroll
    for (int i = 0; i < 4; ++i)
#pragma unroll
        for (int j = 0; j < 4; ++j) {
            const int row = m0 + wm * 64 + i * 16 + lg * 4;
            const int col = n0 + wn * 64 + j * 16 + lr;
#pragma unroll
            for (int r = 0; r < 4; ++r) {
                const size_t idx = (size_t)(row + r) * N + col;
                const float v = acc[i][j][r];
                if (EP == 0) {
                    Cb[idx] = __float2bfloat16(v);
                } else if (EP == 1) {
                    Cf[idx] = resid[idx] + v;
                } else {
                    const float g = __bfloat162float(other[idx]);
                    const float s = g / (1.0f + __expf(-g));
                    Cb[idx] = __float2bfloat16(s * v);
                }
            }
        }
}

// ---------------- causal flash attention: 4 waves split KV range, KVBLK=64 ----------------
// q,k live inside fused qkv (row stride SQKV); vT is [DIM][SEQ]
__global__ __launch_bounds__(256) void attn_fwd_k(
    const bf16* __restrict__ qkv, const bf16* __restrict__ vT, bf16* __restrict__ ctx)
{
    const int tid = threadIdx.x;
    const int w = tid >> 6, lane = tid & 63;
    const int lr = lane & 15, lg = lane >> 4;
    const int h = blockIdx.y;
    const int q0 = blockIdx.x * 16;
    __shared__ __align__(16) unsigned short P[4][16][64];
    __shared__ float Mw[4][16], Lw[4][16];
    __shared__ __align__(16) unsigned short Ow[4][16][128];   // bf16 partials

    bf16x8 qf[4];
    const bf16* qrow = qkv + (size_t)(q0 + lr) * SQKV + h * HEAD_DIM;
#pragma unroll
    for (int dt = 0; dt < 4; ++dt)
        qf[dt] = *(const bf16x8*)(qrow + dt * 32 + lg * 8);

    f32x4 o[8] = {};
    float m[4], l[4];
#pragma unroll
    for (int j = 0; j < 4; ++j) { m[j] = -3e38f; l[j] = 0.0f; }
    const float scale = 0.08838834764831845f;   // 1/sqrt(128)
    const int nt = (q0 + 16 + 63) >> 6;         // causal bound in 64-row tiles

    const bf16* kbase = qkv + DIM + h * HEAD_DIM;   // k columns of qkv

    for (int kt = w; kt < nt; kt += 4) {
        const int kb = kt * 64;
        f32x4 s[4] = {};
        __builtin_amdgcn_s_setprio(1);
#pragma unroll
        for (int ss = 0; ss < 4; ++ss) {
            const bf16* krow = kbase + (size_t)(kb + ss * 16 + lr) * SQKV;
#pragma unroll
            for (int dt = 0; dt < 4; ++dt) {
                bf16x8 kf = *(const bf16x8*)(krow + dt * 32 + lg * 8);
                s[ss] = MFMA16(qf[dt], kf, s[ss]);
            }
        }
        __builtin_amdgcn_s_setprio(0);
        float al[4];
#pragma unroll
        for (int j = 0; j < 4; ++j) {
            const int qi = q0 + lg * 4 + j;
            float a[4];
#pragma unroll
            for (int ss = 0; ss < 4; ++ss)
                a[ss] = s[ss][j] * scale + ((kb + ss * 16 + lr) > qi ? -1e9f : 0.0f);
            float mx = fmaxf(fmaxf(a[0], a[1]), fmaxf(a[2], a[3]));
            mx = fmaxf(mx, __shfl_xor(mx, 1));
            mx = fmaxf(mx, __shfl_xor(mx, 2));
            mx = fmaxf(mx, __shfl_xor(mx, 4));
            mx = fmaxf(mx, __shfl_xor(mx, 8));
            const float mn = fmaxf(m[j], mx);
            const float asc = __expf(m[j] - mn);
            float e0 = __expf(a[0] - mn), e1 = __expf(a[1] - mn);
            float e2 = __expf(a[2] - mn), e3 = __expf(a[3] - mn);
            float rs = (e0 + e1) + (e2 + e3);
            rs += __shfl_xor(rs, 1); rs += __shfl_xor(rs, 2);
            rs += __shfl_xor(rs, 4); rs += __shfl_xor(rs, 8);
            l[j] = l[j] * asc + rs;
            m[j] = mn;
            al[j] = asc;
            P[w][lg * 4 + j][lr]      = f2bu(e0);
            P[w][lg * 4 + j][16 + lr] = f2bu(e1);
            P[w][lg * 4 + j][32 + lr] = f2bu(e2);
            P[w][lg * 4 + j][48 + lr] = f2bu(e3);
        }
#pragma unroll
        for (int d2 = 0; d2 < 8; ++d2)
#pragma unroll
            for (int j = 0; j < 4; ++j) o[d2][j] *= al[j];
        asm volatile("s_waitcnt lgkmcnt(0)" ::: "memory");
        __builtin_amdgcn_sched_barrier(0);
        bf16x8 pa0 = *(const bf16x8*)&P[w][lr][lg * 8];
        bf16x8 pa1 = *(const bf16x8*)&P[w][lr][32 + lg * 8];
        __builtin_amdgcn_s_setprio(1);
#pragma unroll
        for (int d2 = 0; d2 < 8; ++d2) {
            const bf16* vrow = vT + (size_t)(h * HEAD_DIM + d2 * 16 + lr) * SEQ + kb;
            bf16x8 vf0 = *(const bf16x8*)(vrow + lg * 8);
            bf16x8 vf1 = *(const bf16x8*)(vrow + 32 + lg * 8);
            o[d2] = MFMA16(pa0, vf0, o[d2]);
            o[d2] = MFMA16(pa1, vf1, o[d2]);
        }
        __builtin_amdgcn_s_setprio(0);
    }

    // publish per-wave partials (bf16)
#pragma unroll
    for (int j = 0; j < 4; ++j) {
        if (lr == 0) { Mw[w][lg * 4 + j] = m[j]; Lw[w][lg * 4 + j] = l[j]; }
#pragma unroll
        for (int d2 = 0; d2 < 8; ++d2)
            Ow[w][lg * 4 + j][d2 * 16 + lr] = f2bu(o[d2][j]);
    }
    __syncthreads();

    // combine 4 wave-partials: 16 threads per q-row, 8 d each
    {
        const int qq = tid >> 4;
        const int dbase = (tid & 15) * 8;
        float mw0 = Mw[0][qq], mw1 = Mw[1][qq], mw2 = Mw[2][qq], mw3 = Mw[3][qq];
        float mg = fmaxf(fmaxf(mw0, mw1), fmaxf(mw2, mw3));
        float sc0 = __expf(mw0 - mg), sc1 = __expf(mw1 - mg);
        float sc2 = __expf(mw2 - mg), sc3 = __expf(mw3 - mg);
        float ls = sc0 * Lw[0][qq] + sc1 * Lw[1][qq]
                 + sc2 * Lw[2][qq] + sc3 * Lw[3][qq];
        const float inv = 1.0f / ls;
        bf16x8 p0 = *(const bf16x8*)&Ow[0][qq][dbase];
        bf16x8 p1 = *(const bf16x8*)&Ow[1][qq][dbase];
        bf16x8 p2 = *(const bf16x8*)&Ow[2][qq][dbase];
        bf16x8 p3 = *(const bf16x8*)&Ow[3][qq][dbase];
        bf16* dst = ctx + (size_t)(q0 + qq) * DIM + h * HEAD_DIM + dbase;
#pragma unroll
        for (int e = 0; e < 8; ++e) {
            union { unsigned short u; bf16 b; } c0, c1, c2, c3;
            c0.u = (unsigned short)p0[e]; c1.u = (unsigned short)p1[e];
            c2.u = (unsigned short)p2[e]; c3.u = (unsigned short)p3[e];
            float acc = sc0 * __bfloat162float(c0.b) + sc1 * __bfloat162float(c1.b)
                      + sc2 * __bfloat162float(c2.b) + sc3 * __bfloat162float(c3.b);
            dst[e] = __float2bfloat16(acc * inv);
        }
    }
}

// ---------------- host ----------------
extern "C" void kernel_launch(void* const* d_in, const int* in_sizes, int n_in,
                              void* d_out, int out_size, void* d_ws, size_t ws_size,
                              hipStream_t stream)
{
    const float* x   = (const float*)d_in[0];
    const float* fc  = (const float*)d_in[1];
    const float* fs  = (const float*)d_in[2];
    // d_in[3] = mask (unused; causal computed analytically)
    const float* wq  = (const float*)d_in[4];
    const float* wk  = (const float*)d_in[5];
    const float* wv  = (const float*)d_in[6];
    const float* wo  = (const float*)d_in[7];
    const float* w1  = (const float*)d_in[8];
    const float* w2  = (const float*)d_in[9];
    const float* w3  = (const float*)d_in[10];
    const float* anw = (const float*)d_in[11];
    const float* fnw = (const float*)d_in[12];
    float* out = (float*)d_out;

    char* p = (char*)d_ws;
    auto alloc = [&](size_t n) { char* r = p; p += (n + 255) & ~(size_t)255; return r; };
    bf16* wT  = (bf16*)alloc((size_t)HID * DIM * 2);   // 32MB, reused per weight group
    bf16* hn  = (bf16*)alloc((size_t)SEQ * DIM * 2);
    bf16* qkv = (bf16*)alloc((size_t)SEQ * SQKV * 2);  // fused q|k|v, stride 6144
    bf16* vt  = (bf16*)alloc((size_t)SEQ * DIM * 2);
    bf16* ctx = (bf16*)alloc((size_t)SEQ * DIM * 2);
    bf16* fn  = (bf16*)alloc((size_t)SEQ * DIM * 2);
    float* h  = (float*)alloc((size_t)SEQ * DIM * 4);
    bf16* g   = (bf16*)alloc((size_t)SEQ * HID * 2);

    const dim3 tb32(32, 8);

    rmsnorm_bf16_k<<<SEQ, 256, 0, stream>>>(x, anw, hn);

    // fused QKV: wT[0:6144][2048] = [wq^T; wk^T; wv^T], one GEMM -> qkv[2048][6144]
    convT3_f32_bf16_k<<<dim3(DIM / 32, DIM / 32, 3), tb32, 0, stream>>>(wq, wk, wv, wT);
    gemm_bt_k<0><<<dim3(SQKV / 128, SEQ / 128), 256, 0, stream>>>(hn, wT, qkv, nullptr, nullptr, nullptr, SEQ, SQKV, DIM);

    rope_qk_k<<<(SEQ * 1024) / 256, 256, 0, stream>>>(qkv, qkv + DIM, fc, fs);
    transpose_bf16_k<<<dim3(DIM / 32, SEQ / 32), tb32, 0, stream>>>(qkv + 2 * DIM, SQKV, vt);

    attn_fwd_k<<<dim3(SEQ / 16, N_HEADS), 256, 0, stream>>>(qkv, vt, ctx);

    convT_f32_bf16_k<<<dim3(DIM / 32, DIM / 32), tb32, 0, stream>>>(wo, wT, DIM, DIM);
    gemm_bt_k<1><<<dim3(DIM / 128, SEQ / 128), 256, 0, stream>>>(ctx, wT, nullptr, h, x, nullptr, SEQ, DIM, DIM);

    rmsnorm_bf16_k<<<SEQ, 256, 0, stream>>>(h, fnw, fn);

    convT_f32_bf16_k<<<dim3(HID / 32, DIM / 32), tb32, 0, stream>>>(w1, wT, DIM, HID);
    gemm_bt_k<0><<<dim3(HID / 128, SEQ / 128), 256, 0, stream>>>(fn, wT, g, nullptr, nullptr, nullptr, SEQ, HID, DIM);
    convT_f32_bf16_k<<<dim3(HID / 32, DIM / 32), tb32, 0, stream>>>(w3, wT, DIM, HID);
    gemm_bt_k<2><<<dim3(HID / 128, SEQ / 128), 256, 0, stream>>>(fn, wT, g, nullptr, nullptr, g, SEQ, HID, DIM);

    convT_f32_bf16_k<<<dim3(DIM / 32, HID / 32), tb32, 0, stream>>>(w2, wT, HID, DIM);
    gemm_bt_k<1><<<dim3(DIM / 128, SEQ / 128), 256, 0, stream>>>(g, wT, nullptr, out, h, nullptr, SEQ, DIM, HID);
}

// Round 4
// 649.095 us; speedup vs baseline: 1.5616x; 1.1446x over previous
//
#include <hip/hip_runtime.h>
#include <hip/hip_bf16.h>

#define DIM 2048
#define HEAD_DIM 128
#define N_HEADS 16
#define SEQ 2048
#define HID 8192
#define SQKV 6144   // row stride of fused qkv activation

typedef short bf16x8 __attribute__((ext_vector_type(8)));
typedef float f32x4 __attribute__((ext_vector_type(4)));
using bf16 = __hip_bfloat16;

#define MFMA16(a, b, c) __builtin_amdgcn_mfma_f32_16x16x32_bf16(a, b, c, 0, 0, 0)

__device__ __forceinline__ unsigned short f2bu(float f) {
    union { bf16 b; unsigned short u; } cv;
    cv.b = __float2bfloat16(f);
    return cv.u;
}

// async global -> LDS, 16B per lane (dest must be lane-linear per wave)
__device__ __forceinline__ void gl16(const void* g, void* l) {
    __builtin_amdgcn_global_load_lds(
        (const __attribute__((address_space(1))) unsigned int*)g,
        (__attribute__((address_space(3))) unsigned int*)l, 16, 0, 0);
}

// ---------------- rmsnorm (fp32 in -> bf16 out) ----------------
__global__ __launch_bounds__(256) void rmsnorm_bf16_k(
    const float* __restrict__ x, const float* __restrict__ w, bf16* __restrict__ y)
{
    const int row = blockIdx.x;
    const int tid = threadIdx.x;
    const float* xr = x + (size_t)row * DIM;
    float4 v0 = ((const float4*)xr)[tid];
    float4 v1 = ((const float4*)xr)[tid + 256];
    float ss = v0.x*v0.x + v0.y*v0.y + v0.z*v0.z + v0.w*v0.w
             + v1.x*v1.x + v1.y*v1.y + v1.z*v1.z + v1.w*v1.w;
    for (int o = 32; o > 0; o >>= 1) ss += __shfl_down(ss, o);
    __shared__ float red[4];
    if ((tid & 63) == 0) red[tid >> 6] = ss;
    __syncthreads();
    float tot = red[0] + red[1] + red[2] + red[3];
    float r = rsqrtf(tot * (1.0f / DIM) + 1e-6f);
    float4 w0 = ((const float4*)w)[tid];
    float4 w1 = ((const float4*)w)[tid + 256];
    ushort4 o0, o1;
    o0.x = f2bu(v0.x * r * w0.x); o0.y = f2bu(v0.y * r * w0.y);
    o0.z = f2bu(v0.z * r * w0.z); o0.w = f2bu(v0.w * r * w0.w);
    o1.x = f2bu(v1.x * r * w1.x); o1.y = f2bu(v1.y * r * w1.y);
    o1.z = f2bu(v1.z * r * w1.z); o1.w = f2bu(v1.w * r * w1.w);
    ushort4* yr = (ushort4*)(y + (size_t)row * DIM);
    yr[tid] = o0;
    yr[tid + 256] = o1;
}

// ---------------- fp32 [R][C] -> bf16 [C][R] transpose-convert ----------------
__global__ __launch_bounds__(256) void convT_f32_bf16_k(
    const float* __restrict__ in, bf16* __restrict__ out, int R, int C)
{
    __shared__ float t[32][33];
    const int tx = threadIdx.x, ty = threadIdx.y;
    const int x0 = blockIdx.x * 32, y0 = blockIdx.y * 32;
#pragma unroll
    for (int i = 0; i < 4; ++i)
        t[ty + i * 8][tx] = in[(size_t)(y0 + ty + i * 8) * C + x0 + tx];
    __syncthreads();
#pragma unroll
    for (int i = 0; i < 4; ++i)
        out[(size_t)(x0 + ty + i * 8) * R + y0 + tx] = __float2bfloat16(t[tx][ty + i * 8]);
}

// 3 square weights -> one [3*DIM][DIM] B^T buffer (z selects wq/wk/wv)
__global__ __launch_bounds__(256) void convT3_f32_bf16_k(
    const float* __restrict__ wq, const float* __restrict__ wk,
    const float* __restrict__ wv, bf16* __restrict__ out)
{
    const int z = blockIdx.z;
    const float* in = z == 0 ? wq : (z == 1 ? wk : wv);
    bf16* o = out + (size_t)z * DIM * DIM;
    __shared__ float t[32][33];
    const int tx = threadIdx.x, ty = threadIdx.y;
    const int x0 = blockIdx.x * 32, y0 = blockIdx.y * 32;
#pragma unroll
    for (int i = 0; i < 4; ++i)
        t[ty + i * 8][tx] = in[(size_t)(y0 + ty + i * 8) * DIM + x0 + tx];
    __syncthreads();
#pragma unroll
    for (int i = 0; i < 4; ++i)
        o[(size_t)(x0 + ty + i * 8) * DIM + y0 + tx] = __float2bfloat16(t[tx][ty + i * 8]);
}

// ---------------- bf16 transpose with src stride (vt[d][s] = in[s][d]) ----------------
__global__ __launch_bounds__(256) void transpose_bf16_k(
    const bf16* __restrict__ in, int istride, bf16* __restrict__ out)
{
    __shared__ unsigned short t[32][33];
    const int tx = threadIdx.x, ty = threadIdx.y;
    const int x = blockIdx.x * 32 + tx;       // d
    const int y0 = blockIdx.y * 32;           // s
    const unsigned short* inu = (const unsigned short*)in;
    unsigned short* outu = (unsigned short*)out;
#pragma unroll
    for (int i = 0; i < 4; ++i)
        t[ty + i * 8][tx] = inu[(size_t)(y0 + ty + i * 8) * istride + x];
    __syncthreads();
    const int x2 = blockIdx.y * 32 + tx;
    const int y2 = blockIdx.x * 32;
#pragma unroll
    for (int i = 0; i < 4; ++i)
        outu[(size_t)(y2 + ty + i * 8) * SEQ + x2] = t[tx][ty + i * 8];
}

// ---------------- RoPE in-place on strided bf16 q,k ----------------
__global__ __launch_bounds__(256) void rope_qk_k(
    bf16* __restrict__ q, bf16* __restrict__ k,
    const float* __restrict__ cosb, const float* __restrict__ sinb)
{
    const int gid = blockIdx.x * 256 + threadIdx.x;   // < SEQ * 1024
    const int s = gid >> 10;
    const int p = gid & 1023;
    const int h = p >> 6, j = p & 63;
    const size_t off = (size_t)s * SQKV + h * HEAD_DIM + 2 * j;
    const float c = cosb[s * 64 + j], sn = sinb[s * 64 + j];
    float xr = __bfloat162float(q[off]), xi = __bfloat162float(q[off + 1]);
    q[off]     = __float2bfloat16(xr * c - xi * sn);
    q[off + 1] = __float2bfloat16(xr * sn + xi * c);
    xr = __bfloat162float(k[off]); xi = __bfloat162float(k[off + 1]);
    k[off]     = __float2bfloat16(xr * c - xi * sn);
    k[off + 1] = __float2bfloat16(xr * sn + xi * c);
}

// ---------------- GEMM (m97 structure): C[M][N] = A[M][K] x Bt[N][K]^T ----------------
// EP 0: store bf16   EP 1: Cf = resid + acc (fp32)   EP 2: Cb = silu(other)*acc
template <int EP>
__global__ __launch_bounds__(256) void gemm_bt_k(
    const bf16* __restrict__ A, const bf16* __restrict__ Bt,
    bf16* Cb, float* Cf, const float* __restrict__ resid, const bf16* other,
    int M, int N, int K)
{
    __shared__ __align__(16) unsigned short As[128 * 32];
    __shared__ __align__(16) unsigned short Bs[128 * 32];
    const int tid = threadIdx.x;
    const int wid = tid >> 6, lane = tid & 63;
    const int lr = lane & 15, lg = lane >> 4;
    const int wm = wid >> 1, wn = wid & 1;
    const int m0 = blockIdx.y * 128, n0 = blockIdx.x * 128;
    const int s0 = tid, s1 = tid + 256;
    const int r0 = s0 >> 2, c0 = (s0 & 3) * 8;
    const int r1 = s1 >> 2, c1 = (s1 & 3) * 8;
    f32x4 acc[4][4] = {};

    for (int k0 = 0; k0 < K; k0 += 32) {
        if (k0) __syncthreads();
        gl16(A  + (size_t)(m0 + r0) * K + k0 + c0, &As[s0 * 8]);
        gl16(A  + (size_t)(m0 + r1) * K + k0 + c1, &As[s1 * 8]);
        gl16(Bt + (size_t)(n0 + r0) * K + k0 + c0, &Bs[s0 * 8]);
        gl16(Bt + (size_t)(n0 + r1) * K + k0 + c1, &Bs[s1 * 8]);
        __syncthreads();
        bf16x8 af[4], bfr[4];
#pragma unroll
        for (int i = 0; i < 4; ++i)
            af[i] = *(const bf16x8*)&As[(wm * 64 + i * 16 + lr) * 32 + lg * 8];
#pragma unroll
        for (int j = 0; j < 4; ++j)
            bfr[j] = *(const bf16x8*)&Bs[(wn * 64 + j * 16 + lr) * 32 + lg * 8];
#pragma unroll
        for (int i = 0; i < 4; ++i)
#pragma unroll
            for (int j = 0; j < 4; ++j)
                acc[i][j] = MFMA16(af[i], bfr[j], acc[i][j]);
    }

#pragma unroll
    for (int i = 0; i < 4; ++i)
#pragma unroll
        for (int j = 0; j < 4; ++j) {
            const int row = m0 + wm * 64 + i * 16 + lg * 4;
            const int col = n0 + wn * 64 + j * 16 + lr;
#pragma unroll
            for (int r = 0; r < 4; ++r) {
                const size_t idx = (size_t)(row + r) * N + col;
                const float v = acc[i][j][r];
                if (EP == 0) {
                    Cb[idx] = __float2bfloat16(v);
                } else if (EP == 1) {
                    Cf[idx] = resid[idx] + v;
                } else {
                    const float g = __bfloat162float(other[idx]);
                    const float s = g / (1.0f + __expf(-g));
                    Cb[idx] = __float2bfloat16(s * v);
                }
            }
        }
}

// ---------------- causal flash attention: QBLK=64 (4 waves x 16 rows), shared KV tiles ----------------
// K,V staged in LDS via global_load_lds, double-buffered, XOR-swizzled (swizzle on global src).
__global__ __launch_bounds__(256) void attn_fwd_k(
    const bf16* __restrict__ qkv, const bf16* __restrict__ vT, bf16* __restrict__ ctx)
{
    const int tid = threadIdx.x;
    const int w = tid >> 6, lane = tid & 63;
    const int lr = lane & 15, lg = lane >> 4;
    const int h = blockIdx.y;
    // pair heavy+light blocks so co-resident pairs sum to constant work
    const int qidx = (blockIdx.y < 8) ? blockIdx.x : (31 - blockIdx.x);
    const int q0b = qidx * 64;
    const int nt = qidx + 1;                  // 64-row KV tiles (causal)

    __shared__ __align__(16) unsigned short Kt[2][64 * 128];   // [row][d], swizzled
    __shared__ __align__(16) unsigned short Vt[2][128 * 64];   // [d][s], swizzled
    __shared__ __align__(16) unsigned short Pp[4][16 * 64];    // per-wave P, swizzled

    const char* kbase = (const char*)(qkv + DIM + h * HEAD_DIM);
    const char* vbase = (const char*)(vT + (size_t)h * HEAD_DIM * SEQ);

    // staging geometry (per thread, per call c)
    const int krow_c = tid >> 4;              // + c*16
    const int kcolB  = (tid & 15) * 16;
    const int vrow_c = tid >> 3;              // + c*32
    const int vcolB  = (tid & 7) * 16;

    auto stage = [&](int buf, int kb) {
#pragma unroll
        for (int c = 0; c < 4; ++c) {
            const int r = c * 16 + krow_c;
            gl16(kbase + (size_t)(kb + r) * (SQKV * 2) + (kcolB ^ ((r & 7) << 4)),
                 &Kt[buf][c * 2048 + tid * 8]);
        }
#pragma unroll
        for (int c = 0; c < 4; ++c) {
            const int r = c * 32 + vrow_c;
            gl16(vbase + (size_t)r * (SEQ * 2) + kb * 2 + (vcolB ^ ((r & 7) << 4)),
                 &Vt[buf][c * 2048 + tid * 8]);
        }
    };

    // q fragments (16 rows per wave)
    bf16x8 qf[4];
    const bf16* qrow = qkv + (size_t)(q0b + w * 16 + lr) * SQKV + h * HEAD_DIM;
#pragma unroll
    for (int dt = 0; dt < 4; ++dt)
        qf[dt] = *(const bf16x8*)(qrow + dt * 32 + lg * 8);

    f32x4 o[8] = {};
    float m[4], l[4];
#pragma unroll
    for (int j = 0; j < 4; ++j) { m[j] = -3e38f; l[j] = 0.0f; }
    const float scale = 0.08838834764831845f;   // 1/sqrt(128)

    stage(0, 0);
    __syncthreads();                            // drains vmcnt -> tile 0 ready

    int cur = 0;
    for (int t = 0; t < nt; ++t) {
        const int kb = t * 64;
        if (t + 1 < nt) stage(cur ^ 1, kb + 64);   // prefetch overlaps compute

        // ---- QK^T from LDS ----
        f32x4 s[4] = {};
        __builtin_amdgcn_s_setprio(1);
#pragma unroll
        for (int ss = 0; ss < 4; ++ss) {
            const int r = ss * 16 + lr;
            const int sw = (r & 7) << 3;
#pragma unroll
            for (int dt = 0; dt < 4; ++dt) {
                bf16x8 kf = *(const bf16x8*)&Kt[cur][r * 128 + ((dt * 32 + lg * 8) ^ sw)];
                s[ss] = MFMA16(qf[dt], kf, s[ss]);
            }
        }
        __builtin_amdgcn_s_setprio(0);

        // ---- online softmax (16-lane groups) ----
        float al[4];
#pragma unroll
        for (int j = 0; j < 4; ++j) {
            const int qi = q0b + w * 16 + lg * 4 + j;
            const int prow = lg * 4 + j;
            const int psw = (prow & 7) << 3;
            float a[4];
#pragma unroll
            for (int ss = 0; ss < 4; ++ss)
                a[ss] = s[ss][j] * scale + ((kb + ss * 16 + lr) > qi ? -1e9f : 0.0f);
            float mx = fmaxf(fmaxf(a[0], a[1]), fmaxf(a[2], a[3]));
            mx = fmaxf(mx, __shfl_xor(mx, 1));
            mx = fmaxf(mx, __shfl_xor(mx, 2));
            mx = fmaxf(mx, __shfl_xor(mx, 4));
            mx = fmaxf(mx, __shfl_xor(mx, 8));
            const float mn = fmaxf(m[j], mx);
            const float asc = __expf(m[j] - mn);
            float e0 = __expf(a[0] - mn), e1 = __expf(a[1] - mn);
            float e2 = __expf(a[2] - mn), e3 = __expf(a[3] - mn);
            float rs = (e0 + e1) + (e2 + e3);
            rs += __shfl_xor(rs, 1); rs += __shfl_xor(rs, 2);
            rs += __shfl_xor(rs, 4); rs += __shfl_xor(rs, 8);
            l[j] = l[j] * asc + rs;
            m[j] = mn;
            al[j] = asc;
            Pp[w][prow * 64 + ((lr)      ^ psw)] = f2bu(e0);
            Pp[w][prow * 64 + ((16 + lr) ^ psw)] = f2bu(e1);
            Pp[w][prow * 64 + ((32 + lr) ^ psw)] = f2bu(e2);
            Pp[w][prow * 64 + ((48 + lr) ^ psw)] = f2bu(e3);
        }
#pragma unroll
        for (int d2 = 0; d2 < 8; ++d2)
#pragma unroll
            for (int j = 0; j < 4; ++j) o[d2][j] *= al[j];

        asm volatile("s_waitcnt lgkmcnt(0)" ::: "memory");
        __builtin_amdgcn_sched_barrier(0);
        const int asw = (lr & 7) << 3;
        bf16x8 pa0 = *(const bf16x8*)&Pp[w][lr * 64 + ((lg * 8)      ^ asw)];
        bf16x8 pa1 = *(const bf16x8*)&Pp[w][lr * 64 + ((32 + lg * 8) ^ asw)];

        // ---- PV from LDS ----
        __builtin_amdgcn_s_setprio(1);
#pragma unroll
        for (int d2 = 0; d2 < 8; ++d2) {
            const int rv = d2 * 16 + lr;
            const int vsw = (rv & 7) << 3;
            bf16x8 vf0 = *(const bf16x8*)&Vt[cur][rv * 64 + ((lg * 8)      ^ vsw)];
            bf16x8 vf1 = *(const bf16x8*)&Vt[cur][rv * 64 + ((32 + lg * 8) ^ vsw)];
            o[d2] = MFMA16(pa0, vf0, o[d2]);
            o[d2] = MFMA16(pa1, vf1, o[d2]);
        }
        __builtin_amdgcn_s_setprio(0);

        __syncthreads();    // drains vmcnt (prefetch landed) + all waves done with buffers
        cur ^= 1;
    }

    // ---- per-wave epilogue ----
#pragma unroll
    for (int j = 0; j < 4; ++j) {
        const float inv = 1.0f / l[j];
        bf16* dst = ctx + (size_t)(q0b + w * 16 + lg * 4 + j) * DIM + h * HEAD_DIM + lr;
#pragma unroll
        for (int d2 = 0; d2 < 8; ++d2)
            dst[d2 * 16] = __float2bfloat16(o[d2][j] * inv);
    }
}

// ---------------- host ----------------
extern "C" void kernel_launch(void* const* d_in, const int* in_sizes, int n_in,
                              void* d_out, int out_size, void* d_ws, size_t ws_size,
                              hipStream_t stream)
{
    const float* x   = (const float*)d_in[0];
    const float* fc  = (const float*)d_in[1];
    const float* fs  = (const float*)d_in[2];
    // d_in[3] = mask (unused; causal computed analytically)
    const float* wq  = (const float*)d_in[4];
    const float* wk  = (const float*)d_in[5];
    const float* wv  = (const float*)d_in[6];
    const float* wo  = (const float*)d_in[7];
    const float* w1  = (const float*)d_in[8];
    const float* w2  = (const float*)d_in[9];
    const float* w3  = (const float*)d_in[10];
    const float* anw = (const float*)d_in[11];
    const float* fnw = (const float*)d_in[12];
    float* out = (float*)d_out;

    char* p = (char*)d_ws;
    auto alloc = [&](size_t n) { char* r = p; p += (n + 255) & ~(size_t)255; return r; };
    bf16* wT  = (bf16*)alloc((size_t)HID * DIM * 2);   // 32MB, reused per weight group
    bf16* hn  = (bf16*)alloc((size_t)SEQ * DIM * 2);
    bf16* qkv = (bf16*)alloc((size_t)SEQ * SQKV * 2);  // fused q|k|v, stride 6144
    bf16* vt  = (bf16*)alloc((size_t)SEQ * DIM * 2);
    bf16* ctx = (bf16*)alloc((size_t)SEQ * DIM * 2);
    bf16* fn  = (bf16*)alloc((size_t)SEQ * DIM * 2);
    float* h  = (float*)alloc((size_t)SEQ * DIM * 4);
    bf16* g   = (bf16*)alloc((size_t)SEQ * HID * 2);

    const dim3 tb32(32, 8);

    rmsnorm_bf16_k<<<SEQ, 256, 0, stream>>>(x, anw, hn);

    // fused QKV: wT[0:6144][2048] = [wq^T; wk^T; wv^T], one GEMM -> qkv[2048][6144]
    convT3_f32_bf16_k<<<dim3(DIM / 32, DIM / 32, 3), tb32, 0, stream>>>(wq, wk, wv, wT);
    gemm_bt_k<0><<<dim3(SQKV / 128, SEQ / 128), 256, 0, stream>>>(hn, wT, qkv, nullptr, nullptr, nullptr, SEQ, SQKV, DIM);

    rope_qk_k<<<(SEQ * 1024) / 256, 256, 0, stream>>>(qkv, qkv + DIM, fc, fs);
    transpose_bf16_k<<<dim3(DIM / 32, SEQ / 32), tb32, 0, stream>>>(qkv + 2 * DIM, SQKV, vt);

    attn_fwd_k<<<dim3(SEQ / 64, N_HEADS), 256, 0, stream>>>(qkv, vt, ctx);

    convT_f32_bf16_k<<<dim3(DIM / 32, DIM / 32), tb32, 0, stream>>>(wo, wT, DIM, DIM);
    gemm_bt_k<1><<<dim3(DIM / 128, SEQ / 128), 256, 0, stream>>>(ctx, wT, nullptr, h, x, nullptr, SEQ, DIM, DIM);

    rmsnorm_bf16_k<<<SEQ, 256, 0, stream>>>(h, fnw, fn);

    convT_f32_bf16_k<<<dim3(HID / 32, DIM / 32), tb32, 0, stream>>>(w1, wT, DIM, HID);
    gemm_bt_k<0><<<dim3(HID / 128, SEQ / 128), 256, 0, stream>>>(fn, wT, g, nullptr, nullptr, nullptr, SEQ, HID, DIM);
    convT_f32_bf16_k<<<dim3(HID / 32, DIM / 32), tb32, 0, stream>>>(w3, wT, DIM, HID);
    gemm_bt_k<2><<<dim3(HID / 128, SEQ / 128), 256, 0, stream>>>(fn, wT, g, nullptr, nullptr, g, SEQ, HID, DIM);

    convT_f32_bf16_k<<<dim3(DIM / 32, HID / 32), tb32, 0, stream>>>(w2, wT, HID, DIM);
    gemm_bt_k<1><<<dim3(DIM / 128, SEQ / 128), 256, 0, stream>>>(g, wT, nullptr, out, h, nullptr, SEQ, DIM, HID);
}

// Round 5
// 634.675 us; speedup vs baseline: 1.5971x; 1.0227x over previous
//
#include <hip/hip_runtime.h>
#include <hip/hip_bf16.h>

#define DIM 2048
#define HEAD_DIM 128
#define N_HEADS 16
#define SEQ 2048
#define HID 8192
#define SQKV 6144   // row stride of fused qkv activation

typedef short bf16x8 __attribute__((ext_vector_type(8)));
typedef float f32x4 __attribute__((ext_vector_type(4)));
using bf16 = __hip_bfloat16;

#define MFMA16(a, b, c) __builtin_amdgcn_mfma_f32_16x16x32_bf16(a, b, c, 0, 0, 0)

__device__ __forceinline__ unsigned short f2bu(float f) {
    union { bf16 b; unsigned short u; } cv;
    cv.b = __float2bfloat16(f);
    return cv.u;
}

// async global -> LDS, 16B per lane (dest must be lane-linear per wave)
__device__ __forceinline__ void gl16(const void* g, void* l) {
    __builtin_amdgcn_global_load_lds(
        (const __attribute__((address_space(1))) unsigned int*)g,
        (__attribute__((address_space(3))) unsigned int*)l, 16, 0, 0);
}

// ---------------- rmsnorm (fp32 in -> bf16 out) ----------------
__global__ __launch_bounds__(256) void rmsnorm_bf16_k(
    const float* __restrict__ x, const float* __restrict__ w, bf16* __restrict__ y)
{
    const int row = blockIdx.x;
    const int tid = threadIdx.x;
    const float* xr = x + (size_t)row * DIM;
    float4 v0 = ((const float4*)xr)[tid];
    float4 v1 = ((const float4*)xr)[tid + 256];
    float ss = v0.x*v0.x + v0.y*v0.y + v0.z*v0.z + v0.w*v0.w
             + v1.x*v1.x + v1.y*v1.y + v1.z*v1.z + v1.w*v1.w;
    for (int o = 32; o > 0; o >>= 1) ss += __shfl_down(ss, o);
    __shared__ float red[4];
    if ((tid & 63) == 0) red[tid >> 6] = ss;
    __syncthreads();
    float tot = red[0] + red[1] + red[2] + red[3];
    float r = rsqrtf(tot * (1.0f / DIM) + 1e-6f);
    float4 w0 = ((const float4*)w)[tid];
    float4 w1 = ((const float4*)w)[tid + 256];
    ushort4 o0, o1;
    o0.x = f2bu(v0.x * r * w0.x); o0.y = f2bu(v0.y * r * w0.y);
    o0.z = f2bu(v0.z * r * w0.z); o0.w = f2bu(v0.w * r * w0.w);
    o1.x = f2bu(v1.x * r * w1.x); o1.y = f2bu(v1.y * r * w1.y);
    o1.z = f2bu(v1.z * r * w1.z); o1.w = f2bu(v1.w * r * w1.w);
    ushort4* yr = (ushort4*)(y + (size_t)row * DIM);
    yr[tid] = o0;
    yr[tid + 256] = o1;
}

// ---------------- fp32 [R][C] -> bf16 [C][R] transpose-convert ----------------
__global__ __launch_bounds__(256) void convT_f32_bf16_k(
    const float* __restrict__ in, bf16* __restrict__ out, int R, int C)
{
    __shared__ float t[32][33];
    const int tx = threadIdx.x, ty = threadIdx.y;
    const int x0 = blockIdx.x * 32, y0 = blockIdx.y * 32;
#pragma unroll
    for (int i = 0; i < 4; ++i)
        t[ty + i * 8][tx] = in[(size_t)(y0 + ty + i * 8) * C + x0 + tx];
    __syncthreads();
#pragma unroll
    for (int i = 0; i < 4; ++i)
        out[(size_t)(x0 + ty + i * 8) * R + y0 + tx] = __float2bfloat16(t[tx][ty + i * 8]);
}

// 3 square weights -> one [3*DIM][DIM] B^T buffer (z selects wq/wk/wv)
__global__ __launch_bounds__(256) void convT3_f32_bf16_k(
    const float* __restrict__ wq, const float* __restrict__ wk,
    const float* __restrict__ wv, bf16* __restrict__ out)
{
    const int z = blockIdx.z;
    const float* in = z == 0 ? wq : (z == 1 ? wk : wv);
    bf16* o = out + (size_t)z * DIM * DIM;
    __shared__ float t[32][33];
    const int tx = threadIdx.x, ty = threadIdx.y;
    const int x0 = blockIdx.x * 32, y0 = blockIdx.y * 32;
#pragma unroll
    for (int i = 0; i < 4; ++i)
        t[ty + i * 8][tx] = in[(size_t)(y0 + ty + i * 8) * DIM + x0 + tx];
    __syncthreads();
#pragma unroll
    for (int i = 0; i < 4; ++i)
        o[(size_t)(x0 + ty + i * 8) * DIM + y0 + tx] = __float2bfloat16(t[tx][ty + i * 8]);
}

// ---------------- bf16 transpose with src stride (vt[d][s] = in[s][d]) ----------------
__global__ __launch_bounds__(256) void transpose_bf16_k(
    const bf16* __restrict__ in, int istride, bf16* __restrict__ out)
{
    __shared__ unsigned short t[32][33];
    const int tx = threadIdx.x, ty = threadIdx.y;
    const int x = blockIdx.x * 32 + tx;       // d
    const int y0 = blockIdx.y * 32;           // s
    const unsigned short* inu = (const unsigned short*)in;
    unsigned short* outu = (unsigned short*)out;
#pragma unroll
    for (int i = 0; i < 4; ++i)
        t[ty + i * 8][tx] = inu[(size_t)(y0 + ty + i * 8) * istride + x];
    __syncthreads();
    const int x2 = blockIdx.y * 32 + tx;
    const int y2 = blockIdx.x * 32;
#pragma unroll
    for (int i = 0; i < 4; ++i)
        outu[(size_t)(y2 + ty + i * 8) * SEQ + x2] = t[tx][ty + i * 8];
}

// ---------------- RoPE in-place on strided bf16 q,k ----------------
__global__ __launch_bounds__(256) void rope_qk_k(
    bf16* __restrict__ q, bf16* __restrict__ k,
    const float* __restrict__ cosb, const float* __restrict__ sinb)
{
    const int gid = blockIdx.x * 256 + threadIdx.x;   // < SEQ * 1024
    const int s = gid >> 10;
    const int p = gid & 1023;
    const int h = p >> 6, j = p & 63;
    const size_t off = (size_t)s * SQKV + h * HEAD_DIM + 2 * j;
    const float c = cosb[s * 64 + j], sn = sinb[s * 64 + j];
    float xr = __bfloat162float(q[off]), xi = __bfloat162float(q[off + 1]);
    q[off]     = __float2bfloat16(xr * c - xi * sn);
    q[off + 1] = __float2bfloat16(xr * sn + xi * c);
    xr = __bfloat162float(k[off]); xi = __bfloat162float(k[off + 1]);
    k[off]     = __float2bfloat16(xr * c - xi * sn);
    k[off + 1] = __float2bfloat16(xr * sn + xi * c);
}

// ---------------- GEMM (m97 structure, 128x128): kept for small-grid shapes ----------------
// EP 1: Cf = resid + acc (fp32)
template <int EP>
__global__ __launch_bounds__(256) void gemm_bt_k(
    const bf16* __restrict__ A, const bf16* __restrict__ Bt,
    bf16* Cb, float* Cf, const float* __restrict__ resid, const bf16* other,
    int M, int N, int K)
{
    __shared__ __align__(16) unsigned short As[128 * 32];
    __shared__ __align__(16) unsigned short Bs[128 * 32];
    const int tid = threadIdx.x;
    const int wid = tid >> 6, lane = tid & 63;
    const int lr = lane & 15, lg = lane >> 4;
    const int wm = wid >> 1, wn = wid & 1;
    const int m0 = blockIdx.y * 128, n0 = blockIdx.x * 128;
    const int s0 = tid, s1 = tid + 256;
    const int r0 = s0 >> 2, c0 = (s0 & 3) * 8;
    const int r1 = s1 >> 2, c1 = (s1 & 3) * 8;
    f32x4 acc[4][4] = {};

    for (int k0 = 0; k0 < K; k0 += 32) {
        if (k0) __syncthreads();
        gl16(A  + (size_t)(m0 + r0) * K + k0 + c0, &As[s0 * 8]);
        gl16(A  + (size_t)(m0 + r1) * K + k0 + c1, &As[s1 * 8]);
        gl16(Bt + (size_t)(n0 + r0) * K + k0 + c0, &Bs[s0 * 8]);
        gl16(Bt + (size_t)(n0 + r1) * K + k0 + c1, &Bs[s1 * 8]);
        __syncthreads();
        bf16x8 af[4], bfr[4];
#pragma unroll
        for (int i = 0; i < 4; ++i)
            af[i] = *(const bf16x8*)&As[(wm * 64 + i * 16 + lr) * 32 + lg * 8];
#pragma unroll
        for (int j = 0; j < 4; ++j)
            bfr[j] = *(const bf16x8*)&Bs[(wn * 64 + j * 16 + lr) * 32 + lg * 8];
#pragma unroll
        for (int i = 0; i < 4; ++i)
#pragma unroll
            for (int j = 0; j < 4; ++j)
                acc[i][j] = MFMA16(af[i], bfr[j], acc[i][j]);
    }

#pragma unroll
    for (int i = 0; i < 4; ++i)
#pragma unroll
        for (int j = 0; j < 4; ++j) {
            const int row = m0 + wm * 64 + i * 16 + lg * 4;
            const int col = n0 + wn * 64 + j * 16 + lr;
#pragma unroll
            for (int r = 0; r < 4; ++r) {
                const size_t idx = (size_t)(row + r) * N + col;
                const float v = acc[i][j][r];
                if (EP == 0) {
                    Cb[idx] = __float2bfloat16(v);
                } else if (EP == 1) {
                    Cf[idx] = resid[idx] + v;
                } else {
                    const float g = __bfloat162float(other[idx]);
                    const float s = g / (1.0f + __expf(-g));
                    Cb[idx] = __float2bfloat16(s * v);
                }
            }
        }
}

// ---------------- 256x256 8-phase GEMM (T2+T3+T4+T5), BK=64, 512 threads ----------------
// EP 0: store bf16    EP 2: Cb = silu(other)*acc  (in-place ok)
// LDS (dynamic 128KB): A halves [buf][2][128*64], B halves at +64KB.
// st_16x32 swizzle byte^=((byte>>9)&1)<<5 applied on ds_read offset AND inverse
// on the global source of global_load_lds (rule #21: linear dest + pre-swz src).
template <int EP>
__global__ __launch_bounds__(512, 2) void gemm256_k(
    const bf16* __restrict__ A, const bf16* __restrict__ Bt,
    bf16* __restrict__ Cb, const bf16* other, int M, int N, int K, int gx)
{
    extern __shared__ char smem[];
    const int t512 = threadIdx.x;
    const int w = t512 >> 6, lane = t512 & 63;
    const int lr = lane & 15, lg = lane >> 4;
    const int wm = w >> 2, wn = w & 3;           // 2 x 4 wave grid
    const int bofs = (wn & 1) * 64;              // B row offset inside its half

    // XCD-bijective block swizzle (m204)
    const int nwg = gridDim.x;
    const int q8 = nwg >> 3, r8 = nwg & 7;
    const int xcd = blockIdx.x & 7, seq = blockIdx.x >> 3;
    const int wgid = (xcd < r8 ? xcd * (q8 + 1) : r8 * (q8 + 1) + (xcd - r8) * q8) + seq;
    const int m0 = (wgid / gx) * 256, n0 = (wgid % gx) * 256;

    const int nt = K >> 6;                        // 64-wide K tiles (nt >= 2 for all uses)

    // stage one 128x64 half-tile (16KB): 2 gl16 per thread, source pre-swizzled
    auto stage_half = [&](int buf, int kt, int isB, int hs) {
        const int k0 = kt << 6;
        char* base = smem + (isB ? 65536 : 0) + (buf * 2 + hs) * 16384;
#pragma unroll
        for (int c = 0; c < 2; ++c) {
            const int s = (c * 512 + t512) * 16;            // linear byte slot
            const int p = s ^ (((s >> 9) & 1) << 5);        // nominal position
            const int row = p >> 7;
            const int colE = (p & 127) >> 1;
            if (isB)
                gl16(Bt + (size_t)(n0 + hs * 128 + row) * K + k0 + colE, base + s);
            else
                gl16(A  + (size_t)(m0 + hs * 128 + row) * K + k0 + colE, base + s);
        }
    };

    f32x4 acc[8][4] = {};
    bf16x8 bfr[4][2];

    // prologue: tile0 -> buf0, tile1 -> buf1 (16 loads/thread)
    stage_half(0, 0, 0, 0); stage_half(0, 0, 0, 1);
    stage_half(0, 0, 1, 0); stage_half(0, 0, 1, 1);
    stage_half(1, 1, 0, 0); stage_half(1, 1, 0, 1);
    stage_half(1, 1, 1, 0); stage_half(1, 1, 1, 1);

    for (int t = 0; t < nt; ++t) {
        const int cur = t & 1;
        // tile t+1's 8 loads are the only ones newer than tile t's -> vmcnt(8)
        if (t + 1 < nt) { asm volatile("s_waitcnt vmcnt(8)" ::: "memory"); }
        else            { asm volatile("s_waitcnt vmcnt(0)" ::: "memory"); }
        __builtin_amdgcn_sched_barrier(0);
        __builtin_amdgcn_s_barrier();

        const char* Am = smem + (cur * 2 + wm) * 16384;
        const char* Bm = smem + 65536 + (cur * 2 + (wn >> 1)) * 16384;
        const bool pf = (t + 2 < nt);

#define LDA_(mf, ks, dst) { int off = ((mf) * 16 + lr) * 128 + (ks) * 64 + lg * 16; \
        off ^= ((off >> 9) & 1) << 5; dst = *(const bf16x8*)(Am + off); }
#define LDB_(nf, ks, dst) { int off = (bofs + (nf) * 16 + lr) * 128 + (ks) * 64 + lg * 16; \
        off ^= ((off >> 9) & 1) << 5; dst = *(const bf16x8*)(Bm + off); }
#define MFMA_PH(mf0) { \
        asm volatile("s_waitcnt lgkmcnt(0)" ::: "memory"); \
        __builtin_amdgcn_sched_barrier(0); \
        __builtin_amdgcn_s_setprio(1); \
        _Pragma("unroll") \
        for (int nf = 0; nf < 4; ++nf) { \
            acc[(mf0)][nf]     = MFMA16(a0, bfr[nf][0], acc[(mf0)][nf]); \
            acc[(mf0)][nf]     = MFMA16(a1, bfr[nf][1], acc[(mf0)][nf]); \
            acc[(mf0) + 1][nf] = MFMA16(a2, bfr[nf][0], acc[(mf0) + 1][nf]); \
            acc[(mf0) + 1][nf] = MFMA16(a3, bfr[nf][1], acc[(mf0) + 1][nf]); \
        } \
        __builtin_amdgcn_s_setprio(0); }

        bf16x8 a0, a1, a2, a3;
        // ---- phase 0: A mf0-1 + all B, 16 MFMA ----
        LDA_(0, 0, a0) LDA_(0, 1, a1) LDA_(1, 0, a2) LDA_(1, 1, a3)
#pragma unroll
        for (int nf = 0; nf < 4; ++nf) { LDB_(nf, 0, bfr[nf][0]) LDB_(nf, 1, bfr[nf][1]) }
        MFMA_PH(0)
        __builtin_amdgcn_s_barrier();            // B half0 readers done
        if (pf) stage_half(cur, t + 2, 1, 0);    // stage B half0 of tile t+2

        // ---- phase 1 ----
        LDA_(2, 0, a0) LDA_(2, 1, a1) LDA_(3, 0, a2) LDA_(3, 1, a3)
        MFMA_PH(2)
        __builtin_amdgcn_s_barrier();            // B half1 readers done
        if (pf) stage_half(cur, t + 2, 1, 1);    // stage B half1

        // ---- phase 2 ----
        LDA_(4, 0, a0) LDA_(4, 1, a1) LDA_(5, 0, a2) LDA_(5, 1, a3)
        MFMA_PH(4)

        // ---- phase 3 ----
        LDA_(6, 0, a0) LDA_(6, 1, a1) LDA_(7, 0, a2) LDA_(7, 1, a3)
        MFMA_PH(6)
        __builtin_amdgcn_s_barrier();            // all A reads of this tile done
        if (pf) { stage_half(cur, t + 2, 0, 0); stage_half(cur, t + 2, 0, 1); }
#undef LDA_
#undef LDB_
#undef MFMA_PH
    }

    // ---- epilogue ----
#pragma unroll
    for (int mf = 0; mf < 8; ++mf)
#pragma unroll
        for (int nf = 0; nf < 4; ++nf) {
            const int row = m0 + wm * 128 + mf * 16 + lg * 4;
            const int col = n0 + wn * 64 + nf * 16 + lr;
#pragma unroll
            for (int r = 0; r < 4; ++r) {
                const size_t idx = (size_t)(row + r) * N + col;
                const float v = acc[mf][nf][r];
                if (EP == 0) {
                    Cb[idx] = __float2bfloat16(v);
                } else {
                    const float gg = __bfloat162float(other[idx]);
                    const float sg = gg / (1.0f + __expf(-gg));
                    Cb[idx] = __float2bfloat16(sg * v);
                }
            }
        }
}

// ---------------- causal flash attention: QBLK=64 (4 waves x 16 rows), shared KV tiles ----------------
__global__ __launch_bounds__(256) void attn_fwd_k(
    const bf16* __restrict__ qkv, const bf16* __restrict__ vT, bf16* __restrict__ ctx)
{
    const int tid = threadIdx.x;
    const int w = tid >> 6, lane = tid & 63;
    const int lr = lane & 15, lg = lane >> 4;
    const int h = blockIdx.y;
    const int qidx = (blockIdx.y < 8) ? blockIdx.x : (31 - blockIdx.x);
    const int q0b = qidx * 64;
    const int nt = qidx + 1;                  // 64-row KV tiles (causal)

    __shared__ __align__(16) unsigned short Kt[2][64 * 128];
    __shared__ __align__(16) unsigned short Vt[2][128 * 64];
    __shared__ __align__(16) unsigned short Pp[4][16 * 64];

    const char* kbase = (const char*)(qkv + DIM + h * HEAD_DIM);
    const char* vbase = (const char*)(vT + (size_t)h * HEAD_DIM * SEQ);

    const int krow_c = tid >> 4;
    const int kcolB  = (tid & 15) * 16;
    const int vrow_c = tid >> 3;
    const int vcolB  = (tid & 7) * 16;

    auto stage = [&](int buf, int kb) {
#pragma unroll
        for (int c = 0; c < 4; ++c) {
            const int r = c * 16 + krow_c;
            gl16(kbase + (size_t)(kb + r) * (SQKV * 2) + (kcolB ^ ((r & 7) << 4)),
                 &Kt[buf][c * 2048 + tid * 8]);
        }
#pragma unroll
        for (int c = 0; c < 4; ++c) {
            const int r = c * 32 + vrow_c;
            gl16(vbase + (size_t)r * (SEQ * 2) + kb * 2 + (vcolB ^ ((r & 7) << 4)),
                 &Vt[buf][c * 2048 + tid * 8]);
        }
    };

    bf16x8 qf[4];
    const bf16* qrow = qkv + (size_t)(q0b + w * 16 + lr) * SQKV + h * HEAD_DIM;
#pragma unroll
    for (int dt = 0; dt < 4; ++dt)
        qf[dt] = *(const bf16x8*)(qrow + dt * 32 + lg * 8);

    f32x4 o[8] = {};
    float m[4], l[4];
#pragma unroll
    for (int j = 0; j < 4; ++j) { m[j] = -3e38f; l[j] = 0.0f; }
    const float scale = 0.08838834764831845f;

    stage(0, 0);
    __syncthreads();

    int cur = 0;
    for (int t = 0; t < nt; ++t) {
        const int kb = t * 64;
        if (t + 1 < nt) stage(cur ^ 1, kb + 64);

        f32x4 s[4] = {};
        __builtin_amdgcn_s_setprio(1);
#pragma unroll
        for (int ss = 0; ss < 4; ++ss) {
            const int r = ss * 16 + lr;
            const int sw = (r & 7) << 3;
#pragma unroll
            for (int dt = 0; dt < 4; ++dt) {
                bf16x8 kf = *(const bf16x8*)&Kt[cur][r * 128 + ((dt * 32 + lg * 8) ^ sw)];
                s[ss] = MFMA16(qf[dt], kf, s[ss]);
            }
        }
        __builtin_amdgcn_s_setprio(0);

        float al[4];
#pragma unroll
        for (int j = 0; j < 4; ++j) {
            const int qi = q0b + w * 16 + lg * 4 + j;
            const int prow = lg * 4 + j;
            const int psw = (prow & 7) << 3;
            float a[4];
#pragma unroll
            for (int ss = 0; ss < 4; ++ss)
                a[ss] = s[ss][j] * scale + ((kb + ss * 16 + lr) > qi ? -1e9f : 0.0f);
            float mx = fmaxf(fmaxf(a[0], a[1]), fmaxf(a[2], a[3]));
            mx = fmaxf(mx, __shfl_xor(mx, 1));
            mx = fmaxf(mx, __shfl_xor(mx, 2));
            mx = fmaxf(mx, __shfl_xor(mx, 4));
            mx = fmaxf(mx, __shfl_xor(mx, 8));
            const float mn = fmaxf(m[j], mx);
            const float asc = __expf(m[j] - mn);
            float e0 = __expf(a[0] - mn), e1 = __expf(a[1] - mn);
            float e2 = __expf(a[2] - mn), e3 = __expf(a[3] - mn);
            float rs = (e0 + e1) + (e2 + e3);
            rs += __shfl_xor(rs, 1); rs += __shfl_xor(rs, 2);
            rs += __shfl_xor(rs, 4); rs += __shfl_xor(rs, 8);
            l[j] = l[j] * asc + rs;
            m[j] = mn;
            al[j] = asc;
            Pp[w][prow * 64 + ((lr)      ^ psw)] = f2bu(e0);
            Pp[w][prow * 64 + ((16 + lr) ^ psw)] = f2bu(e1);
            Pp[w][prow * 64 + ((32 + lr) ^ psw)] = f2bu(e2);
            Pp[w][prow * 64 + ((48 + lr) ^ psw)] = f2bu(e3);
        }
#pragma unroll
        for (int d2 = 0; d2 < 8; ++d2)
#pragma unroll
            for (int j = 0; j < 4; ++j) o[d2][j] *= al[j];

        asm volatile("s_waitcnt lgkmcnt(0)" ::: "memory");
        __builtin_amdgcn_sched_barrier(0);
        const int asw = (lr & 7) << 3;
        bf16x8 pa0 = *(const bf16x8*)&Pp[w][lr * 64 + ((lg * 8)      ^ asw)];
        bf16x8 pa1 = *(const bf16x8*)&Pp[w][lr * 64 + ((32 + lg * 8) ^ asw)];

        __builtin_amdgcn_s_setprio(1);
#pragma unroll
        for (int d2 = 0; d2 < 8; ++d2) {
            const int rv = d2 * 16 + lr;
            const int vsw = (rv & 7) << 3;
            bf16x8 vf0 = *(const bf16x8*)&Vt[cur][rv * 64 + ((lg * 8)      ^ vsw)];
            bf16x8 vf1 = *(const bf16x8*)&Vt[cur][rv * 64 + ((32 + lg * 8) ^ vsw)];
            o[d2] = MFMA16(pa0, vf0, o[d2]);
            o[d2] = MFMA16(pa1, vf1, o[d2]);
        }
        __builtin_amdgcn_s_setprio(0);

        __syncthreads();
        cur ^= 1;
    }

#pragma unroll
    for (int j = 0; j < 4; ++j) {
        const float inv = 1.0f / l[j];
        bf16* dst = ctx + (size_t)(q0b + w * 16 + lg * 4 + j) * DIM + h * HEAD_DIM + lr;
#pragma unroll
        for (int d2 = 0; d2 < 8; ++d2)
            dst[d2 * 16] = __float2bfloat16(o[d2][j] * inv);
    }
}

// ---------------- host ----------------
extern "C" void kernel_launch(void* const* d_in, const int* in_sizes, int n_in,
                              void* d_out, int out_size, void* d_ws, size_t ws_size,
                              hipStream_t stream)
{
    const float* x   = (const float*)d_in[0];
    const float* fc  = (const float*)d_in[1];
    const float* fs  = (const float*)d_in[2];
    // d_in[3] = mask (unused; causal computed analytically)
    const float* wq  = (const float*)d_in[4];
    const float* wk  = (const float*)d_in[5];
    const float* wv  = (const float*)d_in[6];
    const float* wo  = (const float*)d_in[7];
    const float* w1  = (const float*)d_in[8];
    const float* w2  = (const float*)d_in[9];
    const float* w3  = (const float*)d_in[10];
    const float* anw = (const float*)d_in[11];
    const float* fnw = (const float*)d_in[12];
    float* out = (float*)d_out;

    char* p = (char*)d_ws;
    auto alloc = [&](size_t n) { char* r = p; p += (n + 255) & ~(size_t)255; return r; };
    bf16* wT  = (bf16*)alloc((size_t)HID * DIM * 2);   // reused per weight group
    bf16* hn  = (bf16*)alloc((size_t)SEQ * DIM * 2);
    bf16* qkv = (bf16*)alloc((size_t)SEQ * SQKV * 2);  // fused q|k|v, stride 6144
    bf16* vt  = (bf16*)alloc((size_t)SEQ * DIM * 2);
    bf16* ctx = (bf16*)alloc((size_t)SEQ * DIM * 2);
    bf16* fn  = (bf16*)alloc((size_t)SEQ * DIM * 2);
    float* h  = (float*)alloc((size_t)SEQ * DIM * 4);
    bf16* g   = (bf16*)alloc((size_t)SEQ * HID * 2);

    const dim3 tb32(32, 8);
    const int LDS256 = 131072;
    (void)hipFuncSetAttribute((const void*)gemm256_k<0>,
        hipFuncAttributeMaxDynamicSharedMemorySize, LDS256);
    (void)hipFuncSetAttribute((const void*)gemm256_k<2>,
        hipFuncAttributeMaxDynamicSharedMemorySize, LDS256);

    rmsnorm_bf16_k<<<SEQ, 256, 0, stream>>>(x, anw, hn);

    // fused QKV: wT = [wq^T; wk^T; wv^T] (6144x2048) -> qkv[2048][6144]
    convT3_f32_bf16_k<<<dim3(DIM / 32, DIM / 32, 3), tb32, 0, stream>>>(wq, wk, wv, wT);
    gemm256_k<0><<<(SEQ / 256) * (SQKV / 256), 512, LDS256, stream>>>(
        hn, wT, qkv, nullptr, SEQ, SQKV, DIM, SQKV / 256);

    rope_qk_k<<<(SEQ * 1024) / 256, 256, 0, stream>>>(qkv, qkv + DIM, fc, fs);
    transpose_bf16_k<<<dim3(DIM / 32, SEQ / 32), tb32, 0, stream>>>(qkv + 2 * DIM, SQKV, vt);

    attn_fwd_k<<<dim3(SEQ / 64, N_HEADS), 256, 0, stream>>>(qkv, vt, ctx);

    // h = x + ctx @ wo   (64-block shape: keep 128^2 kernel)
    convT_f32_bf16_k<<<dim3(DIM / 32, DIM / 32), tb32, 0, stream>>>(wo, wT, DIM, DIM);
    gemm_bt_k<1><<<dim3(DIM / 128, SEQ / 128), 256, 0, stream>>>(ctx, wT, nullptr, h, x, nullptr, SEQ, DIM, DIM);

    rmsnorm_bf16_k<<<SEQ, 256, 0, stream>>>(h, fnw, fn);

    convT_f32_bf16_k<<<dim3(HID / 32, DIM / 32), tb32, 0, stream>>>(w1, wT, DIM, HID);
    gemm256_k<0><<<(SEQ / 256) * (HID / 256), 512, LDS256, stream>>>(
        fn, wT, g, nullptr, SEQ, HID, DIM, HID / 256);
    convT_f32_bf16_k<<<dim3(HID / 32, DIM / 32), tb32, 0, stream>>>(w3, wT, DIM, HID);
    gemm256_k<2><<<(SEQ / 256) * (HID / 256), 512, LDS256, stream>>>(
        fn, wT, g, g, SEQ, HID, DIM, HID / 256);

    // out = h + g @ w2   (64-block shape at 256^2: keep 128^2 kernel, K=8192 amortizes)
    convT_f32_bf16_k<<<dim3(DIM / 32, HID / 32), tb32, 0, stream>>>(w2, wT, HID, DIM);
    gemm_bt_k<1><<<dim3(DIM / 128, SEQ / 128), 256, 0, stream>>>(g, wT, nullptr, out, h, nullptr, SEQ, DIM, HID);
}

// Round 6
// 552.213 us; speedup vs baseline: 1.8356x; 1.1493x over previous
//
#include <hip/hip_runtime.h>
#include <hip/hip_bf16.h>

#define DIM 2048
#define HEAD_DIM 128
#define N_HEADS 16
#define SEQ 2048
#define HID 8192
#define SQKV 6144   // row stride of fused qkv activation

typedef short bf16x8 __attribute__((ext_vector_type(8)));
typedef float f32x4 __attribute__((ext_vector_type(4)));
using bf16 = __hip_bfloat16;

#define MFMA16(a, b, c) __builtin_amdgcn_mfma_f32_16x16x32_bf16(a, b, c, 0, 0, 0)

__device__ __forceinline__ unsigned short f2bu(float f) {
    union { bf16 b; unsigned short u; } cv;
    cv.b = __float2bfloat16(f);
    return cv.u;
}

// async global -> LDS, 16B per lane (dest must be lane-linear per wave)
__device__ __forceinline__ void gl16(const void* g, void* l) {
    __builtin_amdgcn_global_load_lds(
        (const __attribute__((address_space(1))) unsigned int*)g,
        (__attribute__((address_space(3))) unsigned int*)l, 16, 0, 0);
}

// ---------------- rmsnorm (fp32 in -> bf16 out) ----------------
__global__ __launch_bounds__(256) void rmsnorm_bf16_k(
    const float* __restrict__ x, const float* __restrict__ w, bf16* __restrict__ y)
{
    const int row = blockIdx.x;
    const int tid = threadIdx.x;
    const float* xr = x + (size_t)row * DIM;
    float4 v0 = ((const float4*)xr)[tid];
    float4 v1 = ((const float4*)xr)[tid + 256];
    float ss = v0.x*v0.x + v0.y*v0.y + v0.z*v0.z + v0.w*v0.w
             + v1.x*v1.x + v1.y*v1.y + v1.z*v1.z + v1.w*v1.w;
    for (int o = 32; o > 0; o >>= 1) ss += __shfl_down(ss, o);
    __shared__ float red[4];
    if ((tid & 63) == 0) red[tid >> 6] = ss;
    __syncthreads();
    float tot = red[0] + red[1] + red[2] + red[3];
    float r = rsqrtf(tot * (1.0f / DIM) + 1e-6f);
    float4 w0 = ((const float4*)w)[tid];
    float4 w1 = ((const float4*)w)[tid + 256];
    ushort4 o0, o1;
    o0.x = f2bu(v0.x * r * w0.x); o0.y = f2bu(v0.y * r * w0.y);
    o0.z = f2bu(v0.z * r * w0.z); o0.w = f2bu(v0.w * r * w0.w);
    o1.x = f2bu(v1.x * r * w1.x); o1.y = f2bu(v1.y * r * w1.y);
    o1.z = f2bu(v1.z * r * w1.z); o1.w = f2bu(v1.w * r * w1.w);
    ushort4* yr = (ushort4*)(y + (size_t)row * DIM);
    yr[tid] = o0;
    yr[tid + 256] = o1;
}

// ---------------- split-K reduce + residual + rmsnorm (fp32 h out, bf16 fn out) ----------------
__global__ __launch_bounds__(256) void rmsnorm4_k(
    const float* __restrict__ part, const float* __restrict__ x,
    const float* __restrict__ w, float* __restrict__ hout, bf16* __restrict__ y)
{
    const int row = blockIdx.x;
    const int tid = threadIdx.x;
    const size_t base = (size_t)row * DIM;
    const size_t SP = (size_t)SEQ * DIM;
    float4 r0, r1;
    float ss = 0.0f;
    {
        float4 a  = ((const float4*)(x + base))[tid];
        float4 p0 = ((const float4*)(part + base))[tid];
        float4 p1 = ((const float4*)(part + SP + base))[tid];
        float4 p2 = ((const float4*)(part + 2 * SP + base))[tid];
        float4 p3 = ((const float4*)(part + 3 * SP + base))[tid];
        r0.x = a.x + ((p0.x + p1.x) + (p2.x + p3.x));
        r0.y = a.y + ((p0.y + p1.y) + (p2.y + p3.y));
        r0.z = a.z + ((p0.z + p1.z) + (p2.z + p3.z));
        r0.w = a.w + ((p0.w + p1.w) + (p2.w + p3.w));
        ((float4*)(hout + base))[tid] = r0;
        ss += r0.x*r0.x + r0.y*r0.y + r0.z*r0.z + r0.w*r0.w;
    }
    {
        const int t2 = tid + 256;
        float4 a  = ((const float4*)(x + base))[t2];
        float4 p0 = ((const float4*)(part + base))[t2];
        float4 p1 = ((const float4*)(part + SP + base))[t2];
        float4 p2 = ((const float4*)(part + 2 * SP + base))[t2];
        float4 p3 = ((const float4*)(part + 3 * SP + base))[t2];
        r1.x = a.x + ((p0.x + p1.x) + (p2.x + p3.x));
        r1.y = a.y + ((p0.y + p1.y) + (p2.y + p3.y));
        r1.z = a.z + ((p0.z + p1.z) + (p2.z + p3.z));
        r1.w = a.w + ((p0.w + p1.w) + (p2.w + p3.w));
        ((float4*)(hout + base))[t2] = r1;
        ss += r1.x*r1.x + r1.y*r1.y + r1.z*r1.z + r1.w*r1.w;
    }
    for (int o = 32; o > 0; o >>= 1) ss += __shfl_down(ss, o);
    __shared__ float red[4];
    if ((tid & 63) == 0) red[tid >> 6] = ss;
    __syncthreads();
    float tot = red[0] + red[1] + red[2] + red[3];
    float r = rsqrtf(tot * (1.0f / DIM) + 1e-6f);
    float4 w0 = ((const float4*)w)[tid];
    float4 w1 = ((const float4*)w)[tid + 256];
    ushort4 o0, o1;
    o0.x = f2bu(r0.x * r * w0.x); o0.y = f2bu(r0.y * r * w0.y);
    o0.z = f2bu(r0.z * r * w0.z); o0.w = f2bu(r0.w * r * w0.w);
    o1.x = f2bu(r1.x * r * w1.x); o1.y = f2bu(r1.y * r * w1.y);
    o1.z = f2bu(r1.z * r * w1.z); o1.w = f2bu(r1.w * r * w1.w);
    ushort4* yr = (ushort4*)(y + base);
    yr[tid] = o0;
    yr[tid + 256] = o1;
}

// ---------------- split-K reduce + residual (fp32 out) ----------------
__global__ __launch_bounds__(256) void reduce4_k(
    const float* __restrict__ part, const float* __restrict__ h, float* __restrict__ out)
{
    const size_t i = (size_t)blockIdx.x * 256 + threadIdx.x;   // float4 index
    const size_t SP4 = (size_t)SEQ * DIM / 4;
    float4 a  = ((const float4*)h)[i];
    float4 p0 = ((const float4*)part)[i];
    float4 p1 = ((const float4*)part)[i + SP4];
    float4 p2 = ((const float4*)part)[i + 2 * SP4];
    float4 p3 = ((const float4*)part)[i + 3 * SP4];
    float4 r;
    r.x = a.x + ((p0.x + p1.x) + (p2.x + p3.x));
    r.y = a.y + ((p0.y + p1.y) + (p2.y + p3.y));
    r.z = a.z + ((p0.z + p1.z) + (p2.z + p3.z));
    r.w = a.w + ((p0.w + p1.w) + (p2.w + p3.w));
    ((float4*)out)[i] = r;
}

// ---------------- fp32 [R][C] -> bf16 [C][R] transpose-convert ----------------
__global__ __launch_bounds__(256) void convT_f32_bf16_k(
    const float* __restrict__ in, bf16* __restrict__ out, int R, int C)
{
    __shared__ float t[32][33];
    const int tx = threadIdx.x, ty = threadIdx.y;
    const int x0 = blockIdx.x * 32, y0 = blockIdx.y * 32;
#pragma unroll
    for (int i = 0; i < 4; ++i)
        t[ty + i * 8][tx] = in[(size_t)(y0 + ty + i * 8) * C + x0 + tx];
    __syncthreads();
#pragma unroll
    for (int i = 0; i < 4; ++i)
        out[(size_t)(x0 + ty + i * 8) * R + y0 + tx] = __float2bfloat16(t[tx][ty + i * 8]);
}

// 3 square weights -> one [3*DIM][DIM] B^T buffer (z selects wq/wk/wv)
__global__ __launch_bounds__(256) void convT3_f32_bf16_k(
    const float* __restrict__ wq, const float* __restrict__ wk,
    const float* __restrict__ wv, bf16* __restrict__ out)
{
    const int z = blockIdx.z;
    const float* in = z == 0 ? wq : (z == 1 ? wk : wv);
    bf16* o = out + (size_t)z * DIM * DIM;
    __shared__ float t[32][33];
    const int tx = threadIdx.x, ty = threadIdx.y;
    const int x0 = blockIdx.x * 32, y0 = blockIdx.y * 32;
#pragma unroll
    for (int i = 0; i < 4; ++i)
        t[ty + i * 8][tx] = in[(size_t)(y0 + ty + i * 8) * DIM + x0 + tx];
    __syncthreads();
#pragma unroll
    for (int i = 0; i < 4; ++i)
        o[(size_t)(x0 + ty + i * 8) * DIM + y0 + tx] = __float2bfloat16(t[tx][ty + i * 8]);
}

// ---------------- bf16 transpose with src stride (vt[d][s] = in[s][d]) ----------------
__global__ __launch_bounds__(256) void transpose_bf16_k(
    const bf16* __restrict__ in, int istride, bf16* __restrict__ out)
{
    __shared__ unsigned short t[32][33];
    const int tx = threadIdx.x, ty = threadIdx.y;
    const int x = blockIdx.x * 32 + tx;       // d
    const int y0 = blockIdx.y * 32;           // s
    const unsigned short* inu = (const unsigned short*)in;
    unsigned short* outu = (unsigned short*)out;
#pragma unroll
    for (int i = 0; i < 4; ++i)
        t[ty + i * 8][tx] = inu[(size_t)(y0 + ty + i * 8) * istride + x];
    __syncthreads();
    const int x2 = blockIdx.y * 32 + tx;
    const int y2 = blockIdx.x * 32;
#pragma unroll
    for (int i = 0; i < 4; ++i)
        outu[(size_t)(y2 + ty + i * 8) * SEQ + x2] = t[tx][ty + i * 8];
}

// ---------------- RoPE in-place on strided bf16 q,k ----------------
__global__ __launch_bounds__(256) void rope_qk_k(
    bf16* __restrict__ q, bf16* __restrict__ k,
    const float* __restrict__ cosb, const float* __restrict__ sinb)
{
    const int gid = blockIdx.x * 256 + threadIdx.x;   // < SEQ * 1024
    const int s = gid >> 10;
    const int p = gid & 1023;
    const int h = p >> 6, j = p & 63;
    const size_t off = (size_t)s * SQKV + h * HEAD_DIM + 2 * j;
    const float c = cosb[s * 64 + j], sn = sinb[s * 64 + j];
    float xr = __bfloat162float(q[off]), xi = __bfloat162float(q[off + 1]);
    q[off]     = __float2bfloat16(xr * c - xi * sn);
    q[off + 1] = __float2bfloat16(xr * sn + xi * c);
    xr = __bfloat162float(k[off]); xi = __bfloat162float(k[off + 1]);
    k[off]     = __float2bfloat16(xr * c - xi * sn);
    k[off + 1] = __float2bfloat16(xr * sn + xi * c);
}

// ---------------- 256x256 8-phase GEMM (T2+T3+T4+T5), BK=64, 512 threads, split-K ----------------
// EP 0: store bf16    EP 2: Cb = silu(other)*acc (in-place ok)    EP 3: fp32 partial store
// LDS (dynamic 128KB): A halves [buf][2][128*64], B halves at +64KB.
// st_16x32 swizzle byte^=((byte>>9)&1)<<5 on ds_read offset, inverse on global src (rule #21).
template <int EP>
__global__ __launch_bounds__(512, 2) void gemm256_k(
    const bf16* __restrict__ A, const bf16* __restrict__ Bt,
    bf16* __restrict__ Cb, const bf16* other, float* __restrict__ Pf,
    int M, int N, int K, int gx, int ntile, int Ks)
{
    extern __shared__ char smem[];
    const int t512 = threadIdx.x;
    const int w = t512 >> 6, lane = t512 & 63;
    const int lr = lane & 15, lg = lane >> 4;
    const int wm = w >> 2, wn = w & 3;           // 2 x 4 wave grid
    const int bofs = (wn & 1) * 64;              // B row offset inside its half

    // XCD-bijective block swizzle (m204)
    const int nwg = gridDim.x;                    // = ntile * splitk
    const int q8 = nwg >> 3, r8 = nwg & 7;
    const int xcd = blockIdx.x & 7, seq = blockIdx.x >> 3;
    const int wgid = (xcd < r8 ? xcd * (q8 + 1) : r8 * (q8 + 1) + (xcd - r8) * q8) + seq;
    const int split = wgid / ntile;
    const int tile = wgid % ntile;
    const int m0 = (tile / gx) * 256, n0 = (tile % gx) * 256;
    const int kb0 = split * Ks;

    const int nt = Ks >> 6;                       // 64-wide K tiles (nt >= 2 everywhere)

    // stage one 128x64 half-tile (16KB): 2 gl16 per thread, source pre-swizzled
    auto stage_half = [&](int buf, int kt, int isB, int hs) {
        const int k0 = kb0 + (kt << 6);
        char* base = smem + (isB ? 65536 : 0) + (buf * 2 + hs) * 16384;
#pragma unroll
        for (int c = 0; c < 2; ++c) {
            const int s = (c * 512 + t512) * 16;            // linear byte slot
            const int p = s ^ (((s >> 9) & 1) << 5);        // nominal position
            const int row = p >> 7;
            const int colE = (p & 127) >> 1;
            if (isB)
                gl16(Bt + (size_t)(n0 + hs * 128 + row) * K + k0 + colE, base + s);
            else
                gl16(A  + (size_t)(m0 + hs * 128 + row) * K + k0 + colE, base + s);
        }
    };

    f32x4 acc[8][4] = {};
    bf16x8 bfr[4][2];

    // prologue: tile0 -> buf0, tile1 -> buf1 (16 loads/thread)
    stage_half(0, 0, 0, 0); stage_half(0, 0, 0, 1);
    stage_half(0, 0, 1, 0); stage_half(0, 0, 1, 1);
    stage_half(1, 1, 0, 0); stage_half(1, 1, 0, 1);
    stage_half(1, 1, 1, 0); stage_half(1, 1, 1, 1);

    for (int t = 0; t < nt; ++t) {
        const int cur = t & 1;
        // tile t+1's 8 loads are the only ones newer than tile t's -> vmcnt(8)
        if (t + 1 < nt) { asm volatile("s_waitcnt vmcnt(8)" ::: "memory"); }
        else            { asm volatile("s_waitcnt vmcnt(0)" ::: "memory"); }
        __builtin_amdgcn_sched_barrier(0);
        __builtin_amdgcn_s_barrier();

        const char* Am = smem + (cur * 2 + wm) * 16384;
        const char* Bm = smem + 65536 + (cur * 2 + (wn >> 1)) * 16384;
        const bool pf = (t + 2 < nt);

#define LDA_(mf, ks, dst) { int off = ((mf) * 16 + lr) * 128 + (ks) * 64 + lg * 16; \
        off ^= ((off >> 9) & 1) << 5; dst = *(const bf16x8*)(Am + off); }
#define LDB_(nf, ks, dst) { int off = (bofs + (nf) * 16 + lr) * 128 + (ks) * 64 + lg * 16; \
        off ^= ((off >> 9) & 1) << 5; dst = *(const bf16x8*)(Bm + off); }
#define MFMA_PH(mf0) { \
        asm volatile("s_waitcnt lgkmcnt(0)" ::: "memory"); \
        __builtin_amdgcn_sched_barrier(0); \
        __builtin_amdgcn_s_setprio(1); \
        _Pragma("unroll") \
        for (int nf = 0; nf < 4; ++nf) { \
            acc[(mf0)][nf]     = MFMA16(a0, bfr[nf][0], acc[(mf0)][nf]); \
            acc[(mf0)][nf]     = MFMA16(a1, bfr[nf][1], acc[(mf0)][nf]); \
            acc[(mf0) + 1][nf] = MFMA16(a2, bfr[nf][0], acc[(mf0) + 1][nf]); \
            acc[(mf0) + 1][nf] = MFMA16(a3, bfr[nf][1], acc[(mf0) + 1][nf]); \
        } \
        __builtin_amdgcn_s_setprio(0); }

        bf16x8 a0, a1, a2, a3;
        // ---- phase 0: A mf0-1 + all B, 16 MFMA ----
        LDA_(0, 0, a0) LDA_(0, 1, a1) LDA_(1, 0, a2) LDA_(1, 1, a3)
#pragma unroll
        for (int nf = 0; nf < 4; ++nf) { LDB_(nf, 0, bfr[nf][0]) LDB_(nf, 1, bfr[nf][1]) }
        MFMA_PH(0)
        __builtin_amdgcn_s_barrier();            // B half0 readers done
        if (pf) stage_half(cur, t + 2, 1, 0);    // stage B half0 of tile t+2

        // ---- phase 1 ----
        LDA_(2, 0, a0) LDA_(2, 1, a1) LDA_(3, 0, a2) LDA_(3, 1, a3)
        MFMA_PH(2)
        __builtin_amdgcn_s_barrier();            // B half1 readers done
        if (pf) stage_half(cur, t + 2, 1, 1);    // stage B half1

        // ---- phase 2 ----
        LDA_(4, 0, a0) LDA_(4, 1, a1) LDA_(5, 0, a2) LDA_(5, 1, a3)
        MFMA_PH(4)

        // ---- phase 3 ----
        LDA_(6, 0, a0) LDA_(6, 1, a1) LDA_(7, 0, a2) LDA_(7, 1, a3)
        MFMA_PH(6)
        __builtin_amdgcn_s_barrier();            // all A reads of this tile done
        if (pf) { stage_half(cur, t + 2, 0, 0); stage_half(cur, t + 2, 0, 1); }
#undef LDA_
#undef LDB_
#undef MFMA_PH
    }

    // ---- epilogue ----
    float* pf_base = Pf + (size_t)split * M * N;
#pragma unroll
    for (int mf = 0; mf < 8; ++mf)
#pragma unroll
        for (int nf = 0; nf < 4; ++nf) {
            const int row = m0 + wm * 128 + mf * 16 + lg * 4;
            const int col = n0 + wn * 64 + nf * 16 + lr;
#pragma unroll
            for (int r = 0; r < 4; ++r) {
                const size_t idx = (size_t)(row + r) * N + col;
                const float v = acc[mf][nf][r];
                if (EP == 0) {
                    Cb[idx] = __float2bfloat16(v);
                } else if (EP == 2) {
                    const float gg = __bfloat162float(other[idx]);
                    const float sg = gg / (1.0f + __expf(-gg));
                    Cb[idx] = __float2bfloat16(sg * v);
                } else {
                    pf_base[idx] = v;
                }
            }
        }
}

// ---------------- causal flash attention: QBLK=64 (4 waves x 16 rows), shared KV tiles ----------------
__global__ __launch_bounds__(256) void attn_fwd_k(
    const bf16* __restrict__ qkv, const bf16* __restrict__ vT, bf16* __restrict__ ctx)
{
    const int tid = threadIdx.x;
    const int w = tid >> 6, lane = tid & 63;
    const int lr = lane & 15, lg = lane >> 4;
    const int h = blockIdx.y;
    const int qidx = (blockIdx.y < 8) ? blockIdx.x : (31 - blockIdx.x);
    const int q0b = qidx * 64;
    const int nt = qidx + 1;                  // 64-row KV tiles (causal)

    __shared__ __align__(16) unsigned short Kt[2][64 * 128];
    __shared__ __align__(16) unsigned short Vt[2][128 * 64];
    __shared__ __align__(16) unsigned short Pp[4][16 * 64];

    const char* kbase = (const char*)(qkv + DIM + h * HEAD_DIM);
    const char* vbase = (const char*)(vT + (size_t)h * HEAD_DIM * SEQ);

    const int krow_c = tid >> 4;
    const int kcolB  = (tid & 15) * 16;
    const int vrow_c = tid >> 3;
    const int vcolB  = (tid & 7) * 16;

    auto stage = [&](int buf, int kb) {
#pragma unroll
        for (int c = 0; c < 4; ++c) {
            const int r = c * 16 + krow_c;
            gl16(kbase + (size_t)(kb + r) * (SQKV * 2) + (kcolB ^ ((r & 7) << 4)),
                 &Kt[buf][c * 2048 + tid * 8]);
        }
#pragma unroll
        for (int c = 0; c < 4; ++c) {
            const int r = c * 32 + vrow_c;
            gl16(vbase + (size_t)r * (SEQ * 2) + kb * 2 + (vcolB ^ ((r & 7) << 4)),
                 &Vt[buf][c * 2048 + tid * 8]);
        }
    };

    bf16x8 qf[4];
    const bf16* qrow = qkv + (size_t)(q0b + w * 16 + lr) * SQKV + h * HEAD_DIM;
#pragma unroll
    for (int dt = 0; dt < 4; ++dt)
        qf[dt] = *(const bf16x8*)(qrow + dt * 32 + lg * 8);

    f32x4 o[8] = {};
    float m[4], l[4];
#pragma unroll
    for (int j = 0; j < 4; ++j) { m[j] = -3e38f; l[j] = 0.0f; }
    const float scale = 0.08838834764831845f;

    stage(0, 0);
    __syncthreads();

    int cur = 0;
    for (int t = 0; t < nt; ++t) {
        const int kb = t * 64;
        if (t + 1 < nt) stage(cur ^ 1, kb + 64);

        f32x4 s[4] = {};
        __builtin_amdgcn_s_setprio(1);
#pragma unroll
        for (int ss = 0; ss < 4; ++ss) {
            const int r = ss * 16 + lr;
            const int sw = (r & 7) << 3;
#pragma unroll
            for (int dt = 0; dt < 4; ++dt) {
                bf16x8 kf = *(const bf16x8*)&Kt[cur][r * 128 + ((dt * 32 + lg * 8) ^ sw)];
                s[ss] = MFMA16(qf[dt], kf, s[ss]);
            }
        }
        __builtin_amdgcn_s_setprio(0);

        float al[4];
#pragma unroll
        for (int j = 0; j < 4; ++j) {
            const int qi = q0b + w * 16 + lg * 4 + j;
            const int prow = lg * 4 + j;
            const int psw = (prow & 7) << 3;
            float a[4];
#pragma unroll
            for (int ss = 0; ss < 4; ++ss)
                a[ss] = s[ss][j] * scale + ((kb + ss * 16 + lr) > qi ? -1e9f : 0.0f);
            float mx = fmaxf(fmaxf(a[0], a[1]), fmaxf(a[2], a[3]));
            mx = fmaxf(mx, __shfl_xor(mx, 1));
            mx = fmaxf(mx, __shfl_xor(mx, 2));
            mx = fmaxf(mx, __shfl_xor(mx, 4));
            mx = fmaxf(mx, __shfl_xor(mx, 8));
            const float mn = fmaxf(m[j], mx);
            const float asc = __expf(m[j] - mn);
            float e0 = __expf(a[0] - mn), e1 = __expf(a[1] - mn);
            float e2 = __expf(a[2] - mn), e3 = __expf(a[3] - mn);
            float rs = (e0 + e1) + (e2 + e3);
            rs += __shfl_xor(rs, 1); rs += __shfl_xor(rs, 2);
            rs += __shfl_xor(rs, 4); rs += __shfl_xor(rs, 8);
            l[j] = l[j] * asc + rs;
            m[j] = mn;
            al[j] = asc;
            Pp[w][prow * 64 + ((lr)      ^ psw)] = f2bu(e0);
            Pp[w][prow * 64 + ((16 + lr) ^ psw)] = f2bu(e1);
            Pp[w][prow * 64 + ((32 + lr) ^ psw)] = f2bu(e2);
            Pp[w][prow * 64 + ((48 + lr) ^ psw)] = f2bu(e3);
        }
#pragma unroll
        for (int d2 = 0; d2 < 8; ++d2)
#pragma unroll
            for (int j = 0; j < 4; ++j) o[d2][j] *= al[j];

        asm volatile("s_waitcnt lgkmcnt(0)" ::: "memory");
        __builtin_amdgcn_sched_barrier(0);
        const int asw = (lr & 7) << 3;
        bf16x8 pa0 = *(const bf16x8*)&Pp[w][lr * 64 + ((lg * 8)      ^ asw)];
        bf16x8 pa1 = *(const bf16x8*)&Pp[w][lr * 64 + ((32 + lg * 8) ^ asw)];

        __builtin_amdgcn_s_setprio(1);
#pragma unroll
        for (int d2 = 0; d2 < 8; ++d2) {
            const int rv = d2 * 16 + lr;
            const int vsw = (rv & 7) << 3;
            bf16x8 vf0 = *(const bf16x8*)&Vt[cur][rv * 64 + ((lg * 8)      ^ vsw)];
            bf16x8 vf1 = *(const bf16x8*)&Vt[cur][rv * 64 + ((32 + lg * 8) ^ vsw)];
            o[d2] = MFMA16(pa0, vf0, o[d2]);
            o[d2] = MFMA16(pa1, vf1, o[d2]);
        }
        __builtin_amdgcn_s_setprio(0);

        __syncthreads();
        cur ^= 1;
    }

#pragma unroll
    for (int j = 0; j < 4; ++j) {
        const float inv = 1.0f / l[j];
        bf16* dst = ctx + (size_t)(q0b + w * 16 + lg * 4 + j) * DIM + h * HEAD_DIM + lr;
#pragma unroll
        for (int d2 = 0; d2 < 8; ++d2)
            dst[d2 * 16] = __float2bfloat16(o[d2][j] * inv);
    }
}

// ---------------- host ----------------
extern "C" void kernel_launch(void* const* d_in, const int* in_sizes, int n_in,
                              void* d_out, int out_size, void* d_ws, size_t ws_size,
                              hipStream_t stream)
{
    const float* x   = (const float*)d_in[0];
    const float* fc  = (const float*)d_in[1];
    const float* fs  = (const float*)d_in[2];
    // d_in[3] = mask (unused; causal computed analytically)
    const float* wq  = (const float*)d_in[4];
    const float* wk  = (const float*)d_in[5];
    const float* wv  = (const float*)d_in[6];
    const float* wo  = (const float*)d_in[7];
    const float* w1  = (const float*)d_in[8];
    const float* w2  = (const float*)d_in[9];
    const float* w3  = (const float*)d_in[10];
    const float* anw = (const float*)d_in[11];
    const float* fnw = (const float*)d_in[12];
    float* out = (float*)d_out;

    char* p = (char*)d_ws;
    auto alloc = [&](size_t n) { char* r = p; p += (n + 255) & ~(size_t)255; return r; };
    bf16* wT  = (bf16*)alloc((size_t)HID * DIM * 2);     // reused per weight group
    bf16* hn  = (bf16*)alloc((size_t)SEQ * DIM * 2);
    bf16* qkv = (bf16*)alloc((size_t)SEQ * SQKV * 2);    // fused q|k|v, stride 6144
    bf16* vt  = (bf16*)alloc((size_t)SEQ * DIM * 2);
    bf16* ctx = (bf16*)alloc((size_t)SEQ * DIM * 2);
    bf16* fn  = (bf16*)alloc((size_t)SEQ * DIM * 2);
    float* h  = (float*)alloc((size_t)SEQ * DIM * 4);
    bf16* g   = (bf16*)alloc((size_t)SEQ * HID * 2);
    float* sk = (float*)alloc((size_t)4 * SEQ * DIM * 4);  // split-K partials (64MB)

    const dim3 tb32(32, 8);
    const int LDS256 = 131072;
    (void)hipFuncSetAttribute((const void*)gemm256_k<0>,
        hipFuncAttributeMaxDynamicSharedMemorySize, LDS256);
    (void)hipFuncSetAttribute((const void*)gemm256_k<2>,
        hipFuncAttributeMaxDynamicSharedMemorySize, LDS256);
    (void)hipFuncSetAttribute((const void*)gemm256_k<3>,
        hipFuncAttributeMaxDynamicSharedMemorySize, LDS256);

    rmsnorm_bf16_k<<<SEQ, 256, 0, stream>>>(x, anw, hn);

    // fused QKV: wT = [wq^T; wk^T; wv^T] (6144x2048) -> qkv[2048][6144]
    convT3_f32_bf16_k<<<dim3(DIM / 32, DIM / 32, 3), tb32, 0, stream>>>(wq, wk, wv, wT);
    gemm256_k<0><<<(SEQ / 256) * (SQKV / 256), 512, LDS256, stream>>>(
        hn, wT, qkv, nullptr, nullptr, SEQ, SQKV, DIM, SQKV / 256, (SEQ / 256) * (SQKV / 256), DIM);

    rope_qk_k<<<(SEQ * 1024) / 256, 256, 0, stream>>>(qkv, qkv + DIM, fc, fs);
    transpose_bf16_k<<<dim3(DIM / 32, SEQ / 32), tb32, 0, stream>>>(qkv + 2 * DIM, SQKV, vt);

    attn_fwd_k<<<dim3(SEQ / 64, N_HEADS), 256, 0, stream>>>(qkv, vt, ctx);

    // h = x + ctx @ wo : split-K=4 (Ks=512) -> partials, fused reduce+residual+rmsnorm
    convT_f32_bf16_k<<<dim3(DIM / 32, DIM / 32), tb32, 0, stream>>>(wo, wT, DIM, DIM);
    gemm256_k<3><<<(SEQ / 256) * (DIM / 256) * 4, 512, LDS256, stream>>>(
        ctx, wT, nullptr, nullptr, sk, SEQ, DIM, DIM, DIM / 256, (SEQ / 256) * (DIM / 256), 512);
    rmsnorm4_k<<<SEQ, 256, 0, stream>>>(sk, x, fnw, h, fn);

    convT_f32_bf16_k<<<dim3(HID / 32, DIM / 32), tb32, 0, stream>>>(w1, wT, DIM, HID);
    gemm256_k<0><<<(SEQ / 256) * (HID / 256), 512, LDS256, stream>>>(
        fn, wT, g, nullptr, nullptr, SEQ, HID, DIM, HID / 256, (SEQ / 256) * (HID / 256), DIM);
    convT_f32_bf16_k<<<dim3(HID / 32, DIM / 32), tb32, 0, stream>>>(w3, wT, DIM, HID);
    gemm256_k<2><<<(SEQ / 256) * (HID / 256), 512, LDS256, stream>>>(
        fn, wT, g, g, nullptr, SEQ, HID, DIM, HID / 256, (SEQ / 256) * (HID / 256), DIM);

    // out = h + g @ w2 : split-K=4 (Ks=2048) -> partials, reduce+residual
    convT_f32_bf16_k<<<dim3(DIM / 32, HID / 32), tb32, 0, stream>>>(w2, wT, HID, DIM);
    gemm256_k<3><<<(SEQ / 256) * (DIM / 256) * 4, 512, LDS256, stream>>>(
        g, wT, nullptr, nullptr, sk, SEQ, DIM, HID, DIM / 256, (SEQ / 256) * (DIM / 256), 2048);
    reduce4_k<<<(SEQ * DIM / 4) / 256, 256, 0, stream>>>(sk, h, out);
}

// Round 7
// 528.541 us; speedup vs baseline: 1.9178x; 1.0448x over previous
//
#include <hip/hip_runtime.h>
#include <hip/hip_bf16.h>

#define DIM 2048
#define HEAD_DIM 128
#define N_HEADS 16
#define SEQ 2048
#define HID 8192
#define SQKV 6144   // row stride of fused qkv activation

typedef short bf16x8 __attribute__((ext_vector_type(8)));
typedef float f32x4 __attribute__((ext_vector_type(4)));
using bf16 = __hip_bfloat16;

#define MFMA16(a, b, c) __builtin_amdgcn_mfma_f32_16x16x32_bf16(a, b, c, 0, 0, 0)

__device__ __forceinline__ unsigned short f2bu(float f) {
    union { bf16 b; unsigned short u; } cv;
    cv.b = __float2bfloat16(f);
    return cv.u;
}

// async global -> LDS, 16B per lane (dest must be lane-linear per wave)
__device__ __forceinline__ void gl16(const void* g, void* l) {
    __builtin_amdgcn_global_load_lds(
        (const __attribute__((address_space(1))) unsigned int*)g,
        (__attribute__((address_space(3))) unsigned int*)l, 16, 0, 0);
}

// ---------------- rmsnorm (fp32 in -> bf16 out) ----------------
__global__ __launch_bounds__(256) void rmsnorm_bf16_k(
    const float* __restrict__ x, const float* __restrict__ w, bf16* __restrict__ y)
{
    const int row = blockIdx.x;
    const int tid = threadIdx.x;
    const float* xr = x + (size_t)row * DIM;
    float4 v0 = ((const float4*)xr)[tid];
    float4 v1 = ((const float4*)xr)[tid + 256];
    float ss = v0.x*v0.x + v0.y*v0.y + v0.z*v0.z + v0.w*v0.w
             + v1.x*v1.x + v1.y*v1.y + v1.z*v1.z + v1.w*v1.w;
    for (int o = 32; o > 0; o >>= 1) ss += __shfl_down(ss, o);
    __shared__ float red[4];
    if ((tid & 63) == 0) red[tid >> 6] = ss;
    __syncthreads();
    float tot = red[0] + red[1] + red[2] + red[3];
    float r = rsqrtf(tot * (1.0f / DIM) + 1e-6f);
    float4 w0 = ((const float4*)w)[tid];
    float4 w1 = ((const float4*)w)[tid + 256];
    ushort4 o0, o1;
    o0.x = f2bu(v0.x * r * w0.x); o0.y = f2bu(v0.y * r * w0.y);
    o0.z = f2bu(v0.z * r * w0.z); o0.w = f2bu(v0.w * r * w0.w);
    o1.x = f2bu(v1.x * r * w1.x); o1.y = f2bu(v1.y * r * w1.y);
    o1.z = f2bu(v1.z * r * w1.z); o1.w = f2bu(v1.w * r * w1.w);
    ushort4* yr = (ushort4*)(y + (size_t)row * DIM);
    yr[tid] = o0;
    yr[tid + 256] = o1;
}

// ---------------- split-K reduce + residual + rmsnorm (fp32 h out, bf16 fn out) ----------------
__global__ __launch_bounds__(256) void rmsnorm4_k(
    const float* __restrict__ part, const float* __restrict__ x,
    const float* __restrict__ w, float* __restrict__ hout, bf16* __restrict__ y)
{
    const int row = blockIdx.x;
    const int tid = threadIdx.x;
    const size_t base = (size_t)row * DIM;
    const size_t SP = (size_t)SEQ * DIM;
    float4 r0, r1;
    float ss = 0.0f;
    {
        float4 a  = ((const float4*)(x + base))[tid];
        float4 p0 = ((const float4*)(part + base))[tid];
        float4 p1 = ((const float4*)(part + SP + base))[tid];
        float4 p2 = ((const float4*)(part + 2 * SP + base))[tid];
        float4 p3 = ((const float4*)(part + 3 * SP + base))[tid];
        r0.x = a.x + ((p0.x + p1.x) + (p2.x + p3.x));
        r0.y = a.y + ((p0.y + p1.y) + (p2.y + p3.y));
        r0.z = a.z + ((p0.z + p1.z) + (p2.z + p3.z));
        r0.w = a.w + ((p0.w + p1.w) + (p2.w + p3.w));
        ((float4*)(hout + base))[tid] = r0;
        ss += r0.x*r0.x + r0.y*r0.y + r0.z*r0.z + r0.w*r0.w;
    }
    {
        const int t2 = tid + 256;
        float4 a  = ((const float4*)(x + base))[t2];
        float4 p0 = ((const float4*)(part + base))[t2];
        float4 p1 = ((const float4*)(part + SP + base))[t2];
        float4 p2 = ((const float4*)(part + 2 * SP + base))[t2];
        float4 p3 = ((const float4*)(part + 3 * SP + base))[t2];
        r1.x = a.x + ((p0.x + p1.x) + (p2.x + p3.x));
        r1.y = a.y + ((p0.y + p1.y) + (p2.y + p3.y));
        r1.z = a.z + ((p0.z + p1.z) + (p2.z + p3.z));
        r1.w = a.w + ((p0.w + p1.w) + (p2.w + p3.w));
        ((float4*)(hout + base))[t2] = r1;
        ss += r1.x*r1.x + r1.y*r1.y + r1.z*r1.z + r1.w*r1.w;
    }
    for (int o = 32; o > 0; o >>= 1) ss += __shfl_down(ss, o);
    __shared__ float red[4];
    if ((tid & 63) == 0) red[tid >> 6] = ss;
    __syncthreads();
    float tot = red[0] + red[1] + red[2] + red[3];
    float r = rsqrtf(tot * (1.0f / DIM) + 1e-6f);
    float4 w0 = ((const float4*)w)[tid];
    float4 w1 = ((const float4*)w)[tid + 256];
    ushort4 o0, o1;
    o0.x = f2bu(r0.x * r * w0.x); o0.y = f2bu(r0.y * r * w0.y);
    o0.z = f2bu(r0.z * r * w0.z); o0.w = f2bu(r0.w * r * w0.w);
    o1.x = f2bu(r1.x * r * w1.x); o1.y = f2bu(r1.y * r * w1.y);
    o1.z = f2bu(r1.z * r * w1.z); o1.w = f2bu(r1.w * r * w1.w);
    ushort4* yr = (ushort4*)(y + base);
    yr[tid] = o0;
    yr[tid + 256] = o1;
}

// ---------------- split-K reduce + residual (fp32 out) ----------------
__global__ __launch_bounds__(256) void reduce4_k(
    const float* __restrict__ part, const float* __restrict__ h, float* __restrict__ out)
{
    const size_t i = (size_t)blockIdx.x * 256 + threadIdx.x;   // float4 index
    const size_t SP4 = (size_t)SEQ * DIM / 4;
    float4 a  = ((const float4*)h)[i];
    float4 p0 = ((const float4*)part)[i];
    float4 p1 = ((const float4*)part)[i + SP4];
    float4 p2 = ((const float4*)part)[i + 2 * SP4];
    float4 p3 = ((const float4*)part)[i + 3 * SP4];
    float4 r;
    r.x = a.x + ((p0.x + p1.x) + (p2.x + p3.x));
    r.y = a.y + ((p0.y + p1.y) + (p2.y + p3.y));
    r.z = a.z + ((p0.z + p1.z) + (p2.z + p3.z));
    r.w = a.w + ((p0.w + p1.w) + (p2.w + p3.w));
    ((float4*)out)[i] = r;
}

// ---------------- fp32 [R][C] -> bf16 [C][R] transpose-convert ----------------
__global__ __launch_bounds__(256) void convT_f32_bf16_k(
    const float* __restrict__ in, bf16* __restrict__ out, int R, int C)
{
    __shared__ float t[32][33];
    const int tx = threadIdx.x, ty = threadIdx.y;
    const int x0 = blockIdx.x * 32, y0 = blockIdx.y * 32;
#pragma unroll
    for (int i = 0; i < 4; ++i)
        t[ty + i * 8][tx] = in[(size_t)(y0 + ty + i * 8) * C + x0 + tx];
    __syncthreads();
#pragma unroll
    for (int i = 0; i < 4; ++i)
        out[(size_t)(x0 + ty + i * 8) * R + y0 + tx] = __float2bfloat16(t[tx][ty + i * 8]);
}

// 3 square weights -> one [3*DIM][DIM] B^T buffer (z selects wq/wk/wv)
__global__ __launch_bounds__(256) void convT3_f32_bf16_k(
    const float* __restrict__ wq, const float* __restrict__ wk,
    const float* __restrict__ wv, bf16* __restrict__ out)
{
    const int z = blockIdx.z;
    const float* in = z == 0 ? wq : (z == 1 ? wk : wv);
    bf16* o = out + (size_t)z * DIM * DIM;
    __shared__ float t[32][33];
    const int tx = threadIdx.x, ty = threadIdx.y;
    const int x0 = blockIdx.x * 32, y0 = blockIdx.y * 32;
#pragma unroll
    for (int i = 0; i < 4; ++i)
        t[ty + i * 8][tx] = in[(size_t)(y0 + ty + i * 8) * DIM + x0 + tx];
    __syncthreads();
#pragma unroll
    for (int i = 0; i < 4; ++i)
        o[(size_t)(x0 + ty + i * 8) * DIM + y0 + tx] = __float2bfloat16(t[tx][ty + i * 8]);
}

// ---------------- bf16 transpose with src stride (vt[d][s] = in[s][d]) ----------------
__global__ __launch_bounds__(256) void transpose_bf16_k(
    const bf16* __restrict__ in, int istride, bf16* __restrict__ out)
{
    __shared__ unsigned short t[32][33];
    const int tx = threadIdx.x, ty = threadIdx.y;
    const int x = blockIdx.x * 32 + tx;       // d
    const int y0 = blockIdx.y * 32;           // s
    const unsigned short* inu = (const unsigned short*)in;
    unsigned short* outu = (unsigned short*)out;
#pragma unroll
    for (int i = 0; i < 4; ++i)
        t[ty + i * 8][tx] = inu[(size_t)(y0 + ty + i * 8) * istride + x];
    __syncthreads();
    const int x2 = blockIdx.y * 32 + tx;
    const int y2 = blockIdx.x * 32;
#pragma unroll
    for (int i = 0; i < 4; ++i)
        outu[(size_t)(y2 + ty + i * 8) * SEQ + x2] = t[tx][ty + i * 8];
}

// ---------------- RoPE in-place on strided bf16 q,k ----------------
__global__ __launch_bounds__(256) void rope_qk_k(
    bf16* __restrict__ q, bf16* __restrict__ k,
    const float* __restrict__ cosb, const float* __restrict__ sinb)
{
    const int gid = blockIdx.x * 256 + threadIdx.x;   // < SEQ * 1024
    const int s = gid >> 10;
    const int p = gid & 1023;
    const int h = p >> 6, j = p & 63;
    const size_t off = (size_t)s * SQKV + h * HEAD_DIM + 2 * j;
    const float c = cosb[s * 64 + j], sn = sinb[s * 64 + j];
    float xr = __bfloat162float(q[off]), xi = __bfloat162float(q[off + 1]);
    q[off]     = __float2bfloat16(xr * c - xi * sn);
    q[off + 1] = __float2bfloat16(xr * sn + xi * c);
    xr = __bfloat162float(k[off]); xi = __bfloat162float(k[off + 1]);
    k[off]     = __float2bfloat16(xr * c - xi * sn);
    k[off + 1] = __float2bfloat16(xr * sn + xi * c);
}

// ---------------- 256x256 8-phase GEMM (T2+T3+T4+T5), BK=64, 512 threads, split-K ----------------
// EP 0: store bf16    EP 2: Cb = silu(other)*acc (in-place ok)    EP 3: fp32 partial store
// LDS (dynamic 128KB): A halves [buf][2][128*64], B halves at +64KB (128B rows).
// Swizzle: byte ^= ((row&7)<<4)  (row = byte>>7). Uniform 8-lanes/16B-slot on every
// ds_read_b128 (the b128 floor). Involution confined to bits 4-6, so the inverse is
// applied on the GLOBAL source of global_load_lds with a linear LDS dest (rule #21).
template <int EP>
__global__ __launch_bounds__(512, 2) void gemm256_k(
    const bf16* __restrict__ A, const bf16* __restrict__ Bt,
    bf16* __restrict__ Cb, const bf16* other, float* __restrict__ Pf,
    int M, int N, int K, int gx, int ntile, int Ks)
{
    extern __shared__ char smem[];
    const int t512 = threadIdx.x;
    const int w = t512 >> 6, lane = t512 & 63;
    const int lr = lane & 15, lg = lane >> 4;
    const int wm = w >> 2, wn = w & 3;           // 2 x 4 wave grid
    const int bofs = (wn & 1) * 64;              // B row offset inside its half

    // XCD-bijective block swizzle (m204)
    const int nwg = gridDim.x;                    // = ntile * splitk
    const int q8 = nwg >> 3, r8 = nwg & 7;
    const int xcd = blockIdx.x & 7, seq = blockIdx.x >> 3;
    const int wgid = (xcd < r8 ? xcd * (q8 + 1) : r8 * (q8 + 1) + (xcd - r8) * q8) + seq;
    const int split = wgid / ntile;
    const int tile = wgid % ntile;
    const int m0 = (tile / gx) * 256, n0 = (tile % gx) * 256;
    const int kb0 = split * Ks;

    const int nt = Ks >> 6;                       // 64-wide K tiles (nt >= 2 everywhere)

    // stage one 128x64 half-tile (16KB): 2 gl16 per thread, source pre-swizzled
    auto stage_half = [&](int buf, int kt, int isB, int hs) {
        const int k0 = kb0 + (kt << 6);
        char* base = smem + (isB ? 65536 : 0) + (buf * 2 + hs) * 16384;
#pragma unroll
        for (int c = 0; c < 2; ++c) {
            const int s = (c * 512 + t512) * 16;            // linear byte slot
            const int p = s ^ (((s >> 7) & 7) << 4);        // nominal position (involution)
            const int row = p >> 7;
            const int colE = (p & 127) >> 1;
            if (isB)
                gl16(Bt + (size_t)(n0 + hs * 128 + row) * K + k0 + colE, base + s);
            else
                gl16(A  + (size_t)(m0 + hs * 128 + row) * K + k0 + colE, base + s);
        }
    };

    f32x4 acc[8][4] = {};
    bf16x8 bfr[4][2];

    // prologue: tile0 -> buf0, tile1 -> buf1 (16 loads/thread)
    stage_half(0, 0, 0, 0); stage_half(0, 0, 0, 1);
    stage_half(0, 0, 1, 0); stage_half(0, 0, 1, 1);
    stage_half(1, 1, 0, 0); stage_half(1, 1, 0, 1);
    stage_half(1, 1, 1, 0); stage_half(1, 1, 1, 1);

    for (int t = 0; t < nt; ++t) {
        const int cur = t & 1;
        // tile t+1's 8 loads are the only ones newer than tile t's -> vmcnt(8)
        if (t + 1 < nt) { asm volatile("s_waitcnt vmcnt(8)" ::: "memory"); }
        else            { asm volatile("s_waitcnt vmcnt(0)" ::: "memory"); }
        __builtin_amdgcn_sched_barrier(0);
        __builtin_amdgcn_s_barrier();

        const char* Am = smem + (cur * 2 + wm) * 16384;
        const char* Bm = smem + 65536 + (cur * 2 + (wn >> 1)) * 16384;
        const bool pf = (t + 2 < nt);

#define LDA_(mf, ks, dst) { int off = (((mf) * 16 + lr) * 128) + ((((ks) * 64) + lg * 16) ^ ((lr & 7) << 4)); \
        dst = *(const bf16x8*)(Am + off); }
#define LDB_(nf, ks, dst) { int off = ((bofs + (nf) * 16 + lr) * 128) + ((((ks) * 64) + lg * 16) ^ ((lr & 7) << 4)); \
        dst = *(const bf16x8*)(Bm + off); }
#define MFMA_PH(mf0) { \
        asm volatile("s_waitcnt lgkmcnt(0)" ::: "memory"); \
        __builtin_amdgcn_sched_barrier(0); \
        __builtin_amdgcn_s_setprio(1); \
        _Pragma("unroll") \
        for (int nf = 0; nf < 4; ++nf) { \
            acc[(mf0)][nf]     = MFMA16(a0, bfr[nf][0], acc[(mf0)][nf]); \
            acc[(mf0)][nf]     = MFMA16(a1, bfr[nf][1], acc[(mf0)][nf]); \
            acc[(mf0) + 1][nf] = MFMA16(a2, bfr[nf][0], acc[(mf0) + 1][nf]); \
            acc[(mf0) + 1][nf] = MFMA16(a3, bfr[nf][1], acc[(mf0) + 1][nf]); \
        } \
        __builtin_amdgcn_s_setprio(0); }

        bf16x8 a0, a1, a2, a3;
        // ---- phase 0: A mf0-1 + all B, 16 MFMA ----
        LDA_(0, 0, a0) LDA_(0, 1, a1) LDA_(1, 0, a2) LDA_(1, 1, a3)
#pragma unroll
        for (int nf = 0; nf < 4; ++nf) { LDB_(nf, 0, bfr[nf][0]) LDB_(nf, 1, bfr[nf][1]) }
        MFMA_PH(0)
        __builtin_amdgcn_s_barrier();            // B half0 readers done
        if (pf) stage_half(cur, t + 2, 1, 0);    // stage B half0 of tile t+2

        // ---- phase 1 ----
        LDA_(2, 0, a0) LDA_(2, 1, a1) LDA_(3, 0, a2) LDA_(3, 1, a3)
        MFMA_PH(2)
        __builtin_amdgcn_s_barrier();            // B half1 readers done
        if (pf) stage_half(cur, t + 2, 1, 1);    // stage B half1

        // ---- phase 2 ----
        LDA_(4, 0, a0) LDA_(4, 1, a1) LDA_(5, 0, a2) LDA_(5, 1, a3)
        MFMA_PH(4)

        // ---- phase 3 ----
        LDA_(6, 0, a0) LDA_(6, 1, a1) LDA_(7, 0, a2) LDA_(7, 1, a3)
        MFMA_PH(6)
        __builtin_amdgcn_s_barrier();            // all A reads of this tile done
        if (pf) { stage_half(cur, t + 2, 0, 0); stage_half(cur, t + 2, 0, 1); }
#undef LDA_
#undef LDB_
#undef MFMA_PH
    }

    // ---- epilogue ----
    float* pf_base = Pf + (size_t)split * M * N;
#pragma unroll
    for (int mf = 0; mf < 8; ++mf)
#pragma unroll
        for (int nf = 0; nf < 4; ++nf) {
            const int row = m0 + wm * 128 + mf * 16 + lg * 4;
            const int col = n0 + wn * 64 + nf * 16 + lr;
#pragma unroll
            for (int r = 0; r < 4; ++r) {
                const size_t idx = (size_t)(row + r) * N + col;
                const float v = acc[mf][nf][r];
                if (EP == 0) {
                    Cb[idx] = __float2bfloat16(v);
                } else if (EP == 2) {
                    const float gg = __bfloat162float(other[idx]);
                    const float sg = gg / (1.0f + __expf(-gg));
                    Cb[idx] = __float2bfloat16(sg * v);
                } else {
                    pf_base[idx] = v;
                }
            }
        }
}

// ---------------- causal flash attention: QBLK=64 (4 waves x 16 rows), shared KV tiles ----------------
__global__ __launch_bounds__(256) void attn_fwd_k(
    const bf16* __restrict__ qkv, const bf16* __restrict__ vT, bf16* __restrict__ ctx)
{
    const int tid = threadIdx.x;
    const int w = tid >> 6, lane = tid & 63;
    const int lr = lane & 15, lg = lane >> 4;
    const int h = blockIdx.y;
    const int qidx = (blockIdx.y < 8) ? blockIdx.x : (31 - blockIdx.x);
    const int q0b = qidx * 64;
    const int nt = qidx + 1;                  // 64-row KV tiles (causal)

    __shared__ __align__(16) unsigned short Kt[2][64 * 128];
    __shared__ __align__(16) unsigned short Vt[2][128 * 64];
    __shared__ __align__(16) unsigned short Pp[4][16 * 64];

    const char* kbase = (const char*)(qkv + DIM + h * HEAD_DIM);
    const char* vbase = (const char*)(vT + (size_t)h * HEAD_DIM * SEQ);

    const int krow_c = tid >> 4;
    const int kcolB  = (tid & 15) * 16;
    const int vrow_c = tid >> 3;
    const int vcolB  = (tid & 7) * 16;

    auto stage = [&](int buf, int kb) {
#pragma unroll
        for (int c = 0; c < 4; ++c) {
            const int r = c * 16 + krow_c;
            gl16(kbase + (size_t)(kb + r) * (SQKV * 2) + (kcolB ^ ((r & 7) << 4)),
                 &Kt[buf][c * 2048 + tid * 8]);
        }
#pragma unroll
        for (int c = 0; c < 4; ++c) {
            const int r = c * 32 + vrow_c;
            gl16(vbase + (size_t)r * (SEQ * 2) + kb * 2 + (vcolB ^ ((r & 7) << 4)),
                 &Vt[buf][c * 2048 + tid * 8]);
        }
    };

    bf16x8 qf[4];
    const bf16* qrow = qkv + (size_t)(q0b + w * 16 + lr) * SQKV + h * HEAD_DIM;
#pragma unroll
    for (int dt = 0; dt < 4; ++dt)
        qf[dt] = *(const bf16x8*)(qrow + dt * 32 + lg * 8);

    f32x4 o[8] = {};
    float m[4], l[4];
#pragma unroll
    for (int j = 0; j < 4; ++j) { m[j] = -3e38f; l[j] = 0.0f; }
    const float scale = 0.08838834764831845f;

    stage(0, 0);
    __syncthreads();

    int cur = 0;
    for (int t = 0; t < nt; ++t) {
        const int kb = t * 64;
        if (t + 1 < nt) stage(cur ^ 1, kb + 64);

        f32x4 s[4] = {};
        __builtin_amdgcn_s_setprio(1);
#pragma unroll
        for (int ss = 0; ss < 4; ++ss) {
            const int r = ss * 16 + lr;
            const int sw = (r & 7) << 3;
#pragma unroll
            for (int dt = 0; dt < 4; ++dt) {
                bf16x8 kf = *(const bf16x8*)&Kt[cur][r * 128 + ((dt * 32 + lg * 8) ^ sw)];
                s[ss] = MFMA16(qf[dt], kf, s[ss]);
            }
        }
        __builtin_amdgcn_s_setprio(0);

        float al[4];
#pragma unroll
        for (int j = 0; j < 4; ++j) {
            const int qi = q0b + w * 16 + lg * 4 + j;
            const int prow = lg * 4 + j;
            const int psw = (prow & 7) << 3;
            float a[4];
#pragma unroll
            for (int ss = 0; ss < 4; ++ss)
                a[ss] = s[ss][j] * scale + ((kb + ss * 16 + lr) > qi ? -1e9f : 0.0f);
            float mx = fmaxf(fmaxf(a[0], a[1]), fmaxf(a[2], a[3]));
            mx = fmaxf(mx, __shfl_xor(mx, 1));
            mx = fmaxf(mx, __shfl_xor(mx, 2));
            mx = fmaxf(mx, __shfl_xor(mx, 4));
            mx = fmaxf(mx, __shfl_xor(mx, 8));
            const float mn = fmaxf(m[j], mx);
            const float asc = __expf(m[j] - mn);
            float e0 = __expf(a[0] - mn), e1 = __expf(a[1] - mn);
            float e2 = __expf(a[2] - mn), e3 = __expf(a[3] - mn);
            float rs = (e0 + e1) + (e2 + e3);
            rs += __shfl_xor(rs, 1); rs += __shfl_xor(rs, 2);
            rs += __shfl_xor(rs, 4); rs += __shfl_xor(rs, 8);
            l[j] = l[j] * asc + rs;
            m[j] = mn;
            al[j] = asc;
            Pp[w][prow * 64 + ((lr)      ^ psw)] = f2bu(e0);
            Pp[w][prow * 64 + ((16 + lr) ^ psw)] = f2bu(e1);
            Pp[w][prow * 64 + ((32 + lr) ^ psw)] = f2bu(e2);
            Pp[w][prow * 64 + ((48 + lr) ^ psw)] = f2bu(e3);
        }
#pragma unroll
        for (int d2 = 0; d2 < 8; ++d2)
#pragma unroll
            for (int j = 0; j < 4; ++j) o[d2][j] *= al[j];

        asm volatile("s_waitcnt lgkmcnt(0)" ::: "memory");
        __builtin_amdgcn_sched_barrier(0);
        const int asw = (lr & 7) << 3;
        bf16x8 pa0 = *(const bf16x8*)&Pp[w][lr * 64 + ((lg * 8)      ^ asw)];
        bf16x8 pa1 = *(const bf16x8*)&Pp[w][lr * 64 + ((32 + lg * 8) ^ asw)];

        __builtin_amdgcn_s_setprio(1);
#pragma unroll
        for (int d2 = 0; d2 < 8; ++d2) {
            const int rv = d2 * 16 + lr;
            const int vsw = (rv & 7) << 3;
            bf16x8 vf0 = *(const bf16x8*)&Vt[cur][rv * 64 + ((lg * 8)      ^ vsw)];
            bf16x8 vf1 = *(const bf16x8*)&Vt[cur][rv * 64 + ((32 + lg * 8) ^ vsw)];
            o[d2] = MFMA16(pa0, vf0, o[d2]);
            o[d2] = MFMA16(pa1, vf1, o[d2]);
        }
        __builtin_amdgcn_s_setprio(0);

        __syncthreads();
        cur ^= 1;
    }

#pragma unroll
    for (int j = 0; j < 4; ++j) {
        const float inv = 1.0f / l[j];
        bf16* dst = ctx + (size_t)(q0b + w * 16 + lg * 4 + j) * DIM + h * HEAD_DIM + lr;
#pragma unroll
        for (int d2 = 0; d2 < 8; ++d2)
            dst[d2 * 16] = __float2bfloat16(o[d2][j] * inv);
    }
}

// ---------------- host ----------------
extern "C" void kernel_launch(void* const* d_in, const int* in_sizes, int n_in,
                              void* d_out, int out_size, void* d_ws, size_t ws_size,
                              hipStream_t stream)
{
    const float* x   = (const float*)d_in[0];
    const float* fc  = (const float*)d_in[1];
    const float* fs  = (const float*)d_in[2];
    // d_in[3] = mask (unused; causal computed analytically)
    const float* wq  = (const float*)d_in[4];
    const float* wk  = (const float*)d_in[5];
    const float* wv  = (const float*)d_in[6];
    const float* wo  = (const float*)d_in[7];
    const float* w1  = (const float*)d_in[8];
    const float* w2  = (const float*)d_in[9];
    const float* w3  = (const float*)d_in[10];
    const float* anw = (const float*)d_in[11];
    const float* fnw = (const float*)d_in[12];
    float* out = (float*)d_out;

    char* p = (char*)d_ws;
    auto alloc = [&](size_t n) { char* r = p; p += (n + 255) & ~(size_t)255; return r; };
    bf16* wT  = (bf16*)alloc((size_t)HID * DIM * 2);     // reused per weight group
    bf16* hn  = (bf16*)alloc((size_t)SEQ * DIM * 2);
    bf16* qkv = (bf16*)alloc((size_t)SEQ * SQKV * 2);    // fused q|k|v, stride 6144
    bf16* vt  = (bf16*)alloc((size_t)SEQ * DIM * 2);
    bf16* ctx = (bf16*)alloc((size_t)SEQ * DIM * 2);
    bf16* fn  = (bf16*)alloc((size_t)SEQ * DIM * 2);
    float* h  = (float*)alloc((size_t)SEQ * DIM * 4);
    bf16* g   = (bf16*)alloc((size_t)SEQ * HID * 2);
    float* sk = (float*)alloc((size_t)4 * SEQ * DIM * 4);  // split-K partials (64MB)

    const dim3 tb32(32, 8);
    const int LDS256 = 131072;
    (void)hipFuncSetAttribute((const void*)gemm256_k<0>,
        hipFuncAttributeMaxDynamicSharedMemorySize, LDS256);
    (void)hipFuncSetAttribute((const void*)gemm256_k<2>,
        hipFuncAttributeMaxDynamicSharedMemorySize, LDS256);
    (void)hipFuncSetAttribute((const void*)gemm256_k<3>,
        hipFuncAttributeMaxDynamicSharedMemorySize, LDS256);

    rmsnorm_bf16_k<<<SEQ, 256, 0, stream>>>(x, anw, hn);

    // fused QKV: wT = [wq^T; wk^T; wv^T] (6144x2048) -> qkv[2048][6144]
    convT3_f32_bf16_k<<<dim3(DIM / 32, DIM / 32, 3), tb32, 0, stream>>>(wq, wk, wv, wT);
    gemm256_k<0><<<(SEQ / 256) * (SQKV / 256), 512, LDS256, stream>>>(
        hn, wT, qkv, nullptr, nullptr, SEQ, SQKV, DIM, SQKV / 256, (SEQ / 256) * (SQKV / 256), DIM);

    rope_qk_k<<<(SEQ * 1024) / 256, 256, 0, stream>>>(qkv, qkv + DIM, fc, fs);
    transpose_bf16_k<<<dim3(DIM / 32, SEQ / 32), tb32, 0, stream>>>(qkv + 2 * DIM, SQKV, vt);

    attn_fwd_k<<<dim3(SEQ / 64, N_HEADS), 256, 0, stream>>>(qkv, vt, ctx);

    // h = x + ctx @ wo : split-K=4 (Ks=512) -> partials, fused reduce+residual+rmsnorm
    convT_f32_bf16_k<<<dim3(DIM / 32, DIM / 32), tb32, 0, stream>>>(wo, wT, DIM, DIM);
    gemm256_k<3><<<(SEQ / 256) * (DIM / 256) * 4, 512, LDS256, stream>>>(
        ctx, wT, nullptr, nullptr, sk, SEQ, DIM, DIM, DIM / 256, (SEQ / 256) * (DIM / 256), 512);
    rmsnorm4_k<<<SEQ, 256, 0, stream>>>(sk, x, fnw, h, fn);

    convT_f32_bf16_k<<<dim3(HID / 32, DIM / 32), tb32, 0, stream>>>(w1, wT, DIM, HID);
    gemm256_k<0><<<(SEQ / 256) * (HID / 256), 512, LDS256, stream>>>(
        fn, wT, g, nullptr, nullptr, SEQ, HID, DIM, HID / 256, (SEQ / 256) * (HID / 256), DIM);
    convT_f32_bf16_k<<<dim3(HID / 32, DIM / 32), tb32, 0, stream>>>(w3, wT, DIM, HID);
    gemm256_k<2><<<(SEQ / 256) * (HID / 256), 512, LDS256, stream>>>(
        fn, wT, g, g, nullptr, SEQ, HID, DIM, HID / 256, (SEQ / 256) * (HID / 256), DIM);

    // out = h + g @ w2 : split-K=4 (Ks=2048) -> partials, reduce+residual
    convT_f32_bf16_k<<<dim3(DIM / 32, HID / 32), tb32, 0, stream>>>(w2, wT, HID, DIM);
    gemm256_k<3><<<(SEQ / 256) * (DIM / 256) * 4, 512, LDS256, stream>>>(
        g, wT, nullptr, nullptr, sk, SEQ, DIM, HID, DIM / 256, (SEQ / 256) * (DIM / 256), 2048);
    reduce4_k<<<(SEQ * DIM / 4) / 256, 256, 0, stream>>>(sk, h, out);
}

// Round 8
// 521.578 us; speedup vs baseline: 1.9434x; 1.0133x over previous
//
#include <hip/hip_runtime.h>
#include <hip/hip_bf16.h>

#define DIM 2048
#define HEAD_DIM 128
#define N_HEADS 16
#define SEQ 2048
#define HID 8192
#define SQKV 6144   // row stride of fused qkv activation

typedef short bf16x8 __attribute__((ext_vector_type(8)));
typedef float f32x4 __attribute__((ext_vector_type(4)));
using bf16 = __hip_bfloat16;

#define MFMA16(a, b, c) __builtin_amdgcn_mfma_f32_16x16x32_bf16(a, b, c, 0, 0, 0)

__device__ __forceinline__ unsigned short f2bu(float f) {
    union { bf16 b; unsigned short u; } cv;
    cv.b = __float2bfloat16(f);
    return cv.u;
}

// async global -> LDS, 16B per lane (dest must be lane-linear per wave)
__device__ __forceinline__ void gl16(const void* g, void* l) {
    __builtin_amdgcn_global_load_lds(
        (const __attribute__((address_space(1))) unsigned int*)g,
        (__attribute__((address_space(3))) unsigned int*)l, 16, 0, 0);
}

// ---------------- rmsnorm (fp32 in -> bf16 out) ----------------
__global__ __launch_bounds__(256) void rmsnorm_bf16_k(
    const float* __restrict__ x, const float* __restrict__ w, bf16* __restrict__ y)
{
    const int row = blockIdx.x;
    const int tid = threadIdx.x;
    const float* xr = x + (size_t)row * DIM;
    float4 v0 = ((const float4*)xr)[tid];
    float4 v1 = ((const float4*)xr)[tid + 256];
    float ss = v0.x*v0.x + v0.y*v0.y + v0.z*v0.z + v0.w*v0.w
             + v1.x*v1.x + v1.y*v1.y + v1.z*v1.z + v1.w*v1.w;
    for (int o = 32; o > 0; o >>= 1) ss += __shfl_down(ss, o);
    __shared__ float red[4];
    if ((tid & 63) == 0) red[tid >> 6] = ss;
    __syncthreads();
    float tot = red[0] + red[1] + red[2] + red[3];
    float r = rsqrtf(tot * (1.0f / DIM) + 1e-6f);
    float4 w0 = ((const float4*)w)[tid];
    float4 w1 = ((const float4*)w)[tid + 256];
    ushort4 o0, o1;
    o0.x = f2bu(v0.x * r * w0.x); o0.y = f2bu(v0.y * r * w0.y);
    o0.z = f2bu(v0.z * r * w0.z); o0.w = f2bu(v0.w * r * w0.w);
    o1.x = f2bu(v1.x * r * w1.x); o1.y = f2bu(v1.y * r * w1.y);
    o1.z = f2bu(v1.z * r * w1.z); o1.w = f2bu(v1.w * r * w1.w);
    ushort4* yr = (ushort4*)(y + (size_t)row * DIM);
    yr[tid] = o0;
    yr[tid + 256] = o1;
}

// ---------------- split-K reduce + residual + rmsnorm (fp32 h out, bf16 fn out) ----------------
__global__ __launch_bounds__(256) void rmsnorm4_k(
    const float* __restrict__ part, const float* __restrict__ x,
    const float* __restrict__ w, float* __restrict__ hout, bf16* __restrict__ y)
{
    const int row = blockIdx.x;
    const int tid = threadIdx.x;
    const size_t base = (size_t)row * DIM;
    const size_t SP = (size_t)SEQ * DIM;
    float4 r0, r1;
    float ss = 0.0f;
    {
        float4 a  = ((const float4*)(x + base))[tid];
        float4 p0 = ((const float4*)(part + base))[tid];
        float4 p1 = ((const float4*)(part + SP + base))[tid];
        float4 p2 = ((const float4*)(part + 2 * SP + base))[tid];
        float4 p3 = ((const float4*)(part + 3 * SP + base))[tid];
        r0.x = a.x + ((p0.x + p1.x) + (p2.x + p3.x));
        r0.y = a.y + ((p0.y + p1.y) + (p2.y + p3.y));
        r0.z = a.z + ((p0.z + p1.z) + (p2.z + p3.z));
        r0.w = a.w + ((p0.w + p1.w) + (p2.w + p3.w));
        ((float4*)(hout + base))[tid] = r0;
        ss += r0.x*r0.x + r0.y*r0.y + r0.z*r0.z + r0.w*r0.w;
    }
    {
        const int t2 = tid + 256;
        float4 a  = ((const float4*)(x + base))[t2];
        float4 p0 = ((const float4*)(part + base))[t2];
        float4 p1 = ((const float4*)(part + SP + base))[t2];
        float4 p2 = ((const float4*)(part + 2 * SP + base))[t2];
        float4 p3 = ((const float4*)(part + 3 * SP + base))[t2];
        r1.x = a.x + ((p0.x + p1.x) + (p2.x + p3.x));
        r1.y = a.y + ((p0.y + p1.y) + (p2.y + p3.y));
        r1.z = a.z + ((p0.z + p1.z) + (p2.z + p3.z));
        r1.w = a.w + ((p0.w + p1.w) + (p2.w + p3.w));
        ((float4*)(hout + base))[t2] = r1;
        ss += r1.x*r1.x + r1.y*r1.y + r1.z*r1.z + r1.w*r1.w;
    }
    for (int o = 32; o > 0; o >>= 1) ss += __shfl_down(ss, o);
    __shared__ float red[4];
    if ((tid & 63) == 0) red[tid >> 6] = ss;
    __syncthreads();
    float tot = red[0] + red[1] + red[2] + red[3];
    float r = rsqrtf(tot * (1.0f / DIM) + 1e-6f);
    float4 w0 = ((const float4*)w)[tid];
    float4 w1 = ((const float4*)w)[tid + 256];
    ushort4 o0, o1;
    o0.x = f2bu(r0.x * r * w0.x); o0.y = f2bu(r0.y * r * w0.y);
    o0.z = f2bu(r0.z * r * w0.z); o0.w = f2bu(r0.w * r * w0.w);
    o1.x = f2bu(r1.x * r * w1.x); o1.y = f2bu(r1.y * r * w1.y);
    o1.z = f2bu(r1.z * r * w1.z); o1.w = f2bu(r1.w * r * w1.w);
    ushort4* yr = (ushort4*)(y + base);
    yr[tid] = o0;
    yr[tid + 256] = o1;
}

// ---------------- split-K reduce + residual (fp32 out) ----------------
__global__ __launch_bounds__(256) void reduce4_k(
    const float* __restrict__ part, const float* __restrict__ h, float* __restrict__ out)
{
    const size_t i = (size_t)blockIdx.x * 256 + threadIdx.x;   // float4 index
    const size_t SP4 = (size_t)SEQ * DIM / 4;
    float4 a  = ((const float4*)h)[i];
    float4 p0 = ((const float4*)part)[i];
    float4 p1 = ((const float4*)part)[i + SP4];
    float4 p2 = ((const float4*)part)[i + 2 * SP4];
    float4 p3 = ((const float4*)part)[i + 3 * SP4];
    float4 r;
    r.x = a.x + ((p0.x + p1.x) + (p2.x + p3.x));
    r.y = a.y + ((p0.y + p1.y) + (p2.y + p3.y));
    r.z = a.z + ((p0.z + p1.z) + (p2.z + p3.z));
    r.w = a.w + ((p0.w + p1.w) + (p2.w + p3.w));
    ((float4*)out)[i] = r;
}

// ---------------- fp32 [R][C] -> bf16 [C][R] transpose-convert ----------------
__global__ __launch_bounds__(256) void convT_f32_bf16_k(
    const float* __restrict__ in, bf16* __restrict__ out, int R, int C)
{
    __shared__ float t[32][33];
    const int tx = threadIdx.x, ty = threadIdx.y;
    const int x0 = blockIdx.x * 32, y0 = blockIdx.y * 32;
#pragma unroll
    for (int i = 0; i < 4; ++i)
        t[ty + i * 8][tx] = in[(size_t)(y0 + ty + i * 8) * C + x0 + tx];
    __syncthreads();
#pragma unroll
    for (int i = 0; i < 4; ++i)
        out[(size_t)(x0 + ty + i * 8) * R + y0 + tx] = __float2bfloat16(t[tx][ty + i * 8]);
}

// 3 square weights -> one [3*DIM][DIM] B^T buffer (z selects wq/wk/wv)
__global__ __launch_bounds__(256) void convT3_f32_bf16_k(
    const float* __restrict__ wq, const float* __restrict__ wk,
    const float* __restrict__ wv, bf16* __restrict__ out)
{
    const int z = blockIdx.z;
    const float* in = z == 0 ? wq : (z == 1 ? wk : wv);
    bf16* o = out + (size_t)z * DIM * DIM;
    __shared__ float t[32][33];
    const int tx = threadIdx.x, ty = threadIdx.y;
    const int x0 = blockIdx.x * 32, y0 = blockIdx.y * 32;
#pragma unroll
    for (int i = 0; i < 4; ++i)
        t[ty + i * 8][tx] = in[(size_t)(y0 + ty + i * 8) * DIM + x0 + tx];
    __syncthreads();
#pragma unroll
    for (int i = 0; i < 4; ++i)
        o[(size_t)(x0 + ty + i * 8) * DIM + y0 + tx] = __float2bfloat16(t[tx][ty + i * 8]);
}

// ---------------- bf16 transpose with src stride (vt[d][s] = in[s][d]) ----------------
__global__ __launch_bounds__(256) void transpose_bf16_k(
    const bf16* __restrict__ in, int istride, bf16* __restrict__ out)
{
    __shared__ unsigned short t[32][33];
    const int tx = threadIdx.x, ty = threadIdx.y;
    const int x = blockIdx.x * 32 + tx;       // d
    const int y0 = blockIdx.y * 32;           // s
    const unsigned short* inu = (const unsigned short*)in;
    unsigned short* outu = (unsigned short*)out;
#pragma unroll
    for (int i = 0; i < 4; ++i)
        t[ty + i * 8][tx] = inu[(size_t)(y0 + ty + i * 8) * istride + x];
    __syncthreads();
    const int x2 = blockIdx.y * 32 + tx;
    const int y2 = blockIdx.x * 32;
#pragma unroll
    for (int i = 0; i < 4; ++i)
        outu[(size_t)(y2 + ty + i * 8) * SEQ + x2] = t[tx][ty + i * 8];
}

// ---------------- RoPE in-place on strided bf16 q,k ----------------
__global__ __launch_bounds__(256) void rope_qk_k(
    bf16* __restrict__ q, bf16* __restrict__ k,
    const float* __restrict__ cosb, const float* __restrict__ sinb)
{
    const int gid = blockIdx.x * 256 + threadIdx.x;   // < SEQ * 1024
    const int s = gid >> 10;
    const int p = gid & 1023;
    const int h = p >> 6, j = p & 63;
    const size_t off = (size_t)s * SQKV + h * HEAD_DIM + 2 * j;
    const float c = cosb[s * 64 + j], sn = sinb[s * 64 + j];
    float xr = __bfloat162float(q[off]), xi = __bfloat162float(q[off + 1]);
    q[off]     = __float2bfloat16(xr * c - xi * sn);
    q[off + 1] = __float2bfloat16(xr * sn + xi * c);
    xr = __bfloat162float(k[off]); xi = __bfloat162float(k[off + 1]);
    k[off]     = __float2bfloat16(xr * c - xi * sn);
    k[off + 1] = __float2bfloat16(xr * sn + xi * c);
}

// ---------------- 256x256 8-phase GEMM (T2+T3+T4+T5), BK=64, 512 threads, split-K ----------------
// EP 0: store bf16    EP 2: Cb = silu(other)*acc (in-place ok)    EP 3: fp32 partial store
// LDS (dynamic 128KB): A halves [buf][2][128*64], B halves at +64KB (128B rows).
// Swizzle: byte ^= ((row&7)<<4); inverse applied on global src of global_load_lds (rule #21).
// Tile map: GROUP_M=4 supertiling so each XCD's contiguous wgid chunk is a compact
// 4m x ~8n region -> per-XCD operand footprint fits L2, B partitions across XCDs.
template <int EP>
__global__ __launch_bounds__(512, 2) void gemm256_k(
    const bf16* __restrict__ A, const bf16* __restrict__ Bt,
    bf16* __restrict__ Cb, const bf16* other, float* __restrict__ Pf,
    int M, int N, int K, int gx, int ntile, int Ks)
{
    extern __shared__ char smem[];
    const int t512 = threadIdx.x;
    const int w = t512 >> 6, lane = t512 & 63;
    const int lr = lane & 15, lg = lane >> 4;
    const int wm = w >> 2, wn = w & 3;           // 2 x 4 wave grid
    const int bofs = (wn & 1) * 64;              // B row offset inside its half

    // XCD-bijective block swizzle (m204)
    const int nwg = gridDim.x;                    // = ntile * splitk
    const int q8 = nwg >> 3, r8 = nwg & 7;
    const int xcd = blockIdx.x & 7, seq = blockIdx.x >> 3;
    const int wgid = (xcd < r8 ? xcd * (q8 + 1) : r8 * (q8 + 1) + (xcd - r8) * q8) + seq;
    const int split = wgid / ntile;
    const int tile = wgid % ntile;
    // GROUP_M=4 supertiling (requires M/256 divisible by 4 -- true for all uses)
    const int grp = tile / (4 * gx), rem = tile % (4 * gx);
    const int m0 = (grp * 4 + (rem & 3)) * 256, n0 = (rem >> 2) * 256;
    const int kb0 = split * Ks;

    const int nt = Ks >> 6;                       // 64-wide K tiles (nt >= 2 everywhere)

    // stage one 128x64 half-tile (16KB): 2 gl16 per thread, source pre-swizzled
    auto stage_half = [&](int buf, int kt, int isB, int hs) {
        const int k0 = kb0 + (kt << 6);
        char* base = smem + (isB ? 65536 : 0) + (buf * 2 + hs) * 16384;
#pragma unroll
        for (int c = 0; c < 2; ++c) {
            const int s = (c * 512 + t512) * 16;            // linear byte slot
            const int p = s ^ (((s >> 7) & 7) << 4);        // nominal position (involution)
            const int row = p >> 7;
            const int colE = (p & 127) >> 1;
            if (isB)
                gl16(Bt + (size_t)(n0 + hs * 128 + row) * K + k0 + colE, base + s);
            else
                gl16(A  + (size_t)(m0 + hs * 128 + row) * K + k0 + colE, base + s);
        }
    };

    f32x4 acc[8][4] = {};
    bf16x8 bfr[4][2];

    // prologue: tile0 -> buf0, tile1 -> buf1 (16 loads/thread)
    stage_half(0, 0, 0, 0); stage_half(0, 0, 0, 1);
    stage_half(0, 0, 1, 0); stage_half(0, 0, 1, 1);
    stage_half(1, 1, 0, 0); stage_half(1, 1, 0, 1);
    stage_half(1, 1, 1, 0); stage_half(1, 1, 1, 1);

    for (int t = 0; t < nt; ++t) {
        const int cur = t & 1;
        // tile t+1's 8 loads are the only ones newer than tile t's -> vmcnt(8)
        if (t + 1 < nt) { asm volatile("s_waitcnt vmcnt(8)" ::: "memory"); }
        else            { asm volatile("s_waitcnt vmcnt(0)" ::: "memory"); }
        __builtin_amdgcn_sched_barrier(0);
        __builtin_amdgcn_s_barrier();

        const char* Am = smem + (cur * 2 + wm) * 16384;
        const char* Bm = smem + 65536 + (cur * 2 + (wn >> 1)) * 16384;
        const bool pf = (t + 2 < nt);

#define LDA_(mf, ks, dst) { int off = (((mf) * 16 + lr) * 128) + ((((ks) * 64) + lg * 16) ^ ((lr & 7) << 4)); \
        dst = *(const bf16x8*)(Am + off); }
#define LDB_(nf, ks, dst) { int off = ((bofs + (nf) * 16 + lr) * 128) + ((((ks) * 64) + lg * 16) ^ ((lr & 7) << 4)); \
        dst = *(const bf16x8*)(Bm + off); }
#define MFMA_PH(mf0) { \
        asm volatile("s_waitcnt lgkmcnt(0)" ::: "memory"); \
        __builtin_amdgcn_sched_barrier(0); \
        __builtin_amdgcn_s_setprio(1); \
        _Pragma("unroll") \
        for (int nf = 0; nf < 4; ++nf) { \
            acc[(mf0)][nf]     = MFMA16(a0, bfr[nf][0], acc[(mf0)][nf]); \
            acc[(mf0)][nf]     = MFMA16(a1, bfr[nf][1], acc[(mf0)][nf]); \
            acc[(mf0) + 1][nf] = MFMA16(a2, bfr[nf][0], acc[(mf0) + 1][nf]); \
            acc[(mf0) + 1][nf] = MFMA16(a3, bfr[nf][1], acc[(mf0) + 1][nf]); \
        } \
        __builtin_amdgcn_s_setprio(0); }

        bf16x8 a0, a1, a2, a3;
        // ---- phase 0: A mf0-1 + all B, 16 MFMA ----
        LDA_(0, 0, a0) LDA_(0, 1, a1) LDA_(1, 0, a2) LDA_(1, 1, a3)
#pragma unroll
        for (int nf = 0; nf < 4; ++nf) { LDB_(nf, 0, bfr[nf][0]) LDB_(nf, 1, bfr[nf][1]) }
        MFMA_PH(0)
        __builtin_amdgcn_s_barrier();            // B half0 readers done
        if (pf) stage_half(cur, t + 2, 1, 0);    // stage B half0 of tile t+2

        // ---- phase 1 ----
        LDA_(2, 0, a0) LDA_(2, 1, a1) LDA_(3, 0, a2) LDA_(3, 1, a3)
        MFMA_PH(2)
        __builtin_amdgcn_s_barrier();            // B half1 readers done
        if (pf) stage_half(cur, t + 2, 1, 1);    // stage B half1

        // ---- phase 2 ----
        LDA_(4, 0, a0) LDA_(4, 1, a1) LDA_(5, 0, a2) LDA_(5, 1, a3)
        MFMA_PH(4)

        // ---- phase 3 ----
        LDA_(6, 0, a0) LDA_(6, 1, a1) LDA_(7, 0, a2) LDA_(7, 1, a3)
        MFMA_PH(6)
        __builtin_amdgcn_s_barrier();            // all A reads of this tile done
        if (pf) { stage_half(cur, t + 2, 0, 0); stage_half(cur, t + 2, 0, 1); }
#undef LDA_
#undef LDB_
#undef MFMA_PH
    }

    // ---- epilogue ----
    float* pf_base = Pf + (size_t)split * M * N;
#pragma unroll
    for (int mf = 0; mf < 8; ++mf)
#pragma unroll
        for (int nf = 0; nf < 4; ++nf) {
            const int row = m0 + wm * 128 + mf * 16 + lg * 4;
            const int col = n0 + wn * 64 + nf * 16 + lr;
#pragma unroll
            for (int r = 0; r < 4; ++r) {
                const size_t idx = (size_t)(row + r) * N + col;
                const float v = acc[mf][nf][r];
                if (EP == 0) {
                    Cb[idx] = __float2bfloat16(v);
                } else if (EP == 2) {
                    const float gg = __bfloat162float(other[idx]);
                    const float sg = gg / (1.0f + __expf(-gg));
                    Cb[idx] = __float2bfloat16(sg * v);
                } else {
                    pf_base[idx] = v;
                }
            }
        }
}

// ---------------- causal flash attention: QBLK=64 (4 waves x 16 rows), shared KV tiles ----------------
__global__ __launch_bounds__(256) void attn_fwd_k(
    const bf16* __restrict__ qkv, const bf16* __restrict__ vT, bf16* __restrict__ ctx)
{
    const int tid = threadIdx.x;
    const int w = tid >> 6, lane = tid & 63;
    const int lr = lane & 15, lg = lane >> 4;
    const int h = blockIdx.y;
    const int qidx = (blockIdx.y < 8) ? blockIdx.x : (31 - blockIdx.x);
    const int q0b = qidx * 64;
    const int nt = qidx + 1;                  // 64-row KV tiles (causal)

    __shared__ __align__(16) unsigned short Kt[2][64 * 128];
    __shared__ __align__(16) unsigned short Vt[2][128 * 64];
    __shared__ __align__(16) unsigned short Pp[4][16 * 64];

    const char* kbase = (const char*)(qkv + DIM + h * HEAD_DIM);
    const char* vbase = (const char*)(vT + (size_t)h * HEAD_DIM * SEQ);

    const int krow_c = tid >> 4;
    const int kcolB  = (tid & 15) * 16;
    const int vrow_c = tid >> 3;
    const int vcolB  = (tid & 7) * 16;

    auto stage = [&](int buf, int kb) {
#pragma unroll
        for (int c = 0; c < 4; ++c) {
            const int r = c * 16 + krow_c;
            gl16(kbase + (size_t)(kb + r) * (SQKV * 2) + (kcolB ^ ((r & 7) << 4)),
                 &Kt[buf][c * 2048 + tid * 8]);
        }
#pragma unroll
        for (int c = 0; c < 4; ++c) {
            const int r = c * 32 + vrow_c;
            gl16(vbase + (size_t)r * (SEQ * 2) + kb * 2 + (vcolB ^ ((r & 7) << 4)),
                 &Vt[buf][c * 2048 + tid * 8]);
        }
    };

    bf16x8 qf[4];
    const bf16* qrow = qkv + (size_t)(q0b + w * 16 + lr) * SQKV + h * HEAD_DIM;
#pragma unroll
    for (int dt = 0; dt < 4; ++dt)
        qf[dt] = *(const bf16x8*)(qrow + dt * 32 + lg * 8);

    f32x4 o[8] = {};
    float m[4], l[4];
#pragma unroll
    for (int j = 0; j < 4; ++j) { m[j] = -3e38f; l[j] = 0.0f; }
    const float scale = 0.08838834764831845f;

    stage(0, 0);
    __syncthreads();

    int cur = 0;
    for (int t = 0; t < nt; ++t) {
        const int kb = t * 64;
        if (t + 1 < nt) stage(cur ^ 1, kb + 64);

        f32x4 s[4] = {};
        __builtin_amdgcn_s_setprio(1);
#pragma unroll
        for (int ss = 0; ss < 4; ++ss) {
            const int r = ss * 16 + lr;
            const int sw = (r & 7) << 3;
#pragma unroll
            for (int dt = 0; dt < 4; ++dt) {
                bf16x8 kf = *(const bf16x8*)&Kt[cur][r * 128 + ((dt * 32 + lg * 8) ^ sw)];
                s[ss] = MFMA16(qf[dt], kf, s[ss]);
            }
        }
        __builtin_amdgcn_s_setprio(0);

        float al[4];
#pragma unroll
        for (int j = 0; j < 4; ++j) {
            const int qi = q0b + w * 16 + lg * 4 + j;
            const int prow = lg * 4 + j;
            const int psw = (prow & 7) << 3;
            float a[4];
#pragma unroll
            for (int ss = 0; ss < 4; ++ss)
                a[ss] = s[ss][j] * scale + ((kb + ss * 16 + lr) > qi ? -1e9f : 0.0f);
            float mx = fmaxf(fmaxf(a[0], a[1]), fmaxf(a[2], a[3]));
            mx = fmaxf(mx, __shfl_xor(mx, 1));
            mx = fmaxf(mx, __shfl_xor(mx, 2));
            mx = fmaxf(mx, __shfl_xor(mx, 4));
            mx = fmaxf(mx, __shfl_xor(mx, 8));
            const float mn = fmaxf(m[j], mx);
            const float asc = __expf(m[j] - mn);
            float e0 = __expf(a[0] - mn), e1 = __expf(a[1] - mn);
            float e2 = __expf(a[2] - mn), e3 = __expf(a[3] - mn);
            float rs = (e0 + e1) + (e2 + e3);
            rs += __shfl_xor(rs, 1); rs += __shfl_xor(rs, 2);
            rs += __shfl_xor(rs, 4); rs += __shfl_xor(rs, 8);
            l[j] = l[j] * asc + rs;
            m[j] = mn;
            al[j] = asc;
            Pp[w][prow * 64 + ((lr)      ^ psw)] = f2bu(e0);
            Pp[w][prow * 64 + ((16 + lr) ^ psw)] = f2bu(e1);
            Pp[w][prow * 64 + ((32 + lr) ^ psw)] = f2bu(e2);
            Pp[w][prow * 64 + ((48 + lr) ^ psw)] = f2bu(e3);
        }
#pragma unroll
        for (int d2 = 0; d2 < 8; ++d2)
#pragma unroll
            for (int j = 0; j < 4; ++j) o[d2][j] *= al[j];

        asm volatile("s_waitcnt lgkmcnt(0)" ::: "memory");
        __builtin_amdgcn_sched_barrier(0);
        const int asw = (lr & 7) << 3;
        bf16x8 pa0 = *(const bf16x8*)&Pp[w][lr * 64 + ((lg * 8)      ^ asw)];
        bf16x8 pa1 = *(const bf16x8*)&Pp[w][lr * 64 + ((32 + lg * 8) ^ asw)];

        __builtin_amdgcn_s_setprio(1);
#pragma unroll
        for (int d2 = 0; d2 < 8; ++d2) {
            const int rv = d2 * 16 + lr;
            const int vsw = (rv & 7) << 3;
            bf16x8 vf0 = *(const bf16x8*)&Vt[cur][rv * 64 + ((lg * 8)      ^ vsw)];
            bf16x8 vf1 = *(const bf16x8*)&Vt[cur][rv * 64 + ((32 + lg * 8) ^ vsw)];
            o[d2] = MFMA16(pa0, vf0, o[d2]);
            o[d2] = MFMA16(pa1, vf1, o[d2]);
        }
        __builtin_amdgcn_s_setprio(0);

        __syncthreads();
        cur ^= 1;
    }

#pragma unroll
    for (int j = 0; j < 4; ++j) {
        const float inv = 1.0f / l[j];
        bf16* dst = ctx + (size_t)(q0b + w * 16 + lg * 4 + j) * DIM + h * HEAD_DIM + lr;
#pragma unroll
        for (int d2 = 0; d2 < 8; ++d2)
            dst[d2 * 16] = __float2bfloat16(o[d2][j] * inv);
    }
}

// ---------------- host ----------------
extern "C" void kernel_launch(void* const* d_in, const int* in_sizes, int n_in,
                              void* d_out, int out_size, void* d_ws, size_t ws_size,
                              hipStream_t stream)
{
    const float* x   = (const float*)d_in[0];
    const float* fc  = (const float*)d_in[1];
    const float* fs  = (const float*)d_in[2];
    // d_in[3] = mask (unused; causal computed analytically)
    const float* wq  = (const float*)d_in[4];
    const float* wk  = (const float*)d_in[5];
    const float* wv  = (const float*)d_in[6];
    const float* wo  = (const float*)d_in[7];
    const float* w1  = (const float*)d_in[8];
    const float* w2  = (const float*)d_in[9];
    const float* w3  = (const float*)d_in[10];
    const float* anw = (const float*)d_in[11];
    const float* fnw = (const float*)d_in[12];
    float* out = (float*)d_out;

    char* p = (char*)d_ws;
    auto alloc = [&](size_t n) { char* r = p; p += (n + 255) & ~(size_t)255; return r; };
    bf16* wT  = (bf16*)alloc((size_t)HID * DIM * 2);     // reused per weight group
    bf16* hn  = (bf16*)alloc((size_t)SEQ * DIM * 2);
    bf16* qkv = (bf16*)alloc((size_t)SEQ * SQKV * 2);    // fused q|k|v, stride 6144
    bf16* vt  = (bf16*)alloc((size_t)SEQ * DIM * 2);
    bf16* ctx = (bf16*)alloc((size_t)SEQ * DIM * 2);
    bf16* fn  = (bf16*)alloc((size_t)SEQ * DIM * 2);
    float* h  = (float*)alloc((size_t)SEQ * DIM * 4);
    bf16* g   = (bf16*)alloc((size_t)SEQ * HID * 2);
    float* sk = (float*)alloc((size_t)4 * SEQ * DIM * 4);  // split-K partials (64MB)

    const dim3 tb32(32, 8);
    const int LDS256 = 131072;
    (void)hipFuncSetAttribute((const void*)gemm256_k<0>,
        hipFuncAttributeMaxDynamicSharedMemorySize, LDS256);
    (void)hipFuncSetAttribute((const void*)gemm256_k<2>,
        hipFuncAttributeMaxDynamicSharedMemorySize, LDS256);
    (void)hipFuncSetAttribute((const void*)gemm256_k<3>,
        hipFuncAttributeMaxDynamicSharedMemorySize, LDS256);

    rmsnorm_bf16_k<<<SEQ, 256, 0, stream>>>(x, anw, hn);

    // fused QKV: wT = [wq^T; wk^T; wv^T] (6144x2048) -> qkv[2048][6144]
    convT3_f32_bf16_k<<<dim3(DIM / 32, DIM / 32, 3), tb32, 0, stream>>>(wq, wk, wv, wT);
    gemm256_k<0><<<(SEQ / 256) * (SQKV / 256), 512, LDS256, stream>>>(
        hn, wT, qkv, nullptr, nullptr, SEQ, SQKV, DIM, SQKV / 256, (SEQ / 256) * (SQKV / 256), DIM);

    rope_qk_k<<<(SEQ * 1024) / 256, 256, 0, stream>>>(qkv, qkv + DIM, fc, fs);
    transpose_bf16_k<<<dim3(DIM / 32, SEQ / 32), tb32, 0, stream>>>(qkv + 2 * DIM, SQKV, vt);

    attn_fwd_k<<<dim3(SEQ / 64, N_HEADS), 256, 0, stream>>>(qkv, vt, ctx);

    // h = x + ctx @ wo : split-K=4 (Ks=512) -> partials, fused reduce+residual+rmsnorm
    convT_f32_bf16_k<<<dim3(DIM / 32, DIM / 32), tb32, 0, stream>>>(wo, wT, DIM, DIM);
    gemm256_k<3><<<(SEQ / 256) * (DIM / 256) * 4, 512, LDS256, stream>>>(
        ctx, wT, nullptr, nullptr, sk, SEQ, DIM, DIM, DIM / 256, (SEQ / 256) * (DIM / 256), 512);
    rmsnorm4_k<<<SEQ, 256, 0, stream>>>(sk, x, fnw, h, fn);

    convT_f32_bf16_k<<<dim3(HID / 32, DIM / 32), tb32, 0, stream>>>(w1, wT, DIM, HID);
    gemm256_k<0><<<(SEQ / 256) * (HID / 256), 512, LDS256, stream>>>(
        fn, wT, g, nullptr, nullptr, SEQ, HID, DIM, HID / 256, (SEQ / 256) * (HID / 256), DIM);
    convT_f32_bf16_k<<<dim3(HID / 32, DIM / 32), tb32, 0, stream>>>(w3, wT, DIM, HID);
    gemm256_k<2><<<(SEQ / 256) * (HID / 256), 512, LDS256, stream>>>(
        fn, wT, g, g, nullptr, SEQ, HID, DIM, HID / 256, (SEQ / 256) * (HID / 256), DIM);

    // out = h + g @ w2 : split-K=4 (Ks=2048) -> partials, reduce+residual
    convT_f32_bf16_k<<<dim3(DIM / 32, HID / 32), tb32, 0, stream>>>(w2, wT, HID, DIM);
    gemm256_k<3><<<(SEQ / 256) * (DIM / 256) * 4, 512, LDS256, stream>>>(
        g, wT, nullptr, nullptr, sk, SEQ, DIM, HID, DIM / 256, (SEQ / 256) * (DIM / 256), 2048);
    reduce4_k<<<(SEQ * DIM / 4) / 256, 256, 0, stream>>>(sk, h, out);
}

// Round 9
// 514.599 us; speedup vs baseline: 1.9698x; 1.0136x over previous
//
#include <hip/hip_runtime.h>
#include <hip/hip_bf16.h>

#define DIM 2048
#define HEAD_DIM 128
#define N_HEADS 16
#define SEQ 2048
#define HID 8192
#define SQKV 6144   // row stride of fused qkv activation

typedef short bf16x8 __attribute__((ext_vector_type(8)));
typedef float f32x4 __attribute__((ext_vector_type(4)));
using bf16 = __hip_bfloat16;

#define MFMA16(a, b, c) __builtin_amdgcn_mfma_f32_16x16x32_bf16(a, b, c, 0, 0, 0)

__device__ __forceinline__ unsigned short f2bu(float f) {
    union { bf16 b; unsigned short u; } cv;
    cv.b = __float2bfloat16(f);
    return cv.u;
}

// async global -> LDS, 16B per lane (dest must be lane-linear per wave)
__device__ __forceinline__ void gl16(const void* g, void* l) {
    __builtin_amdgcn_global_load_lds(
        (const __attribute__((address_space(1))) unsigned int*)g,
        (__attribute__((address_space(3))) unsigned int*)l, 16, 0, 0);
}

// ---------------- rmsnorm (fp32 in -> bf16 out) ----------------
__global__ __launch_bounds__(256) void rmsnorm_bf16_k(
    const float* __restrict__ x, const float* __restrict__ w, bf16* __restrict__ y)
{
    const int row = blockIdx.x;
    const int tid = threadIdx.x;
    const float* xr = x + (size_t)row * DIM;
    float4 v0 = ((const float4*)xr)[tid];
    float4 v1 = ((const float4*)xr)[tid + 256];
    float ss = v0.x*v0.x + v0.y*v0.y + v0.z*v0.z + v0.w*v0.w
             + v1.x*v1.x + v1.y*v1.y + v1.z*v1.z + v1.w*v1.w;
    for (int o = 32; o > 0; o >>= 1) ss += __shfl_down(ss, o);
    __shared__ float red[4];
    if ((tid & 63) == 0) red[tid >> 6] = ss;
    __syncthreads();
    float tot = red[0] + red[1] + red[2] + red[3];
    float r = rsqrtf(tot * (1.0f / DIM) + 1e-6f);
    float4 w0 = ((const float4*)w)[tid];
    float4 w1 = ((const float4*)w)[tid + 256];
    ushort4 o0, o1;
    o0.x = f2bu(v0.x * r * w0.x); o0.y = f2bu(v0.y * r * w0.y);
    o0.z = f2bu(v0.z * r * w0.z); o0.w = f2bu(v0.w * r * w0.w);
    o1.x = f2bu(v1.x * r * w1.x); o1.y = f2bu(v1.y * r * w1.y);
    o1.z = f2bu(v1.z * r * w1.z); o1.w = f2bu(v1.w * r * w1.w);
    ushort4* yr = (ushort4*)(y + (size_t)row * DIM);
    yr[tid] = o0;
    yr[tid + 256] = o1;
}

// ---------------- split-K reduce + residual + rmsnorm (fp32 h out, bf16 fn out) ----------------
__global__ __launch_bounds__(256) void rmsnorm4_k(
    const float* __restrict__ part, const float* __restrict__ x,
    const float* __restrict__ w, float* __restrict__ hout, bf16* __restrict__ y)
{
    const int row = blockIdx.x;
    const int tid = threadIdx.x;
    const size_t base = (size_t)row * DIM;
    const size_t SP = (size_t)SEQ * DIM;
    float4 r0, r1;
    float ss = 0.0f;
    {
        float4 a  = ((const float4*)(x + base))[tid];
        float4 p0 = ((const float4*)(part + base))[tid];
        float4 p1 = ((const float4*)(part + SP + base))[tid];
        float4 p2 = ((const float4*)(part + 2 * SP + base))[tid];
        float4 p3 = ((const float4*)(part + 3 * SP + base))[tid];
        r0.x = a.x + ((p0.x + p1.x) + (p2.x + p3.x));
        r0.y = a.y + ((p0.y + p1.y) + (p2.y + p3.y));
        r0.z = a.z + ((p0.z + p1.z) + (p2.z + p3.z));
        r0.w = a.w + ((p0.w + p1.w) + (p2.w + p3.w));
        ((float4*)(hout + base))[tid] = r0;
        ss += r0.x*r0.x + r0.y*r0.y + r0.z*r0.z + r0.w*r0.w;
    }
    {
        const int t2 = tid + 256;
        float4 a  = ((const float4*)(x + base))[t2];
        float4 p0 = ((const float4*)(part + base))[t2];
        float4 p1 = ((const float4*)(part + SP + base))[t2];
        float4 p2 = ((const float4*)(part + 2 * SP + base))[t2];
        float4 p3 = ((const float4*)(part + 3 * SP + base))[t2];
        r1.x = a.x + ((p0.x + p1.x) + (p2.x + p3.x));
        r1.y = a.y + ((p0.y + p1.y) + (p2.y + p3.y));
        r1.z = a.z + ((p0.z + p1.z) + (p2.z + p3.z));
        r1.w = a.w + ((p0.w + p1.w) + (p2.w + p3.w));
        ((float4*)(hout + base))[t2] = r1;
        ss += r1.x*r1.x + r1.y*r1.y + r1.z*r1.z + r1.w*r1.w;
    }
    for (int o = 32; o > 0; o >>= 1) ss += __shfl_down(ss, o);
    __shared__ float red[4];
    if ((tid & 63) == 0) red[tid >> 6] = ss;
    __syncthreads();
    float tot = red[0] + red[1] + red[2] + red[3];
    float r = rsqrtf(tot * (1.0f / DIM) + 1e-6f);
    float4 w0 = ((const float4*)w)[tid];
    float4 w1 = ((const float4*)w)[tid + 256];
    ushort4 o0, o1;
    o0.x = f2bu(r0.x * r * w0.x); o0.y = f2bu(r0.y * r * w0.y);
    o0.z = f2bu(r0.z * r * w0.z); o0.w = f2bu(r0.w * r * w0.w);
    o1.x = f2bu(r1.x * r * w1.x); o1.y = f2bu(r1.y * r * w1.y);
    o1.z = f2bu(r1.z * r * w1.z); o1.w = f2bu(r1.w * r * w1.w);
    ushort4* yr = (ushort4*)(y + base);
    yr[tid] = o0;
    yr[tid + 256] = o1;
}

// ---------------- split-K reduce + residual (fp32 out) ----------------
__global__ __launch_bounds__(256) void reduce4_k(
    const float* __restrict__ part, const float* __restrict__ h, float* __restrict__ out)
{
    const size_t i = (size_t)blockIdx.x * 256 + threadIdx.x;   // float4 index
    const size_t SP4 = (size_t)SEQ * DIM / 4;
    float4 a  = ((const float4*)h)[i];
    float4 p0 = ((const float4*)part)[i];
    float4 p1 = ((const float4*)part)[i + SP4];
    float4 p2 = ((const float4*)part)[i + 2 * SP4];
    float4 p3 = ((const float4*)part)[i + 3 * SP4];
    float4 r;
    r.x = a.x + ((p0.x + p1.x) + (p2.x + p3.x));
    r.y = a.y + ((p0.y + p1.y) + (p2.y + p3.y));
    r.z = a.z + ((p0.z + p1.z) + (p2.z + p3.z));
    r.w = a.w + ((p0.w + p1.w) + (p2.w + p3.w));
    ((float4*)out)[i] = r;
}

// ---------------- fp32 [R][C] -> bf16 [C][R] transpose-convert ----------------
__global__ __launch_bounds__(256) void convT_f32_bf16_k(
    const float* __restrict__ in, bf16* __restrict__ out, int R, int C)
{
    __shared__ float t[32][33];
    const int tx = threadIdx.x, ty = threadIdx.y;
    const int x0 = blockIdx.x * 32, y0 = blockIdx.y * 32;
#pragma unroll
    for (int i = 0; i < 4; ++i)
        t[ty + i * 8][tx] = in[(size_t)(y0 + ty + i * 8) * C + x0 + tx];
    __syncthreads();
#pragma unroll
    for (int i = 0; i < 4; ++i)
        out[(size_t)(x0 + ty + i * 8) * R + y0 + tx] = __float2bfloat16(t[tx][ty + i * 8]);
}

// 3 square weights -> one [3*DIM][DIM] B^T buffer (z selects wq/wk/wv)
__global__ __launch_bounds__(256) void convT3_f32_bf16_k(
    const float* __restrict__ wq, const float* __restrict__ wk,
    const float* __restrict__ wv, bf16* __restrict__ out)
{
    const int z = blockIdx.z;
    const float* in = z == 0 ? wq : (z == 1 ? wk : wv);
    bf16* o = out + (size_t)z * DIM * DIM;
    __shared__ float t[32][33];
    const int tx = threadIdx.x, ty = threadIdx.y;
    const int x0 = blockIdx.x * 32, y0 = blockIdx.y * 32;
#pragma unroll
    for (int i = 0; i < 4; ++i)
        t[ty + i * 8][tx] = in[(size_t)(y0 + ty + i * 8) * DIM + x0 + tx];
    __syncthreads();
#pragma unroll
    for (int i = 0; i < 4; ++i)
        o[(size_t)(x0 + ty + i * 8) * DIM + y0 + tx] = __float2bfloat16(t[tx][ty + i * 8]);
}

// ---------------- bf16 transpose with src stride (vt[d][s] = in[s][d]) ----------------
__global__ __launch_bounds__(256) void transpose_bf16_k(
    const bf16* __restrict__ in, int istride, bf16* __restrict__ out)
{
    __shared__ unsigned short t[32][33];
    const int tx = threadIdx.x, ty = threadIdx.y;
    const int x = blockIdx.x * 32 + tx;       // d
    const int y0 = blockIdx.y * 32;           // s
    const unsigned short* inu = (const unsigned short*)in;
    unsigned short* outu = (unsigned short*)out;
#pragma unroll
    for (int i = 0; i < 4; ++i)
        t[ty + i * 8][tx] = inu[(size_t)(y0 + ty + i * 8) * istride + x];
    __syncthreads();
    const int x2 = blockIdx.y * 32 + tx;
    const int y2 = blockIdx.x * 32;
#pragma unroll
    for (int i = 0; i < 4; ++i)
        outu[(size_t)(y2 + ty + i * 8) * SEQ + x2] = t[tx][ty + i * 8];
}

// ---------------- RoPE in-place on strided bf16 q,k ----------------
__global__ __launch_bounds__(256) void rope_qk_k(
    bf16* __restrict__ q, bf16* __restrict__ k,
    const float* __restrict__ cosb, const float* __restrict__ sinb)
{
    const int gid = blockIdx.x * 256 + threadIdx.x;   // < SEQ * 1024
    const int s = gid >> 10;
    const int p = gid & 1023;
    const int h = p >> 6, j = p & 63;
    const size_t off = (size_t)s * SQKV + h * HEAD_DIM + 2 * j;
    const float c = cosb[s * 64 + j], sn = sinb[s * 64 + j];
    float xr = __bfloat162float(q[off]), xi = __bfloat162float(q[off + 1]);
    q[off]     = __float2bfloat16(xr * c - xi * sn);
    q[off + 1] = __float2bfloat16(xr * sn + xi * c);
    xr = __bfloat162float(k[off]); xi = __bfloat162float(k[off + 1]);
    k[off]     = __float2bfloat16(xr * c - xi * sn);
    k[off + 1] = __float2bfloat16(xr * sn + xi * c);
}

// ---------------- 256x256 8-phase GEMM, BK=64, 512 threads, split-K ----------------
// EP 0: store bf16    EP 2: Cb = silu(other)*acc (in-place ok)    EP 3: fp32 partial store
// LDS (dynamic 128KB): A halves [buf][2][128*64], B halves at +64KB (128B rows).
// Swizzle: byte ^= ((row&7)<<4); inverse applied on global src of global_load_lds (rule #21).
// GROUP_M=4 supertiling; XCD-bijective block swizzle.
// K-loop: counted-lgkmcnt software pipeline -- phase p+1's A ds_reads issued before
// phase p's MFMA cluster, waits lgkmcnt(4); sched_barrier(0) fences pin issue order.
template <int EP>
__global__ __launch_bounds__(512, 2) void gemm256_k(
    const bf16* __restrict__ A, const bf16* __restrict__ Bt,
    bf16* __restrict__ Cb, const bf16* other, float* __restrict__ Pf,
    int M, int N, int K, int gx, int ntile, int Ks)
{
    extern __shared__ char smem[];
    const int t512 = threadIdx.x;
    const int w = t512 >> 6, lane = t512 & 63;
    const int lr = lane & 15, lg = lane >> 4;
    const int wm = w >> 2, wn = w & 3;           // 2 x 4 wave grid
    const int bofs = (wn & 1) * 64;              // B row offset inside its half

    // XCD-bijective block swizzle (m204)
    const int nwg = gridDim.x;                    // = ntile * splitk
    const int q8 = nwg >> 3, r8 = nwg & 7;
    const int xcd = blockIdx.x & 7, seqq = blockIdx.x >> 3;
    const int wgid = (xcd < r8 ? xcd * (q8 + 1) : r8 * (q8 + 1) + (xcd - r8) * q8) + seqq;
    const int split = wgid / ntile;
    const int tile = wgid % ntile;
    // GROUP_M=4 supertiling (requires M/256 divisible by 4 -- true for all uses)
    const int grp = tile / (4 * gx), rem = tile % (4 * gx);
    const int m0 = (grp * 4 + (rem & 3)) * 256, n0 = (rem >> 2) * 256;
    const int kb0 = split * Ks;
    const int nt = Ks >> 6;                       // 64-wide K tiles (nt >= 2 everywhere)

    // precomputed staging geometry: source pointers (pre-swizzled) advance kt*64 elems
    const bf16* aS[2][2]; const bf16* bS[2][2];   // [half][c]
    int sOff[2];
#pragma unroll
    for (int c = 0; c < 2; ++c) {
        const int s = (c * 512 + t512) * 16;            // linear byte slot
        const int pp = s ^ (((s >> 7) & 7) << 4);       // nominal position (involution)
        const int row = pp >> 7, colE = (pp & 127) >> 1;
        sOff[c] = s;
#pragma unroll
        for (int hs = 0; hs < 2; ++hs) {
            aS[hs][c] = A  + (size_t)(m0 + hs * 128 + row) * K + kb0 + colE;
            bS[hs][c] = Bt + (size_t)(n0 + hs * 128 + row) * K + kb0 + colE;
        }
    }
    auto stageA = [&](int buf, int kt) {
#pragma unroll
        for (int hs = 0; hs < 2; ++hs) {
            char* base = smem + (buf * 2 + hs) * 16384;
            gl16(aS[hs][0] + (kt << 6), base + sOff[0]);
            gl16(aS[hs][1] + (kt << 6), base + sOff[1]);
        }
    };
    auto stageB = [&](int buf, int kt) {
#pragma unroll
        for (int hs = 0; hs < 2; ++hs) {
            char* base = smem + 65536 + (buf * 2 + hs) * 16384;
            gl16(bS[hs][0] + (kt << 6), base + sOff[0]);
            gl16(bS[hs][1] + (kt << 6), base + sOff[1]);
        }
    };

    f32x4 acc[8][4] = {};
    bf16x8 bfr[4][2];

    // prologue: tile0 -> buf0, tile1 -> buf1 (8 loads each, B-then-A order)
    stageB(0, 0); stageA(0, 0);
    stageB(1, 1); stageA(1, 1);

#define SB __builtin_amdgcn_sched_barrier(0)
#define WAITL4 SB; asm volatile("s_waitcnt lgkmcnt(4)" ::: "memory"); SB
#define WAITL0 SB; asm volatile("s_waitcnt lgkmcnt(0)" ::: "memory"); SB
#define LDA_(mf, ks, dst) { int off = (((mf) * 16 + lr) * 128) + ((((ks) * 64) + lg * 16) ^ ((lr & 7) << 4)); \
        dst = *(const bf16x8*)(Am + off); }
#define LDB_(nf, ks, dst) { int off = ((bofs + (nf) * 16 + lr) * 128) + ((((ks) * 64) + lg * 16) ^ ((lr & 7) << 4)); \
        dst = *(const bf16x8*)(Bm + off); }
#define MFMA_PH(mf0, r0, r1, r2, r3) { \
        __builtin_amdgcn_s_setprio(1); \
        _Pragma("unroll") \
        for (int nf = 0; nf < 4; ++nf) { \
            acc[(mf0)][nf]     = MFMA16(r0, bfr[nf][0], acc[(mf0)][nf]); \
            acc[(mf0)][nf]     = MFMA16(r1, bfr[nf][1], acc[(mf0)][nf]); \
            acc[(mf0) + 1][nf] = MFMA16(r2, bfr[nf][0], acc[(mf0) + 1][nf]); \
            acc[(mf0) + 1][nf] = MFMA16(r3, bfr[nf][1], acc[(mf0) + 1][nf]); \
        } \
        __builtin_amdgcn_s_setprio(0); }

    for (int t = 0; t < nt; ++t) {
        const int cur = t & 1;
        // tile t+1's 8 loads are the only ones newer than tile t's -> vmcnt(8)
        if (t + 1 < nt) { asm volatile("s_waitcnt vmcnt(8)" ::: "memory"); }
        else            { asm volatile("s_waitcnt vmcnt(0)" ::: "memory"); }
        SB;
        __builtin_amdgcn_s_barrier();

        const char* Am = smem + (cur * 2 + wm) * 16384;
        const char* Bm = smem + 65536 + (cur * 2 + (wn >> 1)) * 16384;
        const bool pf = (t + 2 < nt);

        bf16x8 x0, x1, x2, x3, y0, y1, y2, y3;
        // issue group 1: all B (8) + A-ph0 (4)
#pragma unroll
        for (int nf = 0; nf < 4; ++nf) { LDB_(nf, 0, bfr[nf][0]) LDB_(nf, 1, bfr[nf][1]) }
        LDA_(0, 0, x0) LDA_(0, 1, x1) LDA_(1, 0, x2) LDA_(1, 1, x3)
        SB;
        // issue group 2: A-ph1 (4)
        LDA_(2, 0, y0) LDA_(2, 1, y1) LDA_(3, 0, y2) LDA_(3, 1, y3)
        WAITL4;                                   // B + A-ph0 complete; A-ph1 in flight
        MFMA_PH(0, x0, x1, x2, x3)
        __builtin_amdgcn_s_barrier();             // all waves' B reads retired
        if (pf) stageB(cur, t + 2);               // B region of buf[cur] free to rewrite

        LDA_(4, 0, x0) LDA_(4, 1, x1) LDA_(5, 0, x2) LDA_(5, 1, x3)   // A-ph2
        WAITL4;                                   // A-ph1 complete; A-ph2 in flight
        MFMA_PH(2, y0, y1, y2, y3)

        LDA_(6, 0, y0) LDA_(6, 1, y1) LDA_(7, 0, y2) LDA_(7, 1, y3)   // A-ph3
        WAITL4;                                   // A-ph2 complete; A-ph3 in flight
        MFMA_PH(4, x0, x1, x2, x3)

        WAITL0;                                   // A-ph3 complete
        MFMA_PH(6, y0, y1, y2, y3)
        __builtin_amdgcn_s_barrier();             // all A reads retired
        if (pf) stageA(cur, t + 2);
    }
#undef LDA_
#undef LDB_
#undef MFMA_PH
#undef WAITL4
#undef WAITL0
#undef SB

    // ---- epilogue ----
    float* pf_base = Pf + (size_t)split * M * N;
#pragma unroll
    for (int mf = 0; mf < 8; ++mf)
#pragma unroll
        for (int nf = 0; nf < 4; ++nf) {
            const int row = m0 + wm * 128 + mf * 16 + lg * 4;
            const int col = n0 + wn * 64 + nf * 16 + lr;
#pragma unroll
            for (int r = 0; r < 4; ++r) {
                const size_t idx = (size_t)(row + r) * N + col;
                const float v = acc[mf][nf][r];
                if (EP == 0) {
                    Cb[idx] = __float2bfloat16(v);
                } else if (EP == 2) {
                    const float gg = __bfloat162float(other[idx]);
                    const float sg = gg / (1.0f + __expf(-gg));
                    Cb[idx] = __float2bfloat16(sg * v);
                } else {
                    pf_base[idx] = v;
                }
            }
        }
}

// ---------------- causal flash attention: QBLK=64 (4 waves x 16 rows), shared KV tiles ----------------
__global__ __launch_bounds__(256) void attn_fwd_k(
    const bf16* __restrict__ qkv, const bf16* __restrict__ vT, bf16* __restrict__ ctx)
{
    const int tid = threadIdx.x;
    const int w = tid >> 6, lane = tid & 63;
    const int lr = lane & 15, lg = lane >> 4;
    const int h = blockIdx.y;
    const int qidx = (blockIdx.y < 8) ? blockIdx.x : (31 - blockIdx.x);
    const int q0b = qidx * 64;
    const int nt = qidx + 1;                  // 64-row KV tiles (causal)

    __shared__ __align__(16) unsigned short Kt[2][64 * 128];
    __shared__ __align__(16) unsigned short Vt[2][128 * 64];
    __shared__ __align__(16) unsigned short Pp[4][16 * 64];

    const char* kbase = (const char*)(qkv + DIM + h * HEAD_DIM);
    const char* vbase = (const char*)(vT + (size_t)h * HEAD_DIM * SEQ);

    const int krow_c = tid >> 4;
    const int kcolB  = (tid & 15) * 16;
    const int vrow_c = tid >> 3;
    const int vcolB  = (tid & 7) * 16;

    auto stage = [&](int buf, int kb) {
#pragma unroll
        for (int c = 0; c < 4; ++c) {
            const int r = c * 16 + krow_c;
            gl16(kbase + (size_t)(kb + r) * (SQKV * 2) + (kcolB ^ ((r & 7) << 4)),
                 &Kt[buf][c * 2048 + tid * 8]);
        }
#pragma unroll
        for (int c = 0; c < 4; ++c) {
            const int r = c * 32 + vrow_c;
            gl16(vbase + (size_t)r * (SEQ * 2) + kb * 2 + (vcolB ^ ((r & 7) << 4)),
                 &Vt[buf][c * 2048 + tid * 8]);
        }
    };

    bf16x8 qf[4];
    const bf16* qrow = qkv + (size_t)(q0b + w * 16 + lr) * SQKV + h * HEAD_DIM;
#pragma unroll
    for (int dt = 0; dt < 4; ++dt)
        qf[dt] = *(const bf16x8*)(qrow + dt * 32 + lg * 8);

    f32x4 o[8] = {};
    float m[4], l[4];
#pragma unroll
    for (int j = 0; j < 4; ++j) { m[j] = -3e38f; l[j] = 0.0f; }
    const float scale = 0.08838834764831845f;

    stage(0, 0);
    __syncthreads();

    int cur = 0;
    for (int t = 0; t < nt; ++t) {
        const int kb = t * 64;
        if (t + 1 < nt) stage(cur ^ 1, kb + 64);

        f32x4 s[4] = {};
        __builtin_amdgcn_s_setprio(1);
#pragma unroll
        for (int ss = 0; ss < 4; ++ss) {
            const int r = ss * 16 + lr;
            const int sw = (r & 7) << 3;
#pragma unroll
            for (int dt = 0; dt < 4; ++dt) {
                bf16x8 kf = *(const bf16x8*)&Kt[cur][r * 128 + ((dt * 32 + lg * 8) ^ sw)];
                s[ss] = MFMA16(qf[dt], kf, s[ss]);
            }
        }
        __builtin_amdgcn_s_setprio(0);

        float al[4];
#pragma unroll
        for (int j = 0; j < 4; ++j) {
            const int qi = q0b + w * 16 + lg * 4 + j;
            const int prow = lg * 4 + j;
            const int psw = (prow & 7) << 3;
            float a[4];
#pragma unroll
            for (int ss = 0; ss < 4; ++ss)
                a[ss] = s[ss][j] * scale + ((kb + ss * 16 + lr) > qi ? -1e9f : 0.0f);
            float mx = fmaxf(fmaxf(a[0], a[1]), fmaxf(a[2], a[3]));
            mx = fmaxf(mx, __shfl_xor(mx, 1));
            mx = fmaxf(mx, __shfl_xor(mx, 2));
            mx = fmaxf(mx, __shfl_xor(mx, 4));
            mx = fmaxf(mx, __shfl_xor(mx, 8));
            const float mn = fmaxf(m[j], mx);
            const float asc = __expf(m[j] - mn);
            float e0 = __expf(a[0] - mn), e1 = __expf(a[1] - mn);
            float e2 = __expf(a[2] - mn), e3 = __expf(a[3] - mn);
            float rs = (e0 + e1) + (e2 + e3);
            rs += __shfl_xor(rs, 1); rs += __shfl_xor(rs, 2);
            rs += __shfl_xor(rs, 4); rs += __shfl_xor(rs, 8);
            l[j] = l[j] * asc + rs;
            m[j] = mn;
            al[j] = asc;
            Pp[w][prow * 64 + ((lr)      ^ psw)] = f2bu(e0);
            Pp[w][prow * 64 + ((16 + lr) ^ psw)] = f2bu(e1);
            Pp[w][prow * 64 + ((32 + lr) ^ psw)] = f2bu(e2);
            Pp[w][prow * 64 + ((48 + lr) ^ psw)] = f2bu(e3);
        }
#pragma unroll
        for (int d2 = 0; d2 < 8; ++d2)
#pragma unroll
            for (int j = 0; j < 4; ++j) o[d2][j] *= al[j];

        asm volatile("s_waitcnt lgkmcnt(0)" ::: "memory");
        __builtin_amdgcn_sched_barrier(0);
        const int asw = (lr & 7) << 3;
        bf16x8 pa0 = *(const bf16x8*)&Pp[w][lr * 64 + ((lg * 8)      ^ asw)];
        bf16x8 pa1 = *(const bf16x8*)&Pp[w][lr * 64 + ((32 + lg * 8) ^ asw)];

        __builtin_amdgcn_s_setprio(1);
#pragma unroll
        for (int d2 = 0; d2 < 8; ++d2) {
            const int rv = d2 * 16 + lr;
            const int vsw = (rv & 7) << 3;
            bf16x8 vf0 = *(const bf16x8*)&Vt[cur][rv * 64 + ((lg * 8)      ^ vsw)];
            bf16x8 vf1 = *(const bf16x8*)&Vt[cur][rv * 64 + ((32 + lg * 8) ^ vsw)];
            o[d2] = MFMA16(pa0, vf0, o[d2]);
            o[d2] = MFMA16(pa1, vf1, o[d2]);
        }
        __builtin_amdgcn_s_setprio(0);

        __syncthreads();
        cur ^= 1;
    }

#pragma unroll
    for (int j = 0; j < 4; ++j) {
        const float inv = 1.0f / l[j];
        bf16* dst = ctx + (size_t)(q0b + w * 16 + lg * 4 + j) * DIM + h * HEAD_DIM + lr;
#pragma unroll
        for (int d2 = 0; d2 < 8; ++d2)
            dst[d2 * 16] = __float2bfloat16(o[d2][j] * inv);
    }
}

// ---------------- host ----------------
extern "C" void kernel_launch(void* const* d_in, const int* in_sizes, int n_in,
                              void* d_out, int out_size, void* d_ws, size_t ws_size,
                              hipStream_t stream)
{
    const float* x   = (const float*)d_in[0];
    const float* fc  = (const float*)d_in[1];
    const float* fs  = (const float*)d_in[2];
    // d_in[3] = mask (unused; causal computed analytically)
    const float* wq  = (const float*)d_in[4];
    const float* wk  = (const float*)d_in[5];
    const float* wv  = (const float*)d_in[6];
    const float* wo  = (const float*)d_in[7];
    const float* w1  = (const float*)d_in[8];
    const float* w2  = (const float*)d_in[9];
    const float* w3  = (const float*)d_in[10];
    const float* anw = (const float*)d_in[11];
    const float* fnw = (const float*)d_in[12];
    float* out = (float*)d_out;

    char* p = (char*)d_ws;
    auto alloc = [&](size_t n) { char* r = p; p += (n + 255) & ~(size_t)255; return r; };
    bf16* wT  = (bf16*)alloc((size_t)HID * DIM * 2);     // reused per weight group
    bf16* hn  = (bf16*)alloc((size_t)SEQ * DIM * 2);
    bf16* qkv = (bf16*)alloc((size_t)SEQ * SQKV * 2);    // fused q|k|v, stride 6144
    bf16* vt  = (bf16*)alloc((size_t)SEQ * DIM * 2);
    bf16* ctx = (bf16*)alloc((size_t)SEQ * DIM * 2);
    bf16* fn  = (bf16*)alloc((size_t)SEQ * DIM * 2);
    float* h  = (float*)alloc((size_t)SEQ * DIM * 4);
    bf16* g   = (bf16*)alloc((size_t)SEQ * HID * 2);
    float* sk = (float*)alloc((size_t)4 * SEQ * DIM * 4);  // split-K partials (64MB)

    const dim3 tb32(32, 8);
    const int LDS256 = 131072;
    (void)hipFuncSetAttribute((const void*)gemm256_k<0>,
        hipFuncAttributeMaxDynamicSharedMemorySize, LDS256);
    (void)hipFuncSetAttribute((const void*)gemm256_k<2>,
        hipFuncAttributeMaxDynamicSharedMemorySize, LDS256);
    (void)hipFuncSetAttribute((const void*)gemm256_k<3>,
        hipFuncAttributeMaxDynamicSharedMemorySize, LDS256);

    rmsnorm_bf16_k<<<SEQ, 256, 0, stream>>>(x, anw, hn);

    // fused QKV: wT = [wq^T; wk^T; wv^T] (6144x2048) -> qkv[2048][6144]
    convT3_f32_bf16_k<<<dim3(DIM / 32, DIM / 32, 3), tb32, 0, stream>>>(wq, wk, wv, wT);
    gemm256_k<0><<<(SEQ / 256) * (SQKV / 256), 512, LDS256, stream>>>(
        hn, wT, qkv, nullptr, nullptr, SEQ, SQKV, DIM, SQKV / 256, (SEQ / 256) * (SQKV / 256), DIM);

    rope_qk_k<<<(SEQ * 1024) / 256, 256, 0, stream>>>(qkv, qkv + DIM, fc, fs);
    transpose_bf16_k<<<dim3(DIM / 32, SEQ / 32), tb32, 0, stream>>>(qkv + 2 * DIM, SQKV, vt);

    attn_fwd_k<<<dim3(SEQ / 64, N_HEADS), 256, 0, stream>>>(qkv, vt, ctx);

    // h = x + ctx @ wo : split-K=4 (Ks=512) -> partials, fused reduce+residual+rmsnorm
    convT_f32_bf16_k<<<dim3(DIM / 32, DIM / 32), tb32, 0, stream>>>(wo, wT, DIM, DIM);
    gemm256_k<3><<<(SEQ / 256) * (DIM / 256) * 4, 512, LDS256, stream>>>(
        ctx, wT, nullptr, nullptr, sk, SEQ, DIM, DIM, DIM / 256, (SEQ / 256) * (DIM / 256), 512);
    rmsnorm4_k<<<SEQ, 256, 0, stream>>>(sk, x, fnw, h, fn);

    convT_f32_bf16_k<<<dim3(HID / 32, DIM / 32), tb32, 0, stream>>>(w1, wT, DIM, HID);
    gemm256_k<0><<<(SEQ / 256) * (HID / 256), 512, LDS256, stream>>>(
        fn, wT, g, nullptr, nullptr, SEQ, HID, DIM, HID / 256, (SEQ / 256) * (HID / 256), DIM);
    convT_f32_bf16_k<<<dim3(HID / 32, DIM / 32), tb32, 0, stream>>>(w3, wT, DIM, HID);
    gemm256_k<2><<<(SEQ / 256) * (HID / 256), 512, LDS256, stream>>>(
        fn, wT, g, g, nullptr, SEQ, HID, DIM, HID / 256, (SEQ / 256) * (HID / 256), DIM);

    // out = h + g @ w2 : split-K=4 (Ks=2048) -> partials, reduce+residual
    convT_f32_bf16_k<<<dim3(DIM / 32, HID / 32), tb32, 0, stream>>>(w2, wT, HID, DIM);
    gemm256_k<3><<<(SEQ / 256) * (DIM / 256) * 4, 512, LDS256, stream>>>(
        g, wT, nullptr, nullptr, sk, SEQ, DIM, HID, DIM / 256, (SEQ / 256) * (DIM / 256), 2048);
    reduce4_k<<<(SEQ * DIM / 4) / 256, 256, 0, stream>>>(sk, h, out);
}